// Round 15
// baseline (154.859 us; speedup 1.0000x reference)
//
#include <hip/hip_runtime.h>
#include <hip/hip_bf16.h>
#include <cstddef>

// ---------------- problem constants ----------------
#define LSEQ   1024
#define DM     384
#define DSSM   512
#define NSTATE 512
#define HK     32
#define HD     64
#define CHUNKSZ 256
#define NC     4
#define CBCDT  264
#define CTOT   776
#define DMLP   256

typedef __attribute__((ext_vector_type(8))) short short8;
typedef __attribute__((ext_vector_type(4))) float f32x4;

__device__ __forceinline__ float siluf(float x)    { return x / (1.f + expf(-x)); }
__device__ __forceinline__ float softplusf(float x){ return fmaxf(x, 0.f) + log1pf(expf(-fabsf(x))); }

__device__ __forceinline__ ushort f2bf(float f) {
  union { float f; unsigned u; } v; v.f = f;
  unsigned r = v.u + 0x7fffu + ((v.u >> 16) & 1u);
  return (ushort)(r >> 16);
}
__device__ __forceinline__ float bf2f(ushort h) {
  union { unsigned u; float f; } v; v.u = ((unsigned)h) << 16;
  return v.f;
}

__device__ __forceinline__ int dir_src(int k, int l) {
  switch (k) {
    case 0:  return l;
    case 1:  return ((l & 31) << 5) | (l >> 5);
    case 2:  return 1023 - l;
    default: { int lr = 1023 - l; return ((lr & 31) << 5) | (lr >> 5); }
  }
}

// ---------------- weight transpose-casts: grid 246 ----------------
__global__ __launch_bounds__(256) void k_prep(
    const float* __restrict__ W_skip, const float* __restrict__ W_xs,
    const float* __restrict__ W_bcdt, const float* __restrict__ W_out,
    ushort* __restrict__ WsxT, ushort* __restrict__ WbcdtT, ushort* __restrict__ WoutT)
{
  __shared__ __align__(16) ushort T[64 * 72];
  int bid = blockIdx.x;
  const int t = threadIdx.x;
  const float* src; ushort* dst; int N, ldd, nbx;
  if (bid < 96)        {            src = W_skip; dst = WsxT;                     N = 1024; ldd = 384; nbx = 16; }
  else if (bid < 144)  { bid -= 96; src = W_xs;   dst = WsxT + (size_t)1024*384;  N = 512;  ldd = 384; nbx = 8; }
  else if (bid < 174)  { bid -= 144; src = W_bcdt; dst = WbcdtT;                  N = 264;  ldd = 384; nbx = 5; }
  else                 { bid -= 174; src = W_out;  dst = WoutT;                   N = 384;  ldd = 768; nbx = 6; }
  const int n0 = (bid % nbx) * 64, k0 = (bid / nbx) * 64;
  const int rk = t >> 2, q = t & 3;
  const int k = k0 + rk;
  const float* srow = src + (size_t)k * N + n0 + q * 16;
#pragma unroll
  for (int i = 0; i < 16; ++i) {
    int n = n0 + q * 16 + i;
    T[(q * 16 + i) * 72 + rk] = (n < N) ? f2bf(srow[i]) : (ushort)0;
  }
  __syncthreads();
  int n = n0 + rk;
  if (n < N) {
    ushort* d = dst + (size_t)n * ldd + k0 + q * 16;
    *(uint4*)d       = *(const uint4*)&T[rk * 72 + q * 16];
    *(uint4*)(d + 8) = *(const uint4*)&T[rk * 72 + q * 16 + 8];
  }
}

// ---------------- f32-A GEMM body (cast in staging), 128x128 tile, LDS dbuf ----------------
__device__ __forceinline__ void gemm_f32a_body(
    ushort (*As)[128 * 72], ushort (*Bs)[128 * 72],
    const float* __restrict__ A0, const float* __restrict__ A1, int rows0,
    const ushort* __restrict__ BT, float* __restrict__ C, int N, int K)
{
  const int n0 = blockIdx.x * 128, m0 = blockIdx.y * 128;
  const int t = threadIdx.x, lane = t & 63, wv = t >> 6;
  const int wm = wv & 1, wn = wv >> 1;
  const int lrow = lane & 15, lk8 = (lane >> 4) * 8;
  const int rowL = t >> 1, cL = (t & 1) * 32;
  const float* Af = (m0 < rows0) ? (A0 + (size_t)m0 * K) : (A1 + (size_t)(m0 - rows0) * K);
  const float* pa_src = Af + (size_t)rowL * K + cL;
  const int nB = n0 + rowL;
  const ushort* pb_src = BT + (size_t)nB * K + cL;
  const bool bval = (nB < N);
  float4 fa[8]; uint4 pb[4];
#define GAISSUE(k0) do { \
    _Pragma("unroll") for (int q2 = 0; q2 < 8; ++q2) fa[q2] = *(const float4*)(pa_src + (k0) + q2 * 4); \
    if (bval) { \
      pb[0] = *(const uint4*)(pb_src + (k0));      pb[1] = *(const uint4*)(pb_src + (k0) + 8); \
      pb[2] = *(const uint4*)(pb_src + (k0) + 16); pb[3] = *(const uint4*)(pb_src + (k0) + 24); \
    } else { uint4 z = {0,0,0,0}; pb[0]=z; pb[1]=z; pb[2]=z; pb[3]=z; } \
  } while(0)
  GAISSUE(0);
  f32x4 acc[4][4] = {};
  for (int k0 = 0; k0 < K; k0 += 64) {
    const int pbuf = (k0 >> 6) & 1;
#pragma unroll
    for (int q2 = 0; q2 < 8; ++q2) {
      ushort o[4] = { f2bf(fa[q2].x), f2bf(fa[q2].y), f2bf(fa[q2].z), f2bf(fa[q2].w) };
      *(uint2*)&As[pbuf][rowL * 72 + cL + q2 * 4] = *(const uint2*)o;
    }
#pragma unroll
    for (int q2 = 0; q2 < 4; ++q2) *(uint4*)&Bs[pbuf][rowL * 72 + cL + q2 * 8] = pb[q2];
    __syncthreads();
    if (k0 + 64 < K) GAISSUE(k0 + 64);
#pragma unroll
    for (int sub = 0; sub < 2; ++sub) {
      const int ko = lk8 + sub * 32;
      short8 a[4], b[4];
#pragma unroll
      for (int f = 0; f < 4; ++f) {
        a[f] = *(const short8*)&As[pbuf][(wm * 64 + 16 * f + lrow) * 72 + ko];
        b[f] = *(const short8*)&Bs[pbuf][(wn * 64 + 16 * f + lrow) * 72 + ko];
      }
#pragma unroll
      for (int fi = 0; fi < 4; ++fi)
#pragma unroll
        for (int fj = 0; fj < 4; ++fj)
          acc[fi][fj] = __builtin_amdgcn_mfma_f32_16x16x32_bf16(a[fi], b[fj], acc[fi][fj], 0, 0, 0);
    }
  }
#pragma unroll
  for (int fi = 0; fi < 4; ++fi) {
    int row0 = m0 + wm * 64 + 16 * fi + (lane >> 4) * 4;
#pragma unroll
    for (int fj = 0; fj < 4; ++fj) {
      int col = n0 + wn * 64 + 16 * fj + lrow;
      if (col < N)
#pragma unroll
        for (int rr = 0; rr < 4; ++rr)
          C[(size_t)(row0 + rr) * N + col] = acc[fi][fj][rr];
    }
  }
}

// ---------------- fused input GEMMs: z=0 skipxs (12x16), z=1 bcdt (3x16) ----------------
__global__ __launch_bounds__(256) void k_gemm_in(
    const float* __restrict__ u1, const float* __restrict__ u2,
    const float* __restrict__ uc1, const float* __restrict__ uc2,
    const ushort* __restrict__ WsxT, const ushort* __restrict__ WbcdtT,
    float* __restrict__ skipxs, float* __restrict__ bc_pre)
{
  __shared__ __align__(16) ushort As[2][128 * 72];
  __shared__ __align__(16) ushort Bs[2][128 * 72];
  if (blockIdx.z == 0) {
    gemm_f32a_body(As, Bs, u1, u2, 1024, WsxT, skipxs, 1536, 384);
  } else {
    if (blockIdx.x >= 3) return;
    gemm_f32a_body(As, Bs, uc1, uc2, 1024, WbcdtT, bc_pre, 264, 384);
  }
}

// ---------------- depthwise 3x3 conv + bias + SiLU; writes xbcT[s][m][c] ----------------
__global__ __launch_bounds__(256) void k_conv(
    const float* __restrict__ skipxs, const float* __restrict__ bc_pre,
    const float* __restrict__ wxs, const float* __restrict__ bxs,
    const float* __restrict__ wbc, const float* __restrict__ bbc,
    float* __restrict__ xbcT)
{
  const int m = blockIdx.x, s = blockIdx.y;
  const int h = m >> 5, w = m & 31;
  const float* xp = skipxs + (size_t)s * LSEQ * 1536 + 1024;
  const float* bp = bc_pre + (size_t)s * LSEQ * CBCDT;
  for (int c = threadIdx.x; c < CTOT; c += 256) {
    const float* src; int stride; const float* wt; float bias;
    if (c < DSSM) { src = xp + c; stride = 1536; wt = wxs + (size_t)c * 9; bias = bxs[c]; }
    else { int cb = c - DSSM; src = bp + cb; stride = CBCDT; wt = wbc + (size_t)cb * 9; bias = bbc[cb]; }
    float acc = bias;
#pragma unroll
    for (int dh = -1; dh <= 1; ++dh) {
      int h2 = h + dh; if (h2 < 0 || h2 > 31) continue;
#pragma unroll
      for (int dw = -1; dw <= 1; ++dw) {
        int w2 = w + dw; if (w2 < 0 || w2 > 31) continue;
        acc += src[(size_t)(h2 * 32 + w2) * stride] * wt[(dh + 1) * 3 + (dw + 1)];
      }
    }
    xbcT[((size_t)s * LSEQ + m) * CTOT + c] = siluf(acc);
  }
}

// ---------------- fused gathers: [0,512) Xh, [512,576) B/C/BT, [576,592) dA+cumsum ----------------
__global__ __launch_bounds__(256) void k_gather_all(
    const float* __restrict__ xbcT, const float* __restrict__ dt_bias,
    const float* __restrict__ A_logs,
    ushort* __restrict__ XhT, ushort* __restrict__ Bbf, ushort* __restrict__ Cbf,
    ushort* __restrict__ BT, float* __restrict__ dAcs)
{
  __shared__ __align__(16) ushort U[128 * 72];
  const int bid = blockIdx.x, s = blockIdx.y, t = threadIdx.x;
  if (bid < 512) {
    const int lt = bid & 15, kh = bid >> 4;
    const int k = kh >> 3, hh = kh & 7;
    const int r = t >> 2, q = t & 3;
    const int l = lt * 64 + r;
    const int m = dir_src(k, l);
    const float* row = xbcT + ((size_t)s * LSEQ + m) * CTOT;
    float dtv = softplusf(row[768 + hh] + dt_bias[kh]);
    const float* xp = row + hh * 64 + q * 16;
#pragma unroll
    for (int i = 0; i < 16; ++i)
      U[(q * 16 + i) * 72 + r] = f2bf(xp[i] * dtv);
    __syncthreads();
    ushort* dst = XhT + (((size_t)s * HK + kh) * HD + r) * LSEQ + lt * 64 + q * 16;
    *(uint4*)dst       = *(const uint4*)&U[r * 72 + q * 16];
    *(uint4*)(dst + 8) = *(const uint4*)&U[r * 72 + q * 16 + 8];
    return;
  }
  if (bid < 576) {
    const int idx = bid - 512;
    const int lt = idx & 15, k = idx >> 4;
    const int r = t >> 2, q = t & 3;
    const int l = lt * 64 + r;
    const int m = dir_src(k, l);
    const float* row = xbcT + ((size_t)s * LSEQ + m) * CTOT;
    {
      const float* bsrc = row + 512 + q * 32;
      ushort ub[32];
#pragma unroll
      for (int i2 = 0; i2 < 8; ++i2) {
        float4 v = *(const float4*)(bsrc + i2 * 4);
        ub[i2 * 4 + 0] = f2bf(v.x); ub[i2 * 4 + 1] = f2bf(v.y);
        ub[i2 * 4 + 2] = f2bf(v.z); ub[i2 * 4 + 3] = f2bf(v.w);
      }
      ushort* bd = Bbf + ((size_t)s * LSEQ + l) * NSTATE + k * 128 + q * 32;
#pragma unroll
      for (int i2 = 0; i2 < 4; ++i2) *(uint4*)(bd + i2 * 8) = *(const uint4*)&ub[i2 * 8];
#pragma unroll
      for (int i = 0; i < 32; ++i) U[(q * 32 + i) * 72 + r] = ub[i];
    }
    {
      const float* csrc = row + 640 + q * 32;
      ushort uc[32];
#pragma unroll
      for (int i2 = 0; i2 < 8; ++i2) {
        float4 v = *(const float4*)(csrc + i2 * 4);
        uc[i2 * 4 + 0] = f2bf(v.x); uc[i2 * 4 + 1] = f2bf(v.y);
        uc[i2 * 4 + 2] = f2bf(v.z); uc[i2 * 4 + 3] = f2bf(v.w);
      }
      ushort* cd = Cbf + ((size_t)s * LSEQ + l) * NSTATE + k * 128 + q * 32;
#pragma unroll
      for (int i2 = 0; i2 < 4; ++i2) *(uint4*)(cd + i2 * 8) = *(const uint4*)&uc[i2 * 8];
    }
    __syncthreads();
    {
      const int n = t >> 1, half = t & 1;
      ushort* dst = BT + ((size_t)s * NSTATE + k * 128 + n) * LSEQ + lt * 64 + half * 32;
      const ushort* src = &U[n * 72 + half * 32];
#pragma unroll
      for (int i2 = 0; i2 < 4; ++i2) *(uint4*)(dst + i2 * 8) = *(const uint4*)(src + i2 * 8);
    }
    return;
  }
  {
    float* Lf = (float*)U;
    const int idx = bid - 576;
    const int z = idx & 3, k = idx >> 2;
    const int m = dir_src(k, z * 256 + t);
    const float* rowdt = xbcT + ((size_t)s * LSEQ + m) * CTOT + 768;
    float4 d0 = *(const float4*)rowdt;
    float4 d1 = *(const float4*)(rowdt + 4);
    float dv[8] = { d0.x, d0.y, d0.z, d0.w, d1.x, d1.y, d1.z, d1.w };
#pragma unroll
    for (int hh = 0; hh < 8; ++hh) {
      int kh = k * 8 + hh;
      float dAv = softplusf(dv[hh] + dt_bias[kh]) * (-expf(A_logs[kh]));
      Lf[hh * 256 + t] = dAv;
    }
    __syncthreads();
    const int hh = t >> 5, seg = t & 31;
    float p[8]; float run = 0.f;
#pragma unroll
    for (int i = 0; i < 8; ++i) { run += Lf[hh * 256 + seg * 8 + i]; p[i] = run; }
    float sc = run, tot = run;
#pragma unroll
    for (int d = 1; d < 32; d <<= 1) {
      float o = __shfl_up(sc, d, 32);
      if (seg >= d) sc += o;
    }
    float off = sc - tot;
    float* dst = dAcs + ((size_t)s * HK + k * 8 + hh) * LSEQ + z * 256 + seg * 8;
#pragma unroll
    for (int i = 0; i < 8; ++i) dst[i] = p[i] + off;
  }
}

// ---------------- fused scan core: [0,80) CB lower-tri, [80,592) states+scan ----------------
// LDS dbuf + 2-deep register prefetch (slots are compile-time via full unroll)
__global__ __launch_bounds__(256) void k_scan_core(
    const ushort* __restrict__ Cbf, const ushort* __restrict__ Bbf, ushort* __restrict__ CBbf,
    const ushort* __restrict__ BT, const ushort* __restrict__ XhT,
    const float* __restrict__ dAcs, ushort* __restrict__ prevP)
{
  __shared__ __align__(16) ushort As[2][64 * 72];
  __shared__ __align__(16) ushort Bs[2][64 * 72];
  __shared__ __align__(16) ushort Tr[64 * 72];
  __shared__ float decay[CHUNKSZ];
  const int bid = blockIdx.x, t = threadIdx.x;
  const int lane = t & 63, wv = t >> 6;
  const int lrow = lane & 15, lk8 = (lane >> 4) * 8;
  const int rA = t >> 2, cA = (t & 3) * 16;

  if (bid < 80) {
    // CB = C @ B^T, lower-triangular 64x64 tiles only (jt <= it)
    const int sz = bid & 7, pidx = bid >> 3, s = sz >> 2, z = sz & 3;
    int it = 0; { while ((it + 1) * (it + 2) / 2 <= pidx) ++it; }
    const int jt = pidx - it * (it + 1) / 2;
    const ushort* Ap = Cbf + ((size_t)s * LSEQ + z * CHUNKSZ + it * 64 + rA) * NSTATE + cA;
    const ushort* Bp = Bbf + ((size_t)s * LSEQ + z * CHUNKSZ + jt * 64 + rA) * NSTATE + cA;
    uint4 qa0[2], qb0[2], qa1[2], qb1[2];
#define CBISSUE0(k0) do { qa0[0]=*(const uint4*)(Ap+(k0)); qa0[1]=*(const uint4*)(Ap+(k0)+8); \
                          qb0[0]=*(const uint4*)(Bp+(k0)); qb0[1]=*(const uint4*)(Bp+(k0)+8); } while(0)
#define CBISSUE1(k0) do { qa1[0]=*(const uint4*)(Ap+(k0)); qa1[1]=*(const uint4*)(Ap+(k0)+8); \
                          qb1[0]=*(const uint4*)(Bp+(k0)); qb1[1]=*(const uint4*)(Bp+(k0)+8); } while(0)
    CBISSUE0(0); CBISSUE1(64);
    f32x4 acc[4] = {};
#pragma unroll
    for (int k0 = 0; k0 < NSTATE; k0 += 64) {
      const int S = (k0 >> 6) & 1;
      if (S == 0) {
        *(uint4*)&As[0][rA * 72 + cA] = qa0[0]; *(uint4*)&As[0][rA * 72 + cA + 8] = qa0[1];
        *(uint4*)&Bs[0][rA * 72 + cA] = qb0[0]; *(uint4*)&Bs[0][rA * 72 + cA + 8] = qb0[1];
      } else {
        *(uint4*)&As[1][rA * 72 + cA] = qa1[0]; *(uint4*)&As[1][rA * 72 + cA + 8] = qa1[1];
        *(uint4*)&Bs[1][rA * 72 + cA] = qb1[0]; *(uint4*)&Bs[1][rA * 72 + cA + 8] = qb1[1];
      }
      __syncthreads();
      if (k0 + 128 < NSTATE) { if (S == 0) CBISSUE0(k0 + 128); else CBISSUE1(k0 + 128); }
#pragma unroll
      for (int sub = 0; sub < 2; ++sub) {
        const int ko = lk8 + sub * 32;
        short8 a = *(const short8*)&As[S][(16 * wv + lrow) * 72 + ko];
#pragma unroll
        for (int fj = 0; fj < 4; ++fj) {
          short8 b = *(const short8*)&Bs[S][(16 * fj + lrow) * 72 + ko];
          acc[fj] = __builtin_amdgcn_mfma_f32_16x16x32_bf16(a, b, acc[fj], 0, 0, 0);
        }
      }
    }
    ushort* Cp = CBbf + (size_t)sz * CHUNKSZ * CHUNKSZ;
    const int row0 = it * 64 + 16 * wv + (lane >> 4) * 4;
#pragma unroll
    for (int fj = 0; fj < 4; ++fj) {
      int col = jt * 64 + 16 * fj + lrow;
#pragma unroll
      for (int rr = 0; rr < 4; ++rr)
        Cp[(size_t)(row0 + rr) * CHUNKSZ + col] = f2bf(acc[fj][rr]);
    }
    return;
  }

  // states + inter-chunk scan -> prevP
  {
    const int idx = bid - 80;
    const int nh = idx & 7, kh = (idx >> 3) & 31, s = idx >> 8;
    const float* dA = dAcs + ((size_t)s * HK + kh) * LSEQ;
    float carry[4][4];
#pragma unroll
    for (int fj = 0; fj < 4; ++fj)
#pragma unroll
      for (int rr = 0; rr < 4; ++rr) carry[fj][rr] = 0.f;

    for (int z = 0; z < NC; ++z) {
      __syncthreads();
      const float dlast = dA[z * CHUNKSZ + CHUNKSZ - 1];
      decay[t] = __expf(dlast - dA[z * CHUNKSZ + t]);
      {
        const int n_base = 16 * wv + (lane >> 4) * 4;
#pragma unroll
        for (int fj = 0; fj < 4; ++fj) {
          const int p = 16 * fj + lrow;
#pragma unroll
          for (int rr = 0; rr < 4; ++rr)
            Tr[p * 72 + n_base + rr] = f2bf(carry[fj][rr]);
        }
      }
      __syncthreads();
      {
        const int sz = s * 4 + z;
        ushort* dst = prevP + (((size_t)sz * HK + kh) * HD + rA) * NSTATE + nh * 64 + cA;
        *(uint4*)dst       = *(const uint4*)&Tr[rA * 72 + cA];
        *(uint4*)(dst + 8) = *(const uint4*)&Tr[rA * 72 + cA + 8];
      }
      const ushort* Ap = BT + ((size_t)s * NSTATE + nh * 64 + rA) * LSEQ + z * CHUNKSZ + cA;
      const ushort* Xp = XhT + (((size_t)s * HK + kh) * HD + rA) * LSEQ + z * CHUNKSZ + cA;
      uint4 qa0[2], qb0[2], qa1[2], qb1[2];
#define SSISSUE0(k0) do { qa0[0]=*(const uint4*)(Ap+(k0)); qa0[1]=*(const uint4*)(Ap+(k0)+8); \
                          qb0[0]=*(const uint4*)(Xp+(k0)); qb0[1]=*(const uint4*)(Xp+(k0)+8); } while(0)
#define SSISSUE1(k0) do { qa1[0]=*(const uint4*)(Ap+(k0)); qa1[1]=*(const uint4*)(Ap+(k0)+8); \
                          qb1[0]=*(const uint4*)(Xp+(k0)); qb1[1]=*(const uint4*)(Xp+(k0)+8); } while(0)
      SSISSUE0(0); SSISSUE1(64);
      f32x4 acc[4] = {};
#pragma unroll
      for (int k0 = 0; k0 < CHUNKSZ; k0 += 64) {
        const int S = (k0 >> 6) & 1;
        if (S == 0) {
          *(uint4*)&As[0][rA * 72 + cA] = qa0[0]; *(uint4*)&As[0][rA * 72 + cA + 8] = qa0[1];
          ushort tmp[16];
          *(uint4*)&tmp[0] = qb0[0]; *(uint4*)&tmp[8] = qb0[1];
#pragma unroll
          for (int i2 = 0; i2 < 8; ++i2) {
            int c = k0 + cA + 2 * i2;
            unsigned wpk = (unsigned)f2bf(bf2f(tmp[2 * i2]) * decay[c]) |
                           ((unsigned)f2bf(bf2f(tmp[2 * i2 + 1]) * decay[c + 1]) << 16);
            *(unsigned*)&Bs[0][rA * 72 + cA + 2 * i2] = wpk;
          }
        } else {
          *(uint4*)&As[1][rA * 72 + cA] = qa1[0]; *(uint4*)&As[1][rA * 72 + cA + 8] = qa1[1];
          ushort tmp[16];
          *(uint4*)&tmp[0] = qb1[0]; *(uint4*)&tmp[8] = qb1[1];
#pragma unroll
          for (int i2 = 0; i2 < 8; ++i2) {
            int c = k0 + cA + 2 * i2;
            unsigned wpk = (unsigned)f2bf(bf2f(tmp[2 * i2]) * decay[c]) |
                           ((unsigned)f2bf(bf2f(tmp[2 * i2 + 1]) * decay[c + 1]) << 16);
            *(unsigned*)&Bs[1][rA * 72 + cA + 2 * i2] = wpk;
          }
        }
        __syncthreads();
        if (k0 + 128 < CHUNKSZ) { if (S == 0) SSISSUE0(k0 + 128); else SSISSUE1(k0 + 128); }
#pragma unroll
        for (int sub = 0; sub < 2; ++sub) {
          const int ko = lk8 + sub * 32;
          short8 a = *(const short8*)&As[S][(16 * wv + lrow) * 72 + ko];
#pragma unroll
          for (int fj = 0; fj < 4; ++fj) {
            short8 b = *(const short8*)&Bs[S][(16 * fj + lrow) * 72 + ko];
            acc[fj] = __builtin_amdgcn_mfma_f32_16x16x32_bf16(a, b, acc[fj], 0, 0, 0);
          }
        }
      }
      const float cdec = __expf(dlast);
#pragma unroll
      for (int fj = 0; fj < 4; ++fj)
#pragma unroll
        for (int rr = 0; rr < 4; ++rr)
          carry[fj][rr] = carry[fj][rr] * cdec + acc[fj][rr];
    }
  }
}

// ---------------- Y = Ydiag + Yoff (MFMA, LDS dbuf + 2-deep prefetch in phase A) ----------------
// z==0 blocks skip phase A entirely: prev state is identically zero.
__global__ __launch_bounds__(256, 2) void k_y_mfma(
    const ushort* __restrict__ CBbf, const ushort* __restrict__ XhT,
    const ushort* __restrict__ Cbf, const ushort* __restrict__ prevP,
    const float* __restrict__ dAcs, ushort* __restrict__ Ybf)
{
  __shared__ __align__(16) ushort As[2][128 * 72];
  __shared__ __align__(16) ushort Bs[2][64 * 72];
  __shared__ float seg[CHUNKSZ];
  __shared__ float f2s[CHUNKSZ];
  const int it = blockIdx.x, kh = blockIdx.y, sz = blockIdx.z, s = sz >> 2, z = sz & 3;
  const int t = threadIdx.x, lane = t & 63, wv = t >> 6;
  const int lrow = lane & 15, lk8 = (lane >> 4) * 8;
  const int i0 = it * 128;
  const float* dAp = dAcs + ((size_t)s * HK + kh) * LSEQ + z * CHUNKSZ;
  seg[t] = dAp[t];
  __syncthreads();
  f2s[t] = __expf(seg[(t >> 5) << 5] - seg[t]);
  __syncthreads();

  const int rA = t >> 1, cA = (t & 1) * 32;
  const int rB = t >> 2, cB = (t & 3) * 16;
  f32x4 acc[2][4] = {};
  uint4 qa[4], qb[2];

  // phase A: acc = C @ prev^T  (skip for z==0: prev == 0); 2-deep prefetch
  if (z != 0) {
    const ushort* Cp = Cbf + ((size_t)s * LSEQ + z * CHUNKSZ + i0 + rA) * NSTATE + cA;
    const ushort* Pp = prevP + (((size_t)sz * HK + kh) * HD + rB) * NSTATE + cB;
    uint4 pa0[4], pb0[2], pa1[4], pb1[2];
#define YISSUEA0(k0) do { \
    pa0[0]=*(const uint4*)(Cp+(k0));    pa0[1]=*(const uint4*)(Cp+(k0)+8); \
    pa0[2]=*(const uint4*)(Cp+(k0)+16); pa0[3]=*(const uint4*)(Cp+(k0)+24); \
    pb0[0]=*(const uint4*)(Pp+(k0));    pb0[1]=*(const uint4*)(Pp+(k0)+8); } while(0)
#define YISSUEA1(k0) do { \
    pa1[0]=*(const uint4*)(Cp+(k0));    pa1[1]=*(const uint4*)(Cp+(k0)+8); \
    pa1[2]=*(const uint4*)(Cp+(k0)+16); pa1[3]=*(const uint4*)(Cp+(k0)+24); \
    pb1[0]=*(const uint4*)(Pp+(k0));    pb1[1]=*(const uint4*)(Pp+(k0)+8); } while(0)
    YISSUEA0(0); YISSUEA1(64);
#pragma unroll
    for (int k0 = 0; k0 < NSTATE; k0 += 64) {
      const int S = (k0 >> 6) & 1;
      if (S == 0) {
#pragma unroll
        for (int q2 = 0; q2 < 4; ++q2) *(uint4*)&As[0][rA * 72 + cA + q2 * 8] = pa0[q2];
        *(uint4*)&Bs[0][rB * 72 + cB] = pb0[0]; *(uint4*)&Bs[0][rB * 72 + cB + 8] = pb0[1];
      } else {
#pragma unroll
        for (int q2 = 0; q2 < 4; ++q2) *(uint4*)&As[1][rA * 72 + cA + q2 * 8] = pa1[q2];
        *(uint4*)&Bs[1][rB * 72 + cB] = pb1[0]; *(uint4*)&Bs[1][rB * 72 + cB + 8] = pb1[1];
      }
      __syncthreads();
      if (k0 + 128 < NSTATE) { if (S == 0) YISSUEA0(k0 + 128); else YISSUEA1(k0 + 128); }
#pragma unroll
      for (int sub = 0; sub < 2; ++sub) {
        const int ko = lk8 + sub * 32;
        short8 a[2], b[4];
#pragma unroll
        for (int f = 0; f < 2; ++f) a[f] = *(const short8*)&As[S][(32 * wv + 16 * f + lrow) * 72 + ko];
#pragma unroll
        for (int f = 0; f < 4; ++f) b[f] = *(const short8*)&Bs[S][(16 * f + lrow) * 72 + ko];
#pragma unroll
        for (int fi = 0; fi < 2; ++fi)
#pragma unroll
          for (int fj = 0; fj < 4; ++fj)
            acc[fi][fj] = __builtin_amdgcn_mfma_f32_16x16x32_bf16(a[fi], b[fj], acc[fi][fj], 0, 0, 0);
      }
    }
  }

  // prefetch phase-B tile 0 while rescaling
  const ushort* CBp = CBbf + ((size_t)sz * CHUNKSZ + i0 + rA) * CHUNKSZ;
  const ushort* Xp = XhT + (((size_t)s * HK + kh) * HD + rB) * LSEQ + z * CHUNKSZ + cB;
  const int nktB = 2 * it + 2;
#define YISSUEB(kt) do { const ushort* sa = CBp + (kt) * 64 + cA; \
    qa[0]=*(const uint4*)sa;      qa[1]=*(const uint4*)(sa+8); \
    qa[2]=*(const uint4*)(sa+16); qa[3]=*(const uint4*)(sa+24); \
    qb[0]=*(const uint4*)(Xp+(kt)*64); qb[1]=*(const uint4*)(Xp+(kt)*64+8); } while(0)
  YISSUEB(0);

  // scale Yoff rows by e^{seg_i}
  if (z != 0) {
#pragma unroll
    for (int fi = 0; fi < 2; ++fi) {
      int rloc = 32 * wv + 16 * fi + (lane >> 4) * 4;
#pragma unroll
      for (int rr = 0; rr < 4; ++rr) {
        float e = __expf(seg[i0 + rloc + rr]);
#pragma unroll
        for (int fj = 0; fj < 4; ++fj) acc[fi][fj][rr] *= e;
      }
    }
  }

  // phase A ended on buffer 1 (or never ran); phase B starts on buffer 0 -> safe.
  // phase B: Ydiag (slice-factored, CB bf16), 1-deep prefetch
  for (int kt = 0; kt < nktB; ++kt) {
    const int pb2 = kt & 1;
    {
      const int i = i0 + rA;
      const int jbase = kt * 64 + cA;
      if (i >= jbase) {
        float f1 = __expf(seg[i] - seg[jbase]);
        ushort tmp[32];
        *(uint4*)&tmp[0] = qa[0]; *(uint4*)&tmp[8] = qa[1];
        *(uint4*)&tmp[16] = qa[2]; *(uint4*)&tmp[24] = qa[3];
#pragma unroll
        for (int c = 0; c < 32; c += 2) {
          int j = jbase + c;
          float v0 = (j     <= i) ? bf2f(tmp[c])     * f1 : 0.f;
          float v1 = (j + 1 <= i) ? bf2f(tmp[c + 1]) * f1 : 0.f;
          *(unsigned*)&As[pb2][rA * 72 + cA + c] = (unsigned)f2bf(v0) | ((unsigned)f2bf(v1) << 16);
        }
      } else {
        uint4 zz = {0, 0, 0, 0};
#pragma unroll
        for (int q2 = 0; q2 < 4; ++q2) *(uint4*)&As[pb2][rA * 72 + cA + q2 * 8] = zz;
      }
    }
    {
      ushort tmp[16];
      *(uint4*)&tmp[0] = qb[0]; *(uint4*)&tmp[8] = qb[1];
#pragma unroll
      for (int i2 = 0; i2 < 8; ++i2) {
        int j = kt * 64 + cB + 2 * i2;
        unsigned wpk = (unsigned)f2bf(bf2f(tmp[2 * i2]) * f2s[j]) |
                       ((unsigned)f2bf(bf2f(tmp[2 * i2 + 1]) * f2s[j + 1]) << 16);
        *(unsigned*)&Bs[pb2][rB * 72 + cB + 2 * i2] = wpk;
      }
    }
    __syncthreads();
    if (kt + 1 < nktB) YISSUEB(kt + 1);
#pragma unroll
    for (int sub = 0; sub < 2; ++sub) {
      if (2 * kt + sub <= 4 * it + wv) {
        const int ko = lk8 + sub * 32;
        short8 a[2], b[4];
#pragma unroll
        for (int f = 0; f < 2; ++f) a[f] = *(const short8*)&As[pb2][(32 * wv + 16 * f + lrow) * 72 + ko];
#pragma unroll
        for (int f = 0; f < 4; ++f) b[f] = *(const short8*)&Bs[pb2][(16 * f + lrow) * 72 + ko];
#pragma unroll
        for (int fi = 0; fi < 2; ++fi)
#pragma unroll
          for (int fj = 0; fj < 4; ++fj)
            acc[fi][fj] = __builtin_amdgcn_mfma_f32_16x16x32_bf16(a[fi], b[fj], acc[fi][fj], 0, 0, 0);
      }
    }
  }

  ushort* Yp = Ybf + (((size_t)s * LSEQ + z * CHUNKSZ + i0) * HK + kh) * HD;
#pragma unroll
  for (int fi = 0; fi < 2; ++fi) {
    int row0 = 32 * wv + 16 * fi + (lane >> 4) * 4;
#pragma unroll
    for (int fj = 0; fj < 4; ++fj) {
      int col = 16 * fj + lrow;
#pragma unroll
      for (int rr = 0; rr < 4; ++rr)
        Yp[(size_t)(row0 + rr) * (HK * HD) + col] = f2bf(acc[fi][fj][rr]);
    }
  }
}

// ---------------- combine 4 directions + D*x + gated RMSNorm + MLP half (bf16 out) ----------------
__global__ __launch_bounds__(256) void k_combine(
    const ushort* __restrict__ Ybf, const float* __restrict__ xbcT,
    const float* __restrict__ skipxs, const float* __restrict__ Ds,
    const float* __restrict__ normw, ushort* __restrict__ o768bf)
{
  const int m = blockIdx.x, s = blockIdx.y, t = threadIdx.x;
  const int h = m >> 5, w = m & 31;
  const int l0 = m, l1 = (w << 5) | h, l2 = 1023 - m, l3 = 1023 - ((w << 5) | h);
  const ushort* Yb = Ybf + (size_t)s * LSEQ * (HK * HD);
  const float* xrow = xbcT + ((size_t)s * LSEQ + m) * CTOT;
  const float* srow = skipxs + ((size_t)s * LSEQ + m) * 1536;

  float g[2];
  float ss = 0.f;
#pragma unroll
  for (int q = 0; q < 2; ++q) {
    int d = t + q * 256;
    int hh = d >> 6, p = d & 63;
    float dsum = Ds[hh] + Ds[hh + 8] + Ds[hh + 16] + Ds[hh + 24];
    float val = bf2f(Yb[((size_t)l0 * HK + hh) * HD + p])
              + bf2f(Yb[((size_t)l1 * HK + 8 + hh) * HD + p])
              + bf2f(Yb[((size_t)l2 * HK + 16 + hh) * HD + p])
              + bf2f(Yb[((size_t)l3 * HK + 24 + hh) * HD + p])
              + xrow[d] * dsum;
    float zv = srow[512 + d];
    g[q] = val * siluf(zv);
    ss += g[q] * g[q];
  }
  for (int off = 32; off > 0; off >>= 1) ss += __shfl_down(ss, off, 64);
  __shared__ float red[4];
  if ((t & 63) == 0) red[t >> 6] = ss;
  __syncthreads();
  float total = red[0] + red[1] + red[2] + red[3];
  float scale = rsqrtf(total * (1.f / 512.f) + 1e-5f);

  ushort* orow = o768bf + ((size_t)s * LSEQ + m) * 768;
#pragma unroll
  for (int q = 0; q < 2; ++q) {
    int d = t + q * 256;
    orow[256 + d] = f2bf(g[q] * scale * normw[d]);
  }
  float z0 = srow[t], x0 = srow[256 + t];
  orow[t] = f2bf(siluf(z0) * x0);
}

// ---------------- 64x64-tile bf16 GEMM (out GEMM), LDS dbuf ----------------
__global__ __launch_bounds__(256) void gemm64_bf16(
    const ushort* __restrict__ A, const ushort* __restrict__ BT,
    float* __restrict__ C, int M, int N, int K)
{
  __shared__ __align__(16) ushort As[2][64 * 72];
  __shared__ __align__(16) ushort Bs[2][64 * 72];
  const int n0 = blockIdx.x * 64, m0 = blockIdx.y * 64;
  const int t = threadIdx.x, lane = t & 63, wv = t >> 6;
  const int wm = wv & 1, wn = wv >> 1;
  const int lrow = lane & 15, lk8 = (lane >> 4) * 8;
  const int rowL = t >> 2, cL = (t & 3) * 16;
  const ushort* pa_src = A + (size_t)(m0 + rowL) * K + cL;
  const int nB = n0 + rowL;
  const ushort* pb_src = BT + (size_t)nB * K + cL;
  const bool bval = (nB < N);
  uint4 pa[2], pb[2];
#define G64ISSUE(k0) do { \
    pa[0]=*(const uint4*)(pa_src+(k0)); pa[1]=*(const uint4*)(pa_src+(k0)+8); \
    if (bval) { pb[0]=*(const uint4*)(pb_src+(k0)); pb[1]=*(const uint4*)(pb_src+(k0)+8); } \
    else { uint4 z={0,0,0,0}; pb[0]=z; pb[1]=z; } } while(0)
  G64ISSUE(0);
  f32x4 acc[2][2] = {};
  for (int k0 = 0; k0 < K; k0 += 64) {
    const int pbuf = (k0 >> 6) & 1;
    *(uint4*)&As[pbuf][rowL * 72 + cL] = pa[0]; *(uint4*)&As[pbuf][rowL * 72 + cL + 8] = pa[1];
    *(uint4*)&Bs[pbuf][rowL * 72 + cL] = pb[0]; *(uint4*)&Bs[pbuf][rowL * 72 + cL + 8] = pb[1];
    __syncthreads();
    if (k0 + 64 < K) G64ISSUE(k0 + 64);
#pragma unroll
    for (int sub = 0; sub < 2; ++sub) {
      const int ko = lk8 + sub * 32;
      short8 a[2], b[2];
#pragma unroll
      for (int f = 0; f < 2; ++f) {
        a[f] = *(const short8*)&As[pbuf][(wm * 32 + 16 * f + lrow) * 72 + ko];
        b[f] = *(const short8*)&Bs[pbuf][(wn * 32 + 16 * f + lrow) * 72 + ko];
      }
#pragma unroll
      for (int fi = 0; fi < 2; ++fi)
#pragma unroll
        for (int fj = 0; fj < 2; ++fj)
          acc[fi][fj] = __builtin_amdgcn_mfma_f32_16x16x32_bf16(a[fi], b[fj], acc[fi][fj], 0, 0, 0);
    }
  }
#pragma unroll
  for (int fi = 0; fi < 2; ++fi) {
    int row0 = m0 + wm * 32 + 16 * fi + (lane >> 4) * 4;
#pragma unroll
    for (int fj = 0; fj < 2; ++fj) {
      int col = n0 + wn * 32 + 16 * fj + lrow;
      if (col < N)
#pragma unroll
        for (int rr = 0; rr < 4; ++rr)
          C[(size_t)(row0 + rr) * N + col] = acc[fi][fj][rr];
    }
  }
}

// ---------------- workspace layout (float units) ----------------
constexpr size_t OFF_SKIPXS = 0;                         // 2048*1536 f32 = 3145728
constexpr size_t OFF_XBCT   = 3145728;                   // 1589248
constexpr size_t OFF_XHT    = OFF_XBCT + 1589248;        // bf16 -> 2097152 f
constexpr size_t OFF_BBF    = OFF_XHT + 2097152;         // 524288
constexpr size_t OFF_CBF    = OFF_BBF + 524288;          // 524288
constexpr size_t OFF_BTBF   = OFF_CBF + 524288;          // 524288
constexpr size_t OFF_DA     = OFF_BTBF + 524288;         // 65536
constexpr size_t OFF_CB     = OFF_DA + 65536;            // bf16 -> 262144 f
constexpr size_t OFF_PREV   = OFF_CB + 262144;           // bf16 -> 4194304 f
constexpr size_t OFF_Y      = OFF_PREV + 4194304;        // bf16 -> 2097152 f
constexpr size_t OFF_O768   = OFF_Y + 2097152;           // bf16 -> 786432 f
constexpr size_t OFF_WSXT   = OFF_O768 + 786432;         // 294912
constexpr size_t OFF_WBCT   = OFF_WSXT + 294912;         // 50688
constexpr size_t OFF_WOUT   = OFF_WBCT + 50688;          // 147456
constexpr size_t OFF_BCP    = OFF_PREV;                  // overlay: bc_pre (dead before prevP written)

extern "C" void kernel_launch(void* const* d_in, const int* in_sizes, int n_in,
                              void* d_out, int out_size, void* d_ws, size_t ws_size,
                              hipStream_t stream)
{
  const float* u1     = (const float*)d_in[0];
  const float* u2     = (const float*)d_in[1];
  const float* u2c1   = (const float*)d_in[2];
  const float* u1c2   = (const float*)d_in[3];
  const float* W_skip = (const float*)d_in[4];
  const float* W_xs   = (const float*)d_in[5];
  const float* W_bcdt = (const float*)d_in[6];
  const float* cxw    = (const float*)d_in[7];
  const float* cxb    = (const float*)d_in[8];
  const float* cbw    = (const float*)d_in[9];
  const float* cbb    = (const float*)d_in[10];
  const float* Ds     = (const float*)d_in[11];
  const float* normw  = (const float*)d_in[12];
  const float* W_out  = (const float*)d_in[13];
  const float* dt_b   = (const float*)d_in[14];
  const float* A_logs = (const float*)d_in[15];
  float* out = (float*)d_out;
  float* ws  = (float*)d_ws;

  float*  skipxs  = ws + OFF_SKIPXS;
  float*  xbcT    = ws + OFF_XBCT;
  ushort* XhT     = (ushort*)(ws + OFF_XHT);
  ushort* Bbf     = (ushort*)(ws + OFF_BBF);
  ushort* Cbf     = (ushort*)(ws + OFF_CBF);
  ushort* BTbf    = (ushort*)(ws + OFF_BTBF);
  float*  dAcs    = ws + OFF_DA;
  ushort* CBbf    = (ushort*)(ws + OFF_CB);
  ushort* prevP   = (ushort*)(ws + OFF_PREV);
  ushort* Ybf     = (ushort*)(ws + OFF_Y);
  ushort* o768bf  = (ushort*)(ws + OFF_O768);
  ushort* WsxT    = (ushort*)(ws + OFF_WSXT);
  ushort* WbcdtT  = (ushort*)(ws + OFF_WBCT);
  ushort* WoutT   = (ushort*)(ws + OFF_WOUT);
  float*  bc_pre  = ws + OFF_BCP;

  // 1: weight transposes
  k_prep<<<dim3(246), 256, 0, stream>>>(W_skip, W_xs, W_bcdt, W_out, WsxT, WbcdtT, WoutT);
  // 2: both input GEMMs in one launch
  k_gemm_in<<<dim3(12, 16, 2), 256, 0, stream>>>(u1, u2, u2c1, u1c2, WsxT, WbcdtT, skipxs, bc_pre);
  // 3: conv
  k_conv<<<dim3(1024, 2), 256, 0, stream>>>(skipxs, bc_pre, cxw, cxb, cbw, cbb, xbcT);
  // 4: all gathers + cumsum
  k_gather_all<<<dim3(592, 2), 256, 0, stream>>>(xbcT, dt_b, A_logs, XhT, Bbf, Cbf, BTbf, dAcs);
  // 5: CB (lower-tri) + states/scan
  k_scan_core<<<dim3(592), 256, 0, stream>>>(Cbf, Bbf, CBbf, BTbf, XhT, dAcs, prevP);
  // 6: Y (z==0 blocks skip phase A)
  k_y_mfma<<<dim3(2, 32, 8), 256, 0, stream>>>(CBbf, XhT, Cbf, prevP, dAcs, Ybf);
  // 7: combine
  k_combine<<<dim3(1024, 2), 256, 0, stream>>>(Ybf, xbcT, skipxs, Ds, normw, o768bf);
  // 8: out GEMM
  gemm64_bf16<<<dim3(6, 32), 256, 0, stream>>>(o768bf, WoutT, out, 2048, 384, 768);
}

// Round 16
// 115.671 us; speedup vs baseline: 1.3388x; 1.3388x over previous
//
#include <hip/hip_runtime.h>
#include <hip/hip_bf16.h>
#include <cstddef>

// ---------------- problem constants ----------------
#define LSEQ   1024
#define DM     384
#define DSSM   512
#define NSTATE 512
#define HK     32
#define HD     64
#define CHUNKSZ 256
#define NC     4
#define CBCDT  264
#define CTOT   776
#define DMLP   256

typedef __attribute__((ext_vector_type(8))) short short8;
typedef __attribute__((ext_vector_type(4))) float f32x4;

__device__ __forceinline__ float siluf(float x)    { return x / (1.f + expf(-x)); }
__device__ __forceinline__ float softplusf(float x){ return fmaxf(x, 0.f) + log1pf(expf(-fabsf(x))); }

__device__ __forceinline__ ushort f2bf(float f) {
  union { float f; unsigned u; } v; v.f = f;
  unsigned r = v.u + 0x7fffu + ((v.u >> 16) & 1u);
  return (ushort)(r >> 16);
}
__device__ __forceinline__ float bf2f(ushort h) {
  union { unsigned u; float f; } v; v.u = ((unsigned)h) << 16;
  return v.f;
}

__device__ __forceinline__ int dir_src(int k, int l) {
  switch (k) {
    case 0:  return l;
    case 1:  return ((l & 31) << 5) | (l >> 5);
    case 2:  return 1023 - l;
    default: { int lr = 1023 - l; return ((lr & 31) << 5) | (lr >> 5); }
  }
}

// ---------------- weight transpose-casts: grid 246 ----------------
__global__ __launch_bounds__(256) void k_prep(
    const float* __restrict__ W_skip, const float* __restrict__ W_xs,
    const float* __restrict__ W_bcdt, const float* __restrict__ W_out,
    ushort* __restrict__ WsxT, ushort* __restrict__ WbcdtT, ushort* __restrict__ WoutT)
{
  __shared__ __align__(16) ushort T[64 * 72];
  int bid = blockIdx.x;
  const int t = threadIdx.x;
  const float* src; ushort* dst; int N, ldd, nbx;
  if (bid < 96)        {            src = W_skip; dst = WsxT;                     N = 1024; ldd = 384; nbx = 16; }
  else if (bid < 144)  { bid -= 96; src = W_xs;   dst = WsxT + (size_t)1024*384;  N = 512;  ldd = 384; nbx = 8; }
  else if (bid < 174)  { bid -= 144; src = W_bcdt; dst = WbcdtT;                  N = 264;  ldd = 384; nbx = 5; }
  else                 { bid -= 174; src = W_out;  dst = WoutT;                   N = 384;  ldd = 768; nbx = 6; }
  const int n0 = (bid % nbx) * 64, k0 = (bid / nbx) * 64;
  const int rk = t >> 2, q = t & 3;
  const int k = k0 + rk;
  const float* srow = src + (size_t)k * N + n0 + q * 16;
#pragma unroll
  for (int i = 0; i < 16; ++i) {
    int n = n0 + q * 16 + i;
    T[(q * 16 + i) * 72 + rk] = (n < N) ? f2bf(srow[i]) : (ushort)0;
  }
  __syncthreads();
  int n = n0 + rk;
  if (n < N) {
    ushort* d = dst + (size_t)n * ldd + k0 + q * 16;
    *(uint4*)d       = *(const uint4*)&T[rk * 72 + q * 16];
    *(uint4*)(d + 8) = *(const uint4*)&T[rk * 72 + q * 16 + 8];
  }
}

// ---------------- f32-A GEMM body (cast in staging), 128x128 tile, LDS dbuf ----------------
__device__ __forceinline__ void gemm_f32a_body(
    ushort (*As)[128 * 72], ushort (*Bs)[128 * 72],
    const float* __restrict__ A0, const float* __restrict__ A1, int rows0,
    const ushort* __restrict__ BT, float* __restrict__ C, int N, int K)
{
  const int n0 = blockIdx.x * 128, m0 = blockIdx.y * 128;
  const int t = threadIdx.x, lane = t & 63, wv = t >> 6;
  const int wm = wv & 1, wn = wv >> 1;
  const int lrow = lane & 15, lk8 = (lane >> 4) * 8;
  const int rowL = t >> 1, cL = (t & 1) * 32;
  const float* Af = (m0 < rows0) ? (A0 + (size_t)m0 * K) : (A1 + (size_t)(m0 - rows0) * K);
  const float* pa_src = Af + (size_t)rowL * K + cL;
  const int nB = n0 + rowL;
  const ushort* pb_src = BT + (size_t)nB * K + cL;
  const bool bval = (nB < N);
  float4 fa[8]; uint4 pb[4];
#define GAISSUE(k0) do { \
    _Pragma("unroll") for (int q2 = 0; q2 < 8; ++q2) fa[q2] = *(const float4*)(pa_src + (k0) + q2 * 4); \
    if (bval) { \
      pb[0] = *(const uint4*)(pb_src + (k0));      pb[1] = *(const uint4*)(pb_src + (k0) + 8); \
      pb[2] = *(const uint4*)(pb_src + (k0) + 16); pb[3] = *(const uint4*)(pb_src + (k0) + 24); \
    } else { uint4 z = {0,0,0,0}; pb[0]=z; pb[1]=z; pb[2]=z; pb[3]=z; } \
  } while(0)
  GAISSUE(0);
  f32x4 acc[4][4] = {};
  for (int k0 = 0; k0 < K; k0 += 64) {
    const int pbuf = (k0 >> 6) & 1;
#pragma unroll
    for (int q2 = 0; q2 < 8; ++q2) {
      ushort o[4] = { f2bf(fa[q2].x), f2bf(fa[q2].y), f2bf(fa[q2].z), f2bf(fa[q2].w) };
      *(uint2*)&As[pbuf][rowL * 72 + cL + q2 * 4] = *(const uint2*)o;
    }
#pragma unroll
    for (int q2 = 0; q2 < 4; ++q2) *(uint4*)&Bs[pbuf][rowL * 72 + cL + q2 * 8] = pb[q2];
    __syncthreads();
    if (k0 + 64 < K) GAISSUE(k0 + 64);
#pragma unroll
    for (int sub = 0; sub < 2; ++sub) {
      const int ko = lk8 + sub * 32;
      short8 a[4], b[4];
#pragma unroll
      for (int f = 0; f < 4; ++f) {
        a[f] = *(const short8*)&As[pbuf][(wm * 64 + 16 * f + lrow) * 72 + ko];
        b[f] = *(const short8*)&Bs[pbuf][(wn * 64 + 16 * f + lrow) * 72 + ko];
      }
#pragma unroll
      for (int fi = 0; fi < 4; ++fi)
#pragma unroll
        for (int fj = 0; fj < 4; ++fj)
          acc[fi][fj] = __builtin_amdgcn_mfma_f32_16x16x32_bf16(a[fi], b[fj], acc[fi][fj], 0, 0, 0);
    }
  }
#pragma unroll
  for (int fi = 0; fi < 4; ++fi) {
    int row0 = m0 + wm * 64 + 16 * fi + (lane >> 4) * 4;
#pragma unroll
    for (int fj = 0; fj < 4; ++fj) {
      int col = n0 + wn * 64 + 16 * fj + lrow;
      if (col < N)
#pragma unroll
        for (int rr = 0; rr < 4; ++rr)
          C[(size_t)(row0 + rr) * N + col] = acc[fi][fj][rr];
    }
  }
}

// ---------------- fused input GEMMs: z=0 skipxs (12x16), z=1 bcdt (3x16) ----------------
__global__ __launch_bounds__(256) void k_gemm_in(
    const float* __restrict__ u1, const float* __restrict__ u2,
    const float* __restrict__ uc1, const float* __restrict__ uc2,
    const ushort* __restrict__ WsxT, const ushort* __restrict__ WbcdtT,
    float* __restrict__ skipxs, float* __restrict__ bc_pre)
{
  __shared__ __align__(16) ushort As[2][128 * 72];
  __shared__ __align__(16) ushort Bs[2][128 * 72];
  if (blockIdx.z == 0) {
    gemm_f32a_body(As, Bs, u1, u2, 1024, WsxT, skipxs, 1536, 384);
  } else {
    if (blockIdx.x >= 3) return;
    gemm_f32a_body(As, Bs, uc1, uc2, 1024, WbcdtT, bc_pre, 264, 384);
  }
}

// ---------------- depthwise 3x3 conv + bias + SiLU; writes xbcT[s][m][c] ----------------
__global__ __launch_bounds__(256) void k_conv(
    const float* __restrict__ skipxs, const float* __restrict__ bc_pre,
    const float* __restrict__ wxs, const float* __restrict__ bxs,
    const float* __restrict__ wbc, const float* __restrict__ bbc,
    float* __restrict__ xbcT)
{
  const int m = blockIdx.x, s = blockIdx.y;
  const int h = m >> 5, w = m & 31;
  const float* xp = skipxs + (size_t)s * LSEQ * 1536 + 1024;
  const float* bp = bc_pre + (size_t)s * LSEQ * CBCDT;
  for (int c = threadIdx.x; c < CTOT; c += 256) {
    const float* src; int stride; const float* wt; float bias;
    if (c < DSSM) { src = xp + c; stride = 1536; wt = wxs + (size_t)c * 9; bias = bxs[c]; }
    else { int cb = c - DSSM; src = bp + cb; stride = CBCDT; wt = wbc + (size_t)cb * 9; bias = bbc[cb]; }
    float acc = bias;
#pragma unroll
    for (int dh = -1; dh <= 1; ++dh) {
      int h2 = h + dh; if (h2 < 0 || h2 > 31) continue;
#pragma unroll
      for (int dw = -1; dw <= 1; ++dw) {
        int w2 = w + dw; if (w2 < 0 || w2 > 31) continue;
        acc += src[(size_t)(h2 * 32 + w2) * stride] * wt[(dh + 1) * 3 + (dw + 1)];
      }
    }
    xbcT[((size_t)s * LSEQ + m) * CTOT + c] = siluf(acc);
  }
}

// ---------------- fused gathers: [0,512) Xh, [512,576) B/C/BT, [576,592) dA+cumsum ----------------
__global__ __launch_bounds__(256) void k_gather_all(
    const float* __restrict__ xbcT, const float* __restrict__ dt_bias,
    const float* __restrict__ A_logs,
    ushort* __restrict__ XhT, ushort* __restrict__ Bbf, ushort* __restrict__ Cbf,
    ushort* __restrict__ BT, float* __restrict__ dAcs)
{
  __shared__ __align__(16) ushort U[128 * 72];
  const int bid = blockIdx.x, s = blockIdx.y, t = threadIdx.x;
  if (bid < 512) {
    const int lt = bid & 15, kh = bid >> 4;
    const int k = kh >> 3, hh = kh & 7;
    const int r = t >> 2, q = t & 3;
    const int l = lt * 64 + r;
    const int m = dir_src(k, l);
    const float* row = xbcT + ((size_t)s * LSEQ + m) * CTOT;
    float dtv = softplusf(row[768 + hh] + dt_bias[kh]);
    const float* xp = row + hh * 64 + q * 16;
#pragma unroll
    for (int i = 0; i < 16; ++i)
      U[(q * 16 + i) * 72 + r] = f2bf(xp[i] * dtv);
    __syncthreads();
    ushort* dst = XhT + (((size_t)s * HK + kh) * HD + r) * LSEQ + lt * 64 + q * 16;
    *(uint4*)dst       = *(const uint4*)&U[r * 72 + q * 16];
    *(uint4*)(dst + 8) = *(const uint4*)&U[r * 72 + q * 16 + 8];
    return;
  }
  if (bid < 576) {
    const int idx = bid - 512;
    const int lt = idx & 15, k = idx >> 4;
    const int r = t >> 2, q = t & 3;
    const int l = lt * 64 + r;
    const int m = dir_src(k, l);
    const float* row = xbcT + ((size_t)s * LSEQ + m) * CTOT;
    {
      const float* bsrc = row + 512 + q * 32;
      ushort ub[32];
#pragma unroll
      for (int i2 = 0; i2 < 8; ++i2) {
        float4 v = *(const float4*)(bsrc + i2 * 4);
        ub[i2 * 4 + 0] = f2bf(v.x); ub[i2 * 4 + 1] = f2bf(v.y);
        ub[i2 * 4 + 2] = f2bf(v.z); ub[i2 * 4 + 3] = f2bf(v.w);
      }
      ushort* bd = Bbf + ((size_t)s * LSEQ + l) * NSTATE + k * 128 + q * 32;
#pragma unroll
      for (int i2 = 0; i2 < 4; ++i2) *(uint4*)(bd + i2 * 8) = *(const uint4*)&ub[i2 * 8];
#pragma unroll
      for (int i = 0; i < 32; ++i) U[(q * 32 + i) * 72 + r] = ub[i];
    }
    {
      const float* csrc = row + 640 + q * 32;
      ushort uc[32];
#pragma unroll
      for (int i2 = 0; i2 < 8; ++i2) {
        float4 v = *(const float4*)(csrc + i2 * 4);
        uc[i2 * 4 + 0] = f2bf(v.x); uc[i2 * 4 + 1] = f2bf(v.y);
        uc[i2 * 4 + 2] = f2bf(v.z); uc[i2 * 4 + 3] = f2bf(v.w);
      }
      ushort* cd = Cbf + ((size_t)s * LSEQ + l) * NSTATE + k * 128 + q * 32;
#pragma unroll
      for (int i2 = 0; i2 < 4; ++i2) *(uint4*)(cd + i2 * 8) = *(const uint4*)&uc[i2 * 8];
    }
    __syncthreads();
    {
      const int n = t >> 1, half = t & 1;
      ushort* dst = BT + ((size_t)s * NSTATE + k * 128 + n) * LSEQ + lt * 64 + half * 32;
      const ushort* src = &U[n * 72 + half * 32];
#pragma unroll
      for (int i2 = 0; i2 < 4; ++i2) *(uint4*)(dst + i2 * 8) = *(const uint4*)(src + i2 * 8);
    }
    return;
  }
  {
    float* Lf = (float*)U;
    const int idx = bid - 576;
    const int z = idx & 3, k = idx >> 2;
    const int m = dir_src(k, z * 256 + t);
    const float* rowdt = xbcT + ((size_t)s * LSEQ + m) * CTOT + 768;
    float4 d0 = *(const float4*)rowdt;
    float4 d1 = *(const float4*)(rowdt + 4);
    float dv[8] = { d0.x, d0.y, d0.z, d0.w, d1.x, d1.y, d1.z, d1.w };
#pragma unroll
    for (int hh = 0; hh < 8; ++hh) {
      int kh = k * 8 + hh;
      float dAv = softplusf(dv[hh] + dt_bias[kh]) * (-expf(A_logs[kh]));
      Lf[hh * 256 + t] = dAv;
    }
    __syncthreads();
    const int hh = t >> 5, seg = t & 31;
    float p[8]; float run = 0.f;
#pragma unroll
    for (int i = 0; i < 8; ++i) { run += Lf[hh * 256 + seg * 8 + i]; p[i] = run; }
    float sc = run, tot = run;
#pragma unroll
    for (int d = 1; d < 32; d <<= 1) {
      float o = __shfl_up(sc, d, 32);
      if (seg >= d) sc += o;
    }
    float off = sc - tot;
    float* dst = dAcs + ((size_t)s * HK + k * 8 + hh) * LSEQ + z * 256 + seg * 8;
#pragma unroll
    for (int i = 0; i < 8; ++i) dst[i] = p[i] + off;
  }
}

// ---------------- fused scan core: [0,80) CB lower-tri, [80,592) states+scan (LDS dbuf) ----------------
__global__ __launch_bounds__(256) void k_scan_core(
    const ushort* __restrict__ Cbf, const ushort* __restrict__ Bbf, ushort* __restrict__ CBbf,
    const ushort* __restrict__ BT, const ushort* __restrict__ XhT,
    const float* __restrict__ dAcs, ushort* __restrict__ prevP)
{
  __shared__ __align__(16) ushort As[2][64 * 72];
  __shared__ __align__(16) ushort Bs[2][64 * 72];
  __shared__ __align__(16) ushort Tr[64 * 72];
  __shared__ float decay[CHUNKSZ];
  const int bid = blockIdx.x, t = threadIdx.x;
  const int lane = t & 63, wv = t >> 6;
  const int lrow = lane & 15, lk8 = (lane >> 4) * 8;
  const int rA = t >> 2, cA = (t & 3) * 16;

  if (bid < 80) {
    // CB = C @ B^T, lower-triangular 64x64 tiles only (jt <= it)
    const int sz = bid & 7, pidx = bid >> 3, s = sz >> 2, z = sz & 3;
    int it = 0; { while ((it + 1) * (it + 2) / 2 <= pidx) ++it; }
    const int jt = pidx - it * (it + 1) / 2;
    const ushort* Ap = Cbf + ((size_t)s * LSEQ + z * CHUNKSZ + it * 64 + rA) * NSTATE + cA;
    const ushort* Bp = Bbf + ((size_t)s * LSEQ + z * CHUNKSZ + jt * 64 + rA) * NSTATE + cA;
    uint4 qa[2], qb[2];
#define CBISSUE(k0) do { qa[0]=*(const uint4*)(Ap+(k0)); qa[1]=*(const uint4*)(Ap+(k0)+8); \
                         qb[0]=*(const uint4*)(Bp+(k0)); qb[1]=*(const uint4*)(Bp+(k0)+8); } while(0)
    CBISSUE(0);
    f32x4 acc[4] = {};
    for (int k0 = 0; k0 < NSTATE; k0 += 64) {
      const int pb2 = (k0 >> 6) & 1;
      *(uint4*)&As[pb2][rA * 72 + cA] = qa[0]; *(uint4*)&As[pb2][rA * 72 + cA + 8] = qa[1];
      *(uint4*)&Bs[pb2][rA * 72 + cA] = qb[0]; *(uint4*)&Bs[pb2][rA * 72 + cA + 8] = qb[1];
      __syncthreads();
      if (k0 + 64 < NSTATE) CBISSUE(k0 + 64);
#pragma unroll
      for (int sub = 0; sub < 2; ++sub) {
        const int ko = lk8 + sub * 32;
        short8 a = *(const short8*)&As[pb2][(16 * wv + lrow) * 72 + ko];
#pragma unroll
        for (int fj = 0; fj < 4; ++fj) {
          short8 b = *(const short8*)&Bs[pb2][(16 * fj + lrow) * 72 + ko];
          acc[fj] = __builtin_amdgcn_mfma_f32_16x16x32_bf16(a, b, acc[fj], 0, 0, 0);
        }
      }
    }
    ushort* Cp = CBbf + (size_t)sz * CHUNKSZ * CHUNKSZ;
    const int row0 = it * 64 + 16 * wv + (lane >> 4) * 4;
#pragma unroll
    for (int fj = 0; fj < 4; ++fj) {
      int col = jt * 64 + 16 * fj + lrow;
#pragma unroll
      for (int rr = 0; rr < 4; ++rr)
        Cp[(size_t)(row0 + rr) * CHUNKSZ + col] = f2bf(acc[fj][rr]);
    }
    return;
  }

  // states + inter-chunk scan -> prevP
  {
    const int idx = bid - 80;
    const int nh = idx & 7, kh = (idx >> 3) & 31, s = idx >> 8;
    const float* dA = dAcs + ((size_t)s * HK + kh) * LSEQ;
    float carry[4][4];
#pragma unroll
    for (int fj = 0; fj < 4; ++fj)
#pragma unroll
      for (int rr = 0; rr < 4; ++rr) carry[fj][rr] = 0.f;

    for (int z = 0; z < NC; ++z) {
      __syncthreads();
      const float dlast = dA[z * CHUNKSZ + CHUNKSZ - 1];
      decay[t] = __expf(dlast - dA[z * CHUNKSZ + t]);
      {
        const int n_base = 16 * wv + (lane >> 4) * 4;
#pragma unroll
        for (int fj = 0; fj < 4; ++fj) {
          const int p = 16 * fj + lrow;
#pragma unroll
          for (int rr = 0; rr < 4; ++rr)
            Tr[p * 72 + n_base + rr] = f2bf(carry[fj][rr]);
        }
      }
      __syncthreads();
      {
        const int sz = s * 4 + z;
        ushort* dst = prevP + (((size_t)sz * HK + kh) * HD + rA) * NSTATE + nh * 64 + cA;
        *(uint4*)dst       = *(const uint4*)&Tr[rA * 72 + cA];
        *(uint4*)(dst + 8) = *(const uint4*)&Tr[rA * 72 + cA + 8];
      }
      const ushort* Ap = BT + ((size_t)s * NSTATE + nh * 64 + rA) * LSEQ + z * CHUNKSZ + cA;
      const ushort* Xp = XhT + (((size_t)s * HK + kh) * HD + rA) * LSEQ + z * CHUNKSZ + cA;
      uint4 qa[2], qb[2];
#define SSISSUE(k0) do { qa[0]=*(const uint4*)(Ap+(k0)); qa[1]=*(const uint4*)(Ap+(k0)+8); \
                         qb[0]=*(const uint4*)(Xp+(k0)); qb[1]=*(const uint4*)(Xp+(k0)+8); } while(0)
      SSISSUE(0);
      f32x4 acc[4] = {};
      for (int k0 = 0; k0 < CHUNKSZ; k0 += 64) {
        const int pb2 = (k0 >> 6) & 1;
        *(uint4*)&As[pb2][rA * 72 + cA] = qa[0]; *(uint4*)&As[pb2][rA * 72 + cA + 8] = qa[1];
        {
          ushort tmp[16];
          *(uint4*)&tmp[0] = qb[0]; *(uint4*)&tmp[8] = qb[1];
#pragma unroll
          for (int i2 = 0; i2 < 8; ++i2) {
            int c = k0 + cA + 2 * i2;
            unsigned wpk = (unsigned)f2bf(bf2f(tmp[2 * i2]) * decay[c]) |
                           ((unsigned)f2bf(bf2f(tmp[2 * i2 + 1]) * decay[c + 1]) << 16);
            *(unsigned*)&Bs[pb2][rA * 72 + cA + 2 * i2] = wpk;
          }
        }
        __syncthreads();
        if (k0 + 64 < CHUNKSZ) SSISSUE(k0 + 64);
#pragma unroll
        for (int sub = 0; sub < 2; ++sub) {
          const int ko = lk8 + sub * 32;
          short8 a = *(const short8*)&As[pb2][(16 * wv + lrow) * 72 + ko];
#pragma unroll
          for (int fj = 0; fj < 4; ++fj) {
            short8 b = *(const short8*)&Bs[pb2][(16 * fj + lrow) * 72 + ko];
            acc[fj] = __builtin_amdgcn_mfma_f32_16x16x32_bf16(a, b, acc[fj], 0, 0, 0);
          }
        }
      }
      const float cdec = __expf(dlast);
#pragma unroll
      for (int fj = 0; fj < 4; ++fj)
#pragma unroll
        for (int rr = 0; rr < 4; ++rr)
          carry[fj][rr] = carry[fj][rr] * cdec + acc[fj][rr];
    }
  }
}

// ---------------- Y = Ydiag + Yoff (MFMA, LDS dbuf, bf16 out) ----------------
// z==0 blocks skip phase A entirely: prev state is identically zero.
__global__ __launch_bounds__(256) void k_y_mfma(
    const ushort* __restrict__ CBbf, const ushort* __restrict__ XhT,
    const ushort* __restrict__ Cbf, const ushort* __restrict__ prevP,
    const float* __restrict__ dAcs, ushort* __restrict__ Ybf)
{
  __shared__ __align__(16) ushort As[2][128 * 72];
  __shared__ __align__(16) ushort Bs[2][64 * 72];
  __shared__ float seg[CHUNKSZ];
  __shared__ float f2s[CHUNKSZ];
  const int it = blockIdx.x, kh = blockIdx.y, sz = blockIdx.z, s = sz >> 2, z = sz & 3;
  const int t = threadIdx.x, lane = t & 63, wv = t >> 6;
  const int lrow = lane & 15, lk8 = (lane >> 4) * 8;
  const int i0 = it * 128;
  const float* dAp = dAcs + ((size_t)s * HK + kh) * LSEQ + z * CHUNKSZ;
  seg[t] = dAp[t];
  __syncthreads();
  f2s[t] = __expf(seg[(t >> 5) << 5] - seg[t]);
  __syncthreads();

  const int rA = t >> 1, cA = (t & 1) * 32;
  const int rB = t >> 2, cB = (t & 3) * 16;
  f32x4 acc[2][4] = {};
  uint4 qa[4], qb[2];

  // phase A: acc = C @ prev^T  (skip for z==0: prev == 0)
  if (z != 0) {
    const ushort* Cp = Cbf + ((size_t)s * LSEQ + z * CHUNKSZ + i0 + rA) * NSTATE + cA;
    const ushort* Pp = prevP + (((size_t)sz * HK + kh) * HD + rB) * NSTATE + cB;
#define YISSUEA(k0) do { \
    qa[0]=*(const uint4*)(Cp+(k0));    qa[1]=*(const uint4*)(Cp+(k0)+8); \
    qa[2]=*(const uint4*)(Cp+(k0)+16); qa[3]=*(const uint4*)(Cp+(k0)+24); \
    qb[0]=*(const uint4*)(Pp+(k0));    qb[1]=*(const uint4*)(Pp+(k0)+8); } while(0)
    YISSUEA(0);
    for (int k0 = 0; k0 < NSTATE; k0 += 64) {
      const int pb2 = (k0 >> 6) & 1;
#pragma unroll
      for (int q2 = 0; q2 < 4; ++q2) *(uint4*)&As[pb2][rA * 72 + cA + q2 * 8] = qa[q2];
      *(uint4*)&Bs[pb2][rB * 72 + cB] = qb[0]; *(uint4*)&Bs[pb2][rB * 72 + cB + 8] = qb[1];
      __syncthreads();
      if (k0 + 64 < NSTATE) YISSUEA(k0 + 64);
#pragma unroll
      for (int sub = 0; sub < 2; ++sub) {
        const int ko = lk8 + sub * 32;
        short8 a[2], b[4];
#pragma unroll
        for (int f = 0; f < 2; ++f) a[f] = *(const short8*)&As[pb2][(32 * wv + 16 * f + lrow) * 72 + ko];
#pragma unroll
        for (int f = 0; f < 4; ++f) b[f] = *(const short8*)&Bs[pb2][(16 * f + lrow) * 72 + ko];
#pragma unroll
        for (int fi = 0; fi < 2; ++fi)
#pragma unroll
          for (int fj = 0; fj < 4; ++fj)
            acc[fi][fj] = __builtin_amdgcn_mfma_f32_16x16x32_bf16(a[fi], b[fj], acc[fi][fj], 0, 0, 0);
      }
    }
  }

  // prefetch phase-B tile 0 while rescaling
  const ushort* CBp = CBbf + ((size_t)sz * CHUNKSZ + i0 + rA) * CHUNKSZ;
  const ushort* Xp = XhT + (((size_t)s * HK + kh) * HD + rB) * LSEQ + z * CHUNKSZ + cB;
  const int nktB = 2 * it + 2;
#define YISSUEB(kt) do { const ushort* sa = CBp + (kt) * 64 + cA; \
    qa[0]=*(const uint4*)sa;      qa[1]=*(const uint4*)(sa+8); \
    qa[2]=*(const uint4*)(sa+16); qa[3]=*(const uint4*)(sa+24); \
    qb[0]=*(const uint4*)(Xp+(kt)*64); qb[1]=*(const uint4*)(Xp+(kt)*64+8); } while(0)
  YISSUEB(0);

  // scale Yoff rows by e^{seg_i}
  if (z != 0) {
#pragma unroll
    for (int fi = 0; fi < 2; ++fi) {
      int rloc = 32 * wv + 16 * fi + (lane >> 4) * 4;
#pragma unroll
      for (int rr = 0; rr < 4; ++rr) {
        float e = __expf(seg[i0 + rloc + rr]);
#pragma unroll
        for (int fj = 0; fj < 4; ++fj) acc[fi][fj][rr] *= e;
      }
    }
  }

  // phase A ended on buffer pb2=1 (or never ran); phase B starts on buffer 0 -> safe.
  // phase B: Ydiag (slice-factored, CB bf16)
  for (int kt = 0; kt < nktB; ++kt) {
    const int pb2 = kt & 1;
    {
      const int i = i0 + rA;
      const int jbase = kt * 64 + cA;
      if (i >= jbase) {
        float f1 = __expf(seg[i] - seg[jbase]);
        ushort tmp[32];
        *(uint4*)&tmp[0] = qa[0]; *(uint4*)&tmp[8] = qa[1];
        *(uint4*)&tmp[16] = qa[2]; *(uint4*)&tmp[24] = qa[3];
#pragma unroll
        for (int c = 0; c < 32; c += 2) {
          int j = jbase + c;
          float v0 = (j     <= i) ? bf2f(tmp[c])     * f1 : 0.f;
          float v1 = (j + 1 <= i) ? bf2f(tmp[c + 1]) * f1 : 0.f;
          *(unsigned*)&As[pb2][rA * 72 + cA + c] = (unsigned)f2bf(v0) | ((unsigned)f2bf(v1) << 16);
        }
      } else {
        uint4 zz = {0, 0, 0, 0};
#pragma unroll
        for (int q2 = 0; q2 < 4; ++q2) *(uint4*)&As[pb2][rA * 72 + cA + q2 * 8] = zz;
      }
    }
    {
      ushort tmp[16];
      *(uint4*)&tmp[0] = qb[0]; *(uint4*)&tmp[8] = qb[1];
#pragma unroll
      for (int i2 = 0; i2 < 8; ++i2) {
        int j = kt * 64 + cB + 2 * i2;
        unsigned wpk = (unsigned)f2bf(bf2f(tmp[2 * i2]) * f2s[j]) |
                       ((unsigned)f2bf(bf2f(tmp[2 * i2 + 1]) * f2s[j + 1]) << 16);
        *(unsigned*)&Bs[pb2][rB * 72 + cB + 2 * i2] = wpk;
      }
    }
    __syncthreads();
    if (kt + 1 < nktB) YISSUEB(kt + 1);
#pragma unroll
    for (int sub = 0; sub < 2; ++sub) {
      if (2 * kt + sub <= 4 * it + wv) {
        const int ko = lk8 + sub * 32;
        short8 a[2], b[4];
#pragma unroll
        for (int f = 0; f < 2; ++f) a[f] = *(const short8*)&As[pb2][(32 * wv + 16 * f + lrow) * 72 + ko];
#pragma unroll
        for (int f = 0; f < 4; ++f) b[f] = *(const short8*)&Bs[pb2][(16 * f + lrow) * 72 + ko];
#pragma unroll
        for (int fi = 0; fi < 2; ++fi)
#pragma unroll
          for (int fj = 0; fj < 4; ++fj)
            acc[fi][fj] = __builtin_amdgcn_mfma_f32_16x16x32_bf16(a[fi], b[fj], acc[fi][fj], 0, 0, 0);
      }
    }
  }

  ushort* Yp = Ybf + (((size_t)s * LSEQ + z * CHUNKSZ + i0) * HK + kh) * HD;
#pragma unroll
  for (int fi = 0; fi < 2; ++fi) {
    int row0 = 32 * wv + 16 * fi + (lane >> 4) * 4;
#pragma unroll
    for (int fj = 0; fj < 4; ++fj) {
      int col = 16 * fj + lrow;
#pragma unroll
      for (int rr = 0; rr < 4; ++rr)
        Yp[(size_t)(row0 + rr) * (HK * HD) + col] = f2bf(acc[fi][fj][rr]);
    }
  }
}

// ---------------- combine 4 directions + D*x + gated RMSNorm + MLP half (bf16 out) ----------------
__global__ __launch_bounds__(256) void k_combine(
    const ushort* __restrict__ Ybf, const float* __restrict__ xbcT,
    const float* __restrict__ skipxs, const float* __restrict__ Ds,
    const float* __restrict__ normw, ushort* __restrict__ o768bf)
{
  const int m = blockIdx.x, s = blockIdx.y, t = threadIdx.x;
  const int h = m >> 5, w = m & 31;
  const int l0 = m, l1 = (w << 5) | h, l2 = 1023 - m, l3 = 1023 - ((w << 5) | h);
  const ushort* Yb = Ybf + (size_t)s * LSEQ * (HK * HD);
  const float* xrow = xbcT + ((size_t)s * LSEQ + m) * CTOT;
  const float* srow = skipxs + ((size_t)s * LSEQ + m) * 1536;

  float g[2];
  float ss = 0.f;
#pragma unroll
  for (int q = 0; q < 2; ++q) {
    int d = t + q * 256;
    int hh = d >> 6, p = d & 63;
    float dsum = Ds[hh] + Ds[hh + 8] + Ds[hh + 16] + Ds[hh + 24];
    float val = bf2f(Yb[((size_t)l0 * HK + hh) * HD + p])
              + bf2f(Yb[((size_t)l1 * HK + 8 + hh) * HD + p])
              + bf2f(Yb[((size_t)l2 * HK + 16 + hh) * HD + p])
              + bf2f(Yb[((size_t)l3 * HK + 24 + hh) * HD + p])
              + xrow[d] * dsum;
    float zv = srow[512 + d];
    g[q] = val * siluf(zv);
    ss += g[q] * g[q];
  }
  for (int off = 32; off > 0; off >>= 1) ss += __shfl_down(ss, off, 64);
  __shared__ float red[4];
  if ((t & 63) == 0) red[t >> 6] = ss;
  __syncthreads();
  float total = red[0] + red[1] + red[2] + red[3];
  float scale = rsqrtf(total * (1.f / 512.f) + 1e-5f);

  ushort* orow = o768bf + ((size_t)s * LSEQ + m) * 768;
#pragma unroll
  for (int q = 0; q < 2; ++q) {
    int d = t + q * 256;
    orow[256 + d] = f2bf(g[q] * scale * normw[d]);
  }
  float z0 = srow[t], x0 = srow[256 + t];
  orow[t] = f2bf(siluf(z0) * x0);
}

// ---------------- 64x64-tile bf16 GEMM (out GEMM), LDS dbuf ----------------
__global__ __launch_bounds__(256) void gemm64_bf16(
    const ushort* __restrict__ A, const ushort* __restrict__ BT,
    float* __restrict__ C, int M, int N, int K)
{
  __shared__ __align__(16) ushort As[2][64 * 72];
  __shared__ __align__(16) ushort Bs[2][64 * 72];
  const int n0 = blockIdx.x * 64, m0 = blockIdx.y * 64;
  const int t = threadIdx.x, lane = t & 63, wv = t >> 6;
  const int wm = wv & 1, wn = wv >> 1;
  const int lrow = lane & 15, lk8 = (lane >> 4) * 8;
  const int rowL = t >> 2, cL = (t & 3) * 16;
  const ushort* pa_src = A + (size_t)(m0 + rowL) * K + cL;
  const int nB = n0 + rowL;
  const ushort* pb_src = BT + (size_t)nB * K + cL;
  const bool bval = (nB < N);
  uint4 pa[2], pb[2];
#define G64ISSUE(k0) do { \
    pa[0]=*(const uint4*)(pa_src+(k0)); pa[1]=*(const uint4*)(pa_src+(k0)+8); \
    if (bval) { pb[0]=*(const uint4*)(pb_src+(k0)); pb[1]=*(const uint4*)(pb_src+(k0)+8); } \
    else { uint4 z={0,0,0,0}; pb[0]=z; pb[1]=z; } } while(0)
  G64ISSUE(0);
  f32x4 acc[2][2] = {};
  for (int k0 = 0; k0 < K; k0 += 64) {
    const int pbuf = (k0 >> 6) & 1;
    *(uint4*)&As[pbuf][rowL * 72 + cL] = pa[0]; *(uint4*)&As[pbuf][rowL * 72 + cL + 8] = pa[1];
    *(uint4*)&Bs[pbuf][rowL * 72 + cL] = pb[0]; *(uint4*)&Bs[pbuf][rowL * 72 + cL + 8] = pb[1];
    __syncthreads();
    if (k0 + 64 < K) G64ISSUE(k0 + 64);
#pragma unroll
    for (int sub = 0; sub < 2; ++sub) {
      const int ko = lk8 + sub * 32;
      short8 a[2], b[2];
#pragma unroll
      for (int f = 0; f < 2; ++f) {
        a[f] = *(const short8*)&As[pbuf][(wm * 32 + 16 * f + lrow) * 72 + ko];
        b[f] = *(const short8*)&Bs[pbuf][(wn * 32 + 16 * f + lrow) * 72 + ko];
      }
#pragma unroll
      for (int fi = 0; fi < 2; ++fi)
#pragma unroll
        for (int fj = 0; fj < 2; ++fj)
          acc[fi][fj] = __builtin_amdgcn_mfma_f32_16x16x32_bf16(a[fi], b[fj], acc[fi][fj], 0, 0, 0);
    }
  }
#pragma unroll
  for (int fi = 0; fi < 2; ++fi) {
    int row0 = m0 + wm * 32 + 16 * fi + (lane >> 4) * 4;
#pragma unroll
    for (int fj = 0; fj < 2; ++fj) {
      int col = n0 + wn * 32 + 16 * fj + lrow;
      if (col < N)
#pragma unroll
        for (int rr = 0; rr < 4; ++rr)
          C[(size_t)(row0 + rr) * N + col] = acc[fi][fj][rr];
    }
  }
}

// ---------------- workspace layout (float units) ----------------
constexpr size_t OFF_SKIPXS = 0;                         // 2048*1536 f32 = 3145728
constexpr size_t OFF_XBCT   = 3145728;                   // 1589248
constexpr size_t OFF_XHT    = OFF_XBCT + 1589248;        // bf16 -> 2097152 f
constexpr size_t OFF_BBF    = OFF_XHT + 2097152;         // 524288
constexpr size_t OFF_CBF    = OFF_BBF + 524288;          // 524288
constexpr size_t OFF_BTBF   = OFF_CBF + 524288;          // 524288
constexpr size_t OFF_DA     = OFF_BTBF + 524288;         // 65536
constexpr size_t OFF_CB     = OFF_DA + 65536;            // bf16 -> 262144 f
constexpr size_t OFF_PREV   = OFF_CB + 262144;           // bf16 -> 4194304 f
constexpr size_t OFF_Y      = OFF_PREV + 4194304;        // bf16 -> 2097152 f
constexpr size_t OFF_O768   = OFF_Y + 2097152;           // bf16 -> 786432 f
constexpr size_t OFF_WSXT   = OFF_O768 + 786432;         // 294912
constexpr size_t OFF_WBCT   = OFF_WSXT + 294912;         // 50688
constexpr size_t OFF_WOUT   = OFF_WBCT + 50688;          // 147456
constexpr size_t OFF_BCP    = OFF_PREV;                  // overlay: bc_pre (dead before prevP written)

extern "C" void kernel_launch(void* const* d_in, const int* in_sizes, int n_in,
                              void* d_out, int out_size, void* d_ws, size_t ws_size,
                              hipStream_t stream)
{
  const float* u1     = (const float*)d_in[0];
  const float* u2     = (const float*)d_in[1];
  const float* u2c1   = (const float*)d_in[2];
  const float* u1c2   = (const float*)d_in[3];
  const float* W_skip = (const float*)d_in[4];
  const float* W_xs   = (const float*)d_in[5];
  const float* W_bcdt = (const float*)d_in[6];
  const float* cxw    = (const float*)d_in[7];
  const float* cxb    = (const float*)d_in[8];
  const float* cbw    = (const float*)d_in[9];
  const float* cbb    = (const float*)d_in[10];
  const float* Ds     = (const float*)d_in[11];
  const float* normw  = (const float*)d_in[12];
  const float* W_out  = (const float*)d_in[13];
  const float* dt_b   = (const float*)d_in[14];
  const float* A_logs = (const float*)d_in[15];
  float* out = (float*)d_out;
  float* ws  = (float*)d_ws;

  float*  skipxs  = ws + OFF_SKIPXS;
  float*  xbcT    = ws + OFF_XBCT;
  ushort* XhT     = (ushort*)(ws + OFF_XHT);
  ushort* Bbf     = (ushort*)(ws + OFF_BBF);
  ushort* Cbf     = (ushort*)(ws + OFF_CBF);
  ushort* BTbf    = (ushort*)(ws + OFF_BTBF);
  float*  dAcs    = ws + OFF_DA;
  ushort* CBbf    = (ushort*)(ws + OFF_CB);
  ushort* prevP   = (ushort*)(ws + OFF_PREV);
  ushort* Ybf     = (ushort*)(ws + OFF_Y);
  ushort* o768bf  = (ushort*)(ws + OFF_O768);
  ushort* WsxT    = (ushort*)(ws + OFF_WSXT);
  ushort* WbcdtT  = (ushort*)(ws + OFF_WBCT);
  ushort* WoutT   = (ushort*)(ws + OFF_WOUT);
  float*  bc_pre  = ws + OFF_BCP;

  // 1: weight transposes
  k_prep<<<dim3(246), 256, 0, stream>>>(W_skip, W_xs, W_bcdt, W_out, WsxT, WbcdtT, WoutT);
  // 2: both input GEMMs in one launch
  k_gemm_in<<<dim3(12, 16, 2), 256, 0, stream>>>(u1, u2, u2c1, u1c2, WsxT, WbcdtT, skipxs, bc_pre);
  // 3: conv
  k_conv<<<dim3(1024, 2), 256, 0, stream>>>(skipxs, bc_pre, cxw, cxb, cbw, cbb, xbcT);
  // 4: all gathers + cumsum
  k_gather_all<<<dim3(592, 2), 256, 0, stream>>>(xbcT, dt_b, A_logs, XhT, Bbf, Cbf, BTbf, dAcs);
  // 5: CB (lower-tri) + states/scan
  k_scan_core<<<dim3(592), 256, 0, stream>>>(Cbf, Bbf, CBbf, BTbf, XhT, dAcs, prevP);
  // 6: Y (z==0 blocks skip phase A)
  k_y_mfma<<<dim3(2, 32, 8), 256, 0, stream>>>(CBbf, XhT, Cbf, prevP, dAcs, Ybf);
  // 7: combine
  k_combine<<<dim3(1024, 2), 256, 0, stream>>>(Ybf, xbcT, skipxs, Ds, normw, o768bf);
  // 8: out GEMM
  gemm64_bf16<<<dim3(6, 32), 256, 0, stream>>>(o768bf, WoutT, out, 2048, 384, 768);
}

// Round 17
// 112.307 us; speedup vs baseline: 1.3789x; 1.0300x over previous
//
#include <hip/hip_runtime.h>
#include <hip/hip_bf16.h>
#include <cstddef>

// ---------------- problem constants ----------------
#define LSEQ   1024
#define DM     384
#define DSSM   512
#define NSTATE 512
#define HK     32
#define HD     64
#define CHUNKSZ 256
#define NC     4
#define CBCDT  264
#define CTOT   776
#define DMLP   256

typedef __attribute__((ext_vector_type(8))) short short8;
typedef __attribute__((ext_vector_type(4))) float f32x4;

__device__ __forceinline__ float siluf(float x)    { return x / (1.f + expf(-x)); }
__device__ __forceinline__ float softplusf(float x){ return fmaxf(x, 0.f) + log1pf(expf(-fabsf(x))); }

__device__ __forceinline__ ushort f2bf(float f) {
  union { float f; unsigned u; } v; v.f = f;
  unsigned r = v.u + 0x7fffu + ((v.u >> 16) & 1u);
  return (ushort)(r >> 16);
}
__device__ __forceinline__ float bf2f(ushort h) {
  union { unsigned u; float f; } v; v.u = ((unsigned)h) << 16;
  return v.f;
}

__device__ __forceinline__ int dir_src(int k, int l) {
  switch (k) {
    case 0:  return l;
    case 1:  return ((l & 31) << 5) | (l >> 5);
    case 2:  return 1023 - l;
    default: { int lr = 1023 - l; return ((lr & 31) << 5) | (lr >> 5); }
  }
}

// ---------------- weight transpose-casts: grid 246 ----------------
__global__ __launch_bounds__(256) void k_prep(
    const float* __restrict__ W_skip, const float* __restrict__ W_xs,
    const float* __restrict__ W_bcdt, const float* __restrict__ W_out,
    ushort* __restrict__ WsxT, ushort* __restrict__ WbcdtT, ushort* __restrict__ WoutT)
{
  __shared__ __align__(16) ushort T[64 * 72];
  int bid = blockIdx.x;
  const int t = threadIdx.x;
  const float* src; ushort* dst; int N, ldd, nbx;
  if (bid < 96)        {            src = W_skip; dst = WsxT;                     N = 1024; ldd = 384; nbx = 16; }
  else if (bid < 144)  { bid -= 96; src = W_xs;   dst = WsxT + (size_t)1024*384;  N = 512;  ldd = 384; nbx = 8; }
  else if (bid < 174)  { bid -= 144; src = W_bcdt; dst = WbcdtT;                  N = 264;  ldd = 384; nbx = 5; }
  else                 { bid -= 174; src = W_out;  dst = WoutT;                   N = 384;  ldd = 768; nbx = 6; }
  const int n0 = (bid % nbx) * 64, k0 = (bid / nbx) * 64;
  const int rk = t >> 2, q = t & 3;
  const int k = k0 + rk;
  const float* srow = src + (size_t)k * N + n0 + q * 16;
#pragma unroll
  for (int i = 0; i < 16; ++i) {
    int n = n0 + q * 16 + i;
    T[(q * 16 + i) * 72 + rk] = (n < N) ? f2bf(srow[i]) : (ushort)0;
  }
  __syncthreads();
  int n = n0 + rk;
  if (n < N) {
    ushort* d = dst + (size_t)n * ldd + k0 + q * 16;
    *(uint4*)d       = *(const uint4*)&T[rk * 72 + q * 16];
    *(uint4*)(d + 8) = *(const uint4*)&T[rk * 72 + q * 16 + 8];
  }
}

// ---------------- f32-A GEMM body (cast in staging), 128x128 tile, LDS dbuf, bf16 out ----------------
__device__ __forceinline__ void gemm_f32a_body(
    ushort (*As)[128 * 72], ushort (*Bs)[128 * 72],
    const float* __restrict__ A0, const float* __restrict__ A1, int rows0,
    const ushort* __restrict__ BT, ushort* __restrict__ C, int N, int K)
{
  const int n0 = blockIdx.x * 128, m0 = blockIdx.y * 128;
  const int t = threadIdx.x, lane = t & 63, wv = t >> 6;
  const int wm = wv & 1, wn = wv >> 1;
  const int lrow = lane & 15, lk8 = (lane >> 4) * 8;
  const int rowL = t >> 1, cL = (t & 1) * 32;
  const float* Af = (m0 < rows0) ? (A0 + (size_t)m0 * K) : (A1 + (size_t)(m0 - rows0) * K);
  const float* pa_src = Af + (size_t)rowL * K + cL;
  const int nB = n0 + rowL;
  const ushort* pb_src = BT + (size_t)nB * K + cL;
  const bool bval = (nB < N);
  float4 fa[8]; uint4 pb[4];
#define GAISSUE(k0) do { \
    _Pragma("unroll") for (int q2 = 0; q2 < 8; ++q2) fa[q2] = *(const float4*)(pa_src + (k0) + q2 * 4); \
    if (bval) { \
      pb[0] = *(const uint4*)(pb_src + (k0));      pb[1] = *(const uint4*)(pb_src + (k0) + 8); \
      pb[2] = *(const uint4*)(pb_src + (k0) + 16); pb[3] = *(const uint4*)(pb_src + (k0) + 24); \
    } else { uint4 z = {0,0,0,0}; pb[0]=z; pb[1]=z; pb[2]=z; pb[3]=z; } \
  } while(0)
  GAISSUE(0);
  f32x4 acc[4][4] = {};
  for (int k0 = 0; k0 < K; k0 += 64) {
    const int pbuf = (k0 >> 6) & 1;
#pragma unroll
    for (int q2 = 0; q2 < 8; ++q2) {
      ushort o[4] = { f2bf(fa[q2].x), f2bf(fa[q2].y), f2bf(fa[q2].z), f2bf(fa[q2].w) };
      *(uint2*)&As[pbuf][rowL * 72 + cL + q2 * 4] = *(const uint2*)o;
    }
#pragma unroll
    for (int q2 = 0; q2 < 4; ++q2) *(uint4*)&Bs[pbuf][rowL * 72 + cL + q2 * 8] = pb[q2];
    __syncthreads();
    if (k0 + 64 < K) GAISSUE(k0 + 64);
#pragma unroll
    for (int sub = 0; sub < 2; ++sub) {
      const int ko = lk8 + sub * 32;
      short8 a[4], b[4];
#pragma unroll
      for (int f = 0; f < 4; ++f) {
        a[f] = *(const short8*)&As[pbuf][(wm * 64 + 16 * f + lrow) * 72 + ko];
        b[f] = *(const short8*)&Bs[pbuf][(wn * 64 + 16 * f + lrow) * 72 + ko];
      }
#pragma unroll
      for (int fi = 0; fi < 4; ++fi)
#pragma unroll
        for (int fj = 0; fj < 4; ++fj)
          acc[fi][fj] = __builtin_amdgcn_mfma_f32_16x16x32_bf16(a[fi], b[fj], acc[fi][fj], 0, 0, 0);
    }
  }
#pragma unroll
  for (int fi = 0; fi < 4; ++fi) {
    int row0 = m0 + wm * 64 + 16 * fi + (lane >> 4) * 4;
#pragma unroll
    for (int fj = 0; fj < 4; ++fj) {
      int col = n0 + wn * 64 + 16 * fj + lrow;
      if (col < N)
#pragma unroll
        for (int rr = 0; rr < 4; ++rr)
          C[(size_t)(row0 + rr) * N + col] = f2bf(acc[fi][fj][rr]);
    }
  }
}

// ---------------- fused input GEMMs: z=0 skipxs (12x16), z=1 bcdt (3x16) ----------------
__global__ __launch_bounds__(256) void k_gemm_in(
    const float* __restrict__ u1, const float* __restrict__ u2,
    const float* __restrict__ uc1, const float* __restrict__ uc2,
    const ushort* __restrict__ WsxT, const ushort* __restrict__ WbcdtT,
    ushort* __restrict__ skipxs, ushort* __restrict__ bc_pre)
{
  __shared__ __align__(16) ushort As[2][128 * 72];
  __shared__ __align__(16) ushort Bs[2][128 * 72];
  if (blockIdx.z == 0) {
    gemm_f32a_body(As, Bs, u1, u2, 1024, WsxT, skipxs, 1536, 384);
  } else {
    if (blockIdx.x >= 3) return;
    gemm_f32a_body(As, Bs, uc1, uc2, 1024, WbcdtT, bc_pre, 264, 384);
  }
}

// ---------------- depthwise 3x3 conv + bias + SiLU; bf16 in/out; writes xbcT[s][m][c] ----------------
__global__ __launch_bounds__(256) void k_conv(
    const ushort* __restrict__ skipxs, const ushort* __restrict__ bc_pre,
    const float* __restrict__ wxs, const float* __restrict__ bxs,
    const float* __restrict__ wbc, const float* __restrict__ bbc,
    ushort* __restrict__ xbcT)
{
  const int m = blockIdx.x, s = blockIdx.y;
  const int h = m >> 5, w = m & 31;
  const ushort* xp = skipxs + (size_t)s * LSEQ * 1536 + 1024;
  const ushort* bp = bc_pre + (size_t)s * LSEQ * CBCDT;
  for (int c = threadIdx.x; c < CTOT; c += 256) {
    const ushort* src; int stride; const float* wt; float bias;
    if (c < DSSM) { src = xp + c; stride = 1536; wt = wxs + (size_t)c * 9; bias = bxs[c]; }
    else { int cb = c - DSSM; src = bp + cb; stride = CBCDT; wt = wbc + (size_t)cb * 9; bias = bbc[cb]; }
    float acc = bias;
#pragma unroll
    for (int dh = -1; dh <= 1; ++dh) {
      int h2 = h + dh; if (h2 < 0 || h2 > 31) continue;
#pragma unroll
      for (int dw = -1; dw <= 1; ++dw) {
        int w2 = w + dw; if (w2 < 0 || w2 > 31) continue;
        acc += bf2f(src[(size_t)(h2 * 32 + w2) * stride]) * wt[(dh + 1) * 3 + (dw + 1)];
      }
    }
    xbcT[((size_t)s * LSEQ + m) * CTOT + c] = f2bf(siluf(acc));
  }
}

// ---------------- fused gathers (bf16 xbcT): [0,512) Xh, [512,576) B/C/BT, [576,592) dA+cumsum ----------------
__global__ __launch_bounds__(256) void k_gather_all(
    const ushort* __restrict__ xbcT, const float* __restrict__ dt_bias,
    const float* __restrict__ A_logs,
    ushort* __restrict__ XhT, ushort* __restrict__ Bbf, ushort* __restrict__ Cbf,
    ushort* __restrict__ BT, float* __restrict__ dAcs)
{
  __shared__ __align__(16) ushort U[128 * 72];
  const int bid = blockIdx.x, s = blockIdx.y, t = threadIdx.x;
  if (bid < 512) {
    const int lt = bid & 15, kh = bid >> 4;
    const int k = kh >> 3, hh = kh & 7;
    const int r = t >> 2, q = t & 3;
    const int l = lt * 64 + r;
    const int m = dir_src(k, l);
    const ushort* row = xbcT + ((size_t)s * LSEQ + m) * CTOT;
    float dtv = softplusf(bf2f(row[768 + hh]) + dt_bias[kh]);
    const ushort* xp = row + hh * 64 + q * 16;
    ushort xv[16];
    *(uint4*)xv       = *(const uint4*)xp;
    *(uint4*)(xv + 8) = *(const uint4*)(xp + 8);
#pragma unroll
    for (int i = 0; i < 16; ++i)
      U[(q * 16 + i) * 72 + r] = f2bf(bf2f(xv[i]) * dtv);
    __syncthreads();
    ushort* dst = XhT + (((size_t)s * HK + kh) * HD + r) * LSEQ + lt * 64 + q * 16;
    *(uint4*)dst       = *(const uint4*)&U[r * 72 + q * 16];
    *(uint4*)(dst + 8) = *(const uint4*)&U[r * 72 + q * 16 + 8];
    return;
  }
  if (bid < 576) {
    const int idx = bid - 512;
    const int lt = idx & 15, k = idx >> 4;
    const int r = t >> 2, q = t & 3;
    const int l = lt * 64 + r;
    const int m = dir_src(k, l);
    const ushort* row = xbcT + ((size_t)s * LSEQ + m) * CTOT;
    {
      const ushort* bsrc = row + 512 + q * 32;
      ushort ub[32];
#pragma unroll
      for (int i2 = 0; i2 < 4; ++i2) *(uint4*)&ub[i2 * 8] = *(const uint4*)(bsrc + i2 * 8);
      ushort* bd = Bbf + ((size_t)s * LSEQ + l) * NSTATE + k * 128 + q * 32;
#pragma unroll
      for (int i2 = 0; i2 < 4; ++i2) *(uint4*)(bd + i2 * 8) = *(const uint4*)&ub[i2 * 8];
#pragma unroll
      for (int i = 0; i < 32; ++i) U[(q * 32 + i) * 72 + r] = ub[i];
    }
    {
      const ushort* csrc = row + 640 + q * 32;
      ushort uc[32];
#pragma unroll
      for (int i2 = 0; i2 < 4; ++i2) *(uint4*)&uc[i2 * 8] = *(const uint4*)(csrc + i2 * 8);
      ushort* cd = Cbf + ((size_t)s * LSEQ + l) * NSTATE + k * 128 + q * 32;
#pragma unroll
      for (int i2 = 0; i2 < 4; ++i2) *(uint4*)(cd + i2 * 8) = *(const uint4*)&uc[i2 * 8];
    }
    __syncthreads();
    {
      const int n = t >> 1, half = t & 1;
      ushort* dst = BT + ((size_t)s * NSTATE + k * 128 + n) * LSEQ + lt * 64 + half * 32;
      const ushort* src = &U[n * 72 + half * 32];
#pragma unroll
      for (int i2 = 0; i2 < 4; ++i2) *(uint4*)(dst + i2 * 8) = *(const uint4*)(src + i2 * 8);
    }
    return;
  }
  {
    float* Lf = (float*)U;
    const int idx = bid - 576;
    const int z = idx & 3, k = idx >> 2;
    const int m = dir_src(k, z * 256 + t);
    const ushort* rowdt = xbcT + ((size_t)s * LSEQ + m) * CTOT + 768;
    ushort dvu[8];
    *(uint4*)dvu = *(const uint4*)rowdt;
#pragma unroll
    for (int hh = 0; hh < 8; ++hh) {
      int kh = k * 8 + hh;
      float dAv = softplusf(bf2f(dvu[hh]) + dt_bias[kh]) * (-expf(A_logs[kh]));
      Lf[hh * 256 + t] = dAv;
    }
    __syncthreads();
    const int hh = t >> 5, seg = t & 31;
    float p[8]; float run = 0.f;
#pragma unroll
    for (int i = 0; i < 8; ++i) { run += Lf[hh * 256 + seg * 8 + i]; p[i] = run; }
    float sc = run, tot = run;
#pragma unroll
    for (int d = 1; d < 32; d <<= 1) {
      float o = __shfl_up(sc, d, 32);
      if (seg >= d) sc += o;
    }
    float off = sc - tot;
    float* dst = dAcs + ((size_t)s * HK + k * 8 + hh) * LSEQ + z * 256 + seg * 8;
#pragma unroll
    for (int i = 0; i < 8; ++i) dst[i] = p[i] + off;
  }
}

// ---------------- fused scan core: [0,80) CB lower-tri, [80,592) states+scan (LDS dbuf) ----------------
__global__ __launch_bounds__(256) void k_scan_core(
    const ushort* __restrict__ Cbf, const ushort* __restrict__ Bbf, ushort* __restrict__ CBbf,
    const ushort* __restrict__ BT, const ushort* __restrict__ XhT,
    const float* __restrict__ dAcs, ushort* __restrict__ prevP)
{
  __shared__ __align__(16) ushort As[2][64 * 72];
  __shared__ __align__(16) ushort Bs[2][64 * 72];
  __shared__ __align__(16) ushort Tr[64 * 72];
  __shared__ float decay[CHUNKSZ];
  const int bid = blockIdx.x, t = threadIdx.x;
  const int lane = t & 63, wv = t >> 6;
  const int lrow = lane & 15, lk8 = (lane >> 4) * 8;
  const int rA = t >> 2, cA = (t & 3) * 16;

  if (bid < 80) {
    const int sz = bid & 7, pidx = bid >> 3, s = sz >> 2, z = sz & 3;
    int it = 0; { while ((it + 1) * (it + 2) / 2 <= pidx) ++it; }
    const int jt = pidx - it * (it + 1) / 2;
    const ushort* Ap = Cbf + ((size_t)s * LSEQ + z * CHUNKSZ + it * 64 + rA) * NSTATE + cA;
    const ushort* Bp = Bbf + ((size_t)s * LSEQ + z * CHUNKSZ + jt * 64 + rA) * NSTATE + cA;
    uint4 qa[2], qb[2];
#define CBISSUE(k0) do { qa[0]=*(const uint4*)(Ap+(k0)); qa[1]=*(const uint4*)(Ap+(k0)+8); \
                         qb[0]=*(const uint4*)(Bp+(k0)); qb[1]=*(const uint4*)(Bp+(k0)+8); } while(0)
    CBISSUE(0);
    f32x4 acc[4] = {};
    for (int k0 = 0; k0 < NSTATE; k0 += 64) {
      const int pb2 = (k0 >> 6) & 1;
      *(uint4*)&As[pb2][rA * 72 + cA] = qa[0]; *(uint4*)&As[pb2][rA * 72 + cA + 8] = qa[1];
      *(uint4*)&Bs[pb2][rA * 72 + cA] = qb[0]; *(uint4*)&Bs[pb2][rA * 72 + cA + 8] = qb[1];
      __syncthreads();
      if (k0 + 64 < NSTATE) CBISSUE(k0 + 64);
#pragma unroll
      for (int sub = 0; sub < 2; ++sub) {
        const int ko = lk8 + sub * 32;
        short8 a = *(const short8*)&As[pb2][(16 * wv + lrow) * 72 + ko];
#pragma unroll
        for (int fj = 0; fj < 4; ++fj) {
          short8 b = *(const short8*)&Bs[pb2][(16 * fj + lrow) * 72 + ko];
          acc[fj] = __builtin_amdgcn_mfma_f32_16x16x32_bf16(a, b, acc[fj], 0, 0, 0);
        }
      }
    }
    ushort* Cp = CBbf + (size_t)sz * CHUNKSZ * CHUNKSZ;
    const int row0 = it * 64 + 16 * wv + (lane >> 4) * 4;
#pragma unroll
    for (int fj = 0; fj < 4; ++fj) {
      int col = jt * 64 + 16 * fj + lrow;
#pragma unroll
      for (int rr = 0; rr < 4; ++rr)
        Cp[(size_t)(row0 + rr) * CHUNKSZ + col] = f2bf(acc[fj][rr]);
    }
    return;
  }

  // states + inter-chunk scan -> prevP
  {
    const int idx = bid - 80;
    const int nh = idx & 7, kh = (idx >> 3) & 31, s = idx >> 8;
    const float* dA = dAcs + ((size_t)s * HK + kh) * LSEQ;
    float carry[4][4];
#pragma unroll
    for (int fj = 0; fj < 4; ++fj)
#pragma unroll
      for (int rr = 0; rr < 4; ++rr) carry[fj][rr] = 0.f;

    for (int z = 0; z < NC; ++z) {
      __syncthreads();
      const float dlast = dA[z * CHUNKSZ + CHUNKSZ - 1];
      decay[t] = __expf(dlast - dA[z * CHUNKSZ + t]);
      {
        const int n_base = 16 * wv + (lane >> 4) * 4;
#pragma unroll
        for (int fj = 0; fj < 4; ++fj) {
          const int p = 16 * fj + lrow;
#pragma unroll
          for (int rr = 0; rr < 4; ++rr)
            Tr[p * 72 + n_base + rr] = f2bf(carry[fj][rr]);
        }
      }
      __syncthreads();
      {
        const int sz = s * 4 + z;
        ushort* dst = prevP + (((size_t)sz * HK + kh) * HD + rA) * NSTATE + nh * 64 + cA;
        *(uint4*)dst       = *(const uint4*)&Tr[rA * 72 + cA];
        *(uint4*)(dst + 8) = *(const uint4*)&Tr[rA * 72 + cA + 8];
      }
      const ushort* Ap = BT + ((size_t)s * NSTATE + nh * 64 + rA) * LSEQ + z * CHUNKSZ + cA;
      const ushort* Xp = XhT + (((size_t)s * HK + kh) * HD + rA) * LSEQ + z * CHUNKSZ + cA;
      uint4 qa[2], qb[2];
#define SSISSUE(k0) do { qa[0]=*(const uint4*)(Ap+(k0)); qa[1]=*(const uint4*)(Ap+(k0)+8); \
                         qb[0]=*(const uint4*)(Xp+(k0)); qb[1]=*(const uint4*)(Xp+(k0)+8); } while(0)
      SSISSUE(0);
      f32x4 acc[4] = {};
      for (int k0 = 0; k0 < CHUNKSZ; k0 += 64) {
        const int pb2 = (k0 >> 6) & 1;
        *(uint4*)&As[pb2][rA * 72 + cA] = qa[0]; *(uint4*)&As[pb2][rA * 72 + cA + 8] = qa[1];
        {
          ushort tmp[16];
          *(uint4*)&tmp[0] = qb[0]; *(uint4*)&tmp[8] = qb[1];
#pragma unroll
          for (int i2 = 0; i2 < 8; ++i2) {
            int c = k0 + cA + 2 * i2;
            unsigned wpk = (unsigned)f2bf(bf2f(tmp[2 * i2]) * decay[c]) |
                           ((unsigned)f2bf(bf2f(tmp[2 * i2 + 1]) * decay[c + 1]) << 16);
            *(unsigned*)&Bs[pb2][rA * 72 + cA + 2 * i2] = wpk;
          }
        }
        __syncthreads();
        if (k0 + 64 < CHUNKSZ) SSISSUE(k0 + 64);
#pragma unroll
        for (int sub = 0; sub < 2; ++sub) {
          const int ko = lk8 + sub * 32;
          short8 a = *(const short8*)&As[pb2][(16 * wv + lrow) * 72 + ko];
#pragma unroll
          for (int fj = 0; fj < 4; ++fj) {
            short8 b = *(const short8*)&Bs[pb2][(16 * fj + lrow) * 72 + ko];
            acc[fj] = __builtin_amdgcn_mfma_f32_16x16x32_bf16(a, b, acc[fj], 0, 0, 0);
          }
        }
      }
      const float cdec = __expf(dlast);
#pragma unroll
      for (int fj = 0; fj < 4; ++fj)
#pragma unroll
        for (int rr = 0; rr < 4; ++rr)
          carry[fj][rr] = carry[fj][rr] * cdec + acc[fj][rr];
    }
  }
}

// ---------------- Y = Ydiag + Yoff (MFMA, LDS dbuf, bf16 out) ----------------
// z==0 blocks skip phase A entirely: prev state is identically zero.
__global__ __launch_bounds__(256) void k_y_mfma(
    const ushort* __restrict__ CBbf, const ushort* __restrict__ XhT,
    const ushort* __restrict__ Cbf, const ushort* __restrict__ prevP,
    const float* __restrict__ dAcs, ushort* __restrict__ Ybf)
{
  __shared__ __align__(16) ushort As[2][128 * 72];
  __shared__ __align__(16) ushort Bs[2][64 * 72];
  __shared__ float seg[CHUNKSZ];
  __shared__ float f2s[CHUNKSZ];
  const int it = blockIdx.x, kh = blockIdx.y, sz = blockIdx.z, s = sz >> 2, z = sz & 3;
  const int t = threadIdx.x, lane = t & 63, wv = t >> 6;
  const int lrow = lane & 15, lk8 = (lane >> 4) * 8;
  const int i0 = it * 128;
  const float* dAp = dAcs + ((size_t)s * HK + kh) * LSEQ + z * CHUNKSZ;
  seg[t] = dAp[t];
  __syncthreads();
  f2s[t] = __expf(seg[(t >> 5) << 5] - seg[t]);
  __syncthreads();

  const int rA = t >> 1, cA = (t & 1) * 32;
  const int rB = t >> 2, cB = (t & 3) * 16;
  f32x4 acc[2][4] = {};
  uint4 qa[4], qb[2];

  // phase A: acc = C @ prev^T  (skip for z==0: prev == 0)
  if (z != 0) {
    const ushort* Cp = Cbf + ((size_t)s * LSEQ + z * CHUNKSZ + i0 + rA) * NSTATE + cA;
    const ushort* Pp = prevP + (((size_t)sz * HK + kh) * HD + rB) * NSTATE + cB;
#define YISSUEA(k0) do { \
    qa[0]=*(const uint4*)(Cp+(k0));    qa[1]=*(const uint4*)(Cp+(k0)+8); \
    qa[2]=*(const uint4*)(Cp+(k0)+16); qa[3]=*(const uint4*)(Cp+(k0)+24); \
    qb[0]=*(const uint4*)(Pp+(k0));    qb[1]=*(const uint4*)(Pp+(k0)+8); } while(0)
    YISSUEA(0);
    for (int k0 = 0; k0 < NSTATE; k0 += 64) {
      const int pb2 = (k0 >> 6) & 1;
#pragma unroll
      for (int q2 = 0; q2 < 4; ++q2) *(uint4*)&As[pb2][rA * 72 + cA + q2 * 8] = qa[q2];
      *(uint4*)&Bs[pb2][rB * 72 + cB] = qb[0]; *(uint4*)&Bs[pb2][rB * 72 + cB + 8] = qb[1];
      __syncthreads();
      if (k0 + 64 < NSTATE) YISSUEA(k0 + 64);
#pragma unroll
      for (int sub = 0; sub < 2; ++sub) {
        const int ko = lk8 + sub * 32;
        short8 a[2], b[4];
#pragma unroll
        for (int f = 0; f < 2; ++f) a[f] = *(const short8*)&As[pb2][(32 * wv + 16 * f + lrow) * 72 + ko];
#pragma unroll
        for (int f = 0; f < 4; ++f) b[f] = *(const short8*)&Bs[pb2][(16 * f + lrow) * 72 + ko];
#pragma unroll
        for (int fi = 0; fi < 2; ++fi)
#pragma unroll
          for (int fj = 0; fj < 4; ++fj)
            acc[fi][fj] = __builtin_amdgcn_mfma_f32_16x16x32_bf16(a[fi], b[fj], acc[fi][fj], 0, 0, 0);
      }
    }
  }

  // prefetch phase-B tile 0 while rescaling
  const ushort* CBp = CBbf + ((size_t)sz * CHUNKSZ + i0 + rA) * CHUNKSZ;
  const ushort* Xp = XhT + (((size_t)s * HK + kh) * HD + rB) * LSEQ + z * CHUNKSZ + cB;
  const int nktB = 2 * it + 2;
#define YISSUEB(kt) do { const ushort* sa = CBp + (kt) * 64 + cA; \
    qa[0]=*(const uint4*)sa;      qa[1]=*(const uint4*)(sa+8); \
    qa[2]=*(const uint4*)(sa+16); qa[3]=*(const uint4*)(sa+24); \
    qb[0]=*(const uint4*)(Xp+(kt)*64); qb[1]=*(const uint4*)(Xp+(kt)*64+8); } while(0)
  YISSUEB(0);

  // scale Yoff rows by e^{seg_i}
  if (z != 0) {
#pragma unroll
    for (int fi = 0; fi < 2; ++fi) {
      int rloc = 32 * wv + 16 * fi + (lane >> 4) * 4;
#pragma unroll
      for (int rr = 0; rr < 4; ++rr) {
        float e = __expf(seg[i0 + rloc + rr]);
#pragma unroll
        for (int fj = 0; fj < 4; ++fj) acc[fi][fj][rr] *= e;
      }
    }
  }

  // phase A ended on buffer pb2=1 (or never ran); phase B starts on buffer 0 -> safe.
  // phase B: Ydiag (slice-factored, CB bf16)
  for (int kt = 0; kt < nktB; ++kt) {
    const int pb2 = kt & 1;
    {
      const int i = i0 + rA;
      const int jbase = kt * 64 + cA;
      if (i >= jbase) {
        float f1 = __expf(seg[i] - seg[jbase]);
        ushort tmp[32];
        *(uint4*)&tmp[0] = qa[0]; *(uint4*)&tmp[8] = qa[1];
        *(uint4*)&tmp[16] = qa[2]; *(uint4*)&tmp[24] = qa[3];
#pragma unroll
        for (int c = 0; c < 32; c += 2) {
          int j = jbase + c;
          float v0 = (j     <= i) ? bf2f(tmp[c])     * f1 : 0.f;
          float v1 = (j + 1 <= i) ? bf2f(tmp[c + 1]) * f1 : 0.f;
          *(unsigned*)&As[pb2][rA * 72 + cA + c] = (unsigned)f2bf(v0) | ((unsigned)f2bf(v1) << 16);
        }
      } else {
        uint4 zz = {0, 0, 0, 0};
#pragma unroll
        for (int q2 = 0; q2 < 4; ++q2) *(uint4*)&As[pb2][rA * 72 + cA + q2 * 8] = zz;
      }
    }
    {
      ushort tmp[16];
      *(uint4*)&tmp[0] = qb[0]; *(uint4*)&tmp[8] = qb[1];
#pragma unroll
      for (int i2 = 0; i2 < 8; ++i2) {
        int j = kt * 64 + cB + 2 * i2;
        unsigned wpk = (unsigned)f2bf(bf2f(tmp[2 * i2]) * f2s[j]) |
                       ((unsigned)f2bf(bf2f(tmp[2 * i2 + 1]) * f2s[j + 1]) << 16);
        *(unsigned*)&Bs[pb2][rB * 72 + cB + 2 * i2] = wpk;
      }
    }
    __syncthreads();
    if (kt + 1 < nktB) YISSUEB(kt + 1);
#pragma unroll
    for (int sub = 0; sub < 2; ++sub) {
      if (2 * kt + sub <= 4 * it + wv) {
        const int ko = lk8 + sub * 32;
        short8 a[2], b[4];
#pragma unroll
        for (int f = 0; f < 2; ++f) a[f] = *(const short8*)&As[pb2][(32 * wv + 16 * f + lrow) * 72 + ko];
#pragma unroll
        for (int f = 0; f < 4; ++f) b[f] = *(const short8*)&Bs[pb2][(16 * f + lrow) * 72 + ko];
#pragma unroll
        for (int fi = 0; fi < 2; ++fi)
#pragma unroll
          for (int fj = 0; fj < 4; ++fj)
            acc[fi][fj] = __builtin_amdgcn_mfma_f32_16x16x32_bf16(a[fi], b[fj], acc[fi][fj], 0, 0, 0);
      }
    }
  }

  ushort* Yp = Ybf + (((size_t)s * LSEQ + z * CHUNKSZ + i0) * HK + kh) * HD;
#pragma unroll
  for (int fi = 0; fi < 2; ++fi) {
    int row0 = 32 * wv + 16 * fi + (lane >> 4) * 4;
#pragma unroll
    for (int fj = 0; fj < 4; ++fj) {
      int col = 16 * fj + lrow;
#pragma unroll
      for (int rr = 0; rr < 4; ++rr)
        Yp[(size_t)(row0 + rr) * (HK * HD) + col] = f2bf(acc[fi][fj][rr]);
    }
  }
}

// ---------------- combine 4 directions + D*x + gated RMSNorm + MLP half (bf16 in/out) ----------------
__global__ __launch_bounds__(256) void k_combine(
    const ushort* __restrict__ Ybf, const ushort* __restrict__ xbcT,
    const ushort* __restrict__ skipxs, const float* __restrict__ Ds,
    const float* __restrict__ normw, ushort* __restrict__ o768bf)
{
  const int m = blockIdx.x, s = blockIdx.y, t = threadIdx.x;
  const int h = m >> 5, w = m & 31;
  const int l0 = m, l1 = (w << 5) | h, l2 = 1023 - m, l3 = 1023 - ((w << 5) | h);
  const ushort* Yb = Ybf + (size_t)s * LSEQ * (HK * HD);
  const ushort* xrow = xbcT + ((size_t)s * LSEQ + m) * CTOT;
  const ushort* srow = skipxs + ((size_t)s * LSEQ + m) * 1536;

  float g[2];
  float ss = 0.f;
#pragma unroll
  for (int q = 0; q < 2; ++q) {
    int d = t + q * 256;
    int hh = d >> 6, p = d & 63;
    float dsum = Ds[hh] + Ds[hh + 8] + Ds[hh + 16] + Ds[hh + 24];
    float val = bf2f(Yb[((size_t)l0 * HK + hh) * HD + p])
              + bf2f(Yb[((size_t)l1 * HK + 8 + hh) * HD + p])
              + bf2f(Yb[((size_t)l2 * HK + 16 + hh) * HD + p])
              + bf2f(Yb[((size_t)l3 * HK + 24 + hh) * HD + p])
              + bf2f(xrow[d]) * dsum;
    float zv = bf2f(srow[512 + d]);
    g[q] = val * siluf(zv);
    ss += g[q] * g[q];
  }
  for (int off = 32; off > 0; off >>= 1) ss += __shfl_down(ss, off, 64);
  __shared__ float red[4];
  if ((t & 63) == 0) red[t >> 6] = ss;
  __syncthreads();
  float total = red[0] + red[1] + red[2] + red[3];
  float scale = rsqrtf(total * (1.f / 512.f) + 1e-5f);

  ushort* orow = o768bf + ((size_t)s * LSEQ + m) * 768;
#pragma unroll
  for (int q = 0; q < 2; ++q) {
    int d = t + q * 256;
    orow[256 + d] = f2bf(g[q] * scale * normw[d]);
  }
  float z0 = bf2f(srow[t]), x0 = bf2f(srow[256 + t]);
  orow[t] = f2bf(siluf(z0) * x0);
}

// ---------------- 64x64-tile bf16 GEMM (out GEMM), LDS dbuf ----------------
__global__ __launch_bounds__(256) void gemm64_bf16(
    const ushort* __restrict__ A, const ushort* __restrict__ BT,
    float* __restrict__ C, int M, int N, int K)
{
  __shared__ __align__(16) ushort As[2][64 * 72];
  __shared__ __align__(16) ushort Bs[2][64 * 72];
  const int n0 = blockIdx.x * 64, m0 = blockIdx.y * 64;
  const int t = threadIdx.x, lane = t & 63, wv = t >> 6;
  const int wm = wv & 1, wn = wv >> 1;
  const int lrow = lane & 15, lk8 = (lane >> 4) * 8;
  const int rowL = t >> 2, cL = (t & 3) * 16;
  const ushort* pa_src = A + (size_t)(m0 + rowL) * K + cL;
  const int nB = n0 + rowL;
  const ushort* pb_src = BT + (size_t)nB * K + cL;
  const bool bval = (nB < N);
  uint4 pa[2], pb[2];
#define G64ISSUE(k0) do { \
    pa[0]=*(const uint4*)(pa_src+(k0)); pa[1]=*(const uint4*)(pa_src+(k0)+8); \
    if (bval) { pb[0]=*(const uint4*)(pb_src+(k0)); pb[1]=*(const uint4*)(pb_src+(k0)+8); } \
    else { uint4 z={0,0,0,0}; pb[0]=z; pb[1]=z; } } while(0)
  G64ISSUE(0);
  f32x4 acc[2][2] = {};
  for (int k0 = 0; k0 < K; k0 += 64) {
    const int pbuf = (k0 >> 6) & 1;
    *(uint4*)&As[pbuf][rowL * 72 + cL] = pa[0]; *(uint4*)&As[pbuf][rowL * 72 + cL + 8] = pa[1];
    *(uint4*)&Bs[pbuf][rowL * 72 + cL] = pb[0]; *(uint4*)&Bs[pbuf][rowL * 72 + cL + 8] = pb[1];
    __syncthreads();
    if (k0 + 64 < K) G64ISSUE(k0 + 64);
#pragma unroll
    for (int sub = 0; sub < 2; ++sub) {
      const int ko = lk8 + sub * 32;
      short8 a[2], b[2];
#pragma unroll
      for (int f = 0; f < 2; ++f) {
        a[f] = *(const short8*)&As[pbuf][(wm * 32 + 16 * f + lrow) * 72 + ko];
        b[f] = *(const short8*)&Bs[pbuf][(wn * 32 + 16 * f + lrow) * 72 + ko];
      }
#pragma unroll
      for (int fi = 0; fi < 2; ++fi)
#pragma unroll
        for (int fj = 0; fj < 2; ++fj)
          acc[fi][fj] = __builtin_amdgcn_mfma_f32_16x16x32_bf16(a[fi], b[fj], acc[fi][fj], 0, 0, 0);
    }
  }
#pragma unroll
  for (int fi = 0; fi < 2; ++fi) {
    int row0 = m0 + wm * 32 + 16 * fi + (lane >> 4) * 4;
#pragma unroll
    for (int fj = 0; fj < 2; ++fj) {
      int col = n0 + wn * 32 + 16 * fj + lrow;
      if (col < N)
#pragma unroll
        for (int rr = 0; rr < 4; ++rr)
          C[(size_t)(row0 + rr) * N + col] = acc[fi][fj][rr];
    }
  }
}

// ---------------- workspace layout (float units; bf16 buffers use half) ----------------
constexpr size_t OFF_SKIPXS = 0;                         // bf16 2048*1536 -> 1572864 f
constexpr size_t OFF_XBCT   = 3145728;                   // bf16 2048*776 -> 794624 f (slot kept)
constexpr size_t OFF_XHT    = OFF_XBCT + 1589248;        // bf16 -> 2097152 f
constexpr size_t OFF_BBF    = OFF_XHT + 2097152;         // 524288
constexpr size_t OFF_CBF    = OFF_BBF + 524288;          // 524288
constexpr size_t OFF_BTBF   = OFF_CBF + 524288;          // 524288
constexpr size_t OFF_DA     = OFF_BTBF + 524288;         // 65536
constexpr size_t OFF_CB     = OFF_DA + 65536;            // bf16 -> 262144 f
constexpr size_t OFF_PREV   = OFF_CB + 262144;           // bf16 -> 4194304 f
constexpr size_t OFF_Y      = OFF_PREV + 4194304;        // bf16 -> 2097152 f
constexpr size_t OFF_O768   = OFF_Y + 2097152;           // bf16 -> 786432 f
constexpr size_t OFF_WSXT   = OFF_O768 + 786432;         // 294912
constexpr size_t OFF_WBCT   = OFF_WSXT + 294912;         // 50688
constexpr size_t OFF_WOUT   = OFF_WBCT + 50688;          // 147456
constexpr size_t OFF_BCP    = OFF_PREV;                  // overlay: bc_pre bf16 (dead before prevP)

extern "C" void kernel_launch(void* const* d_in, const int* in_sizes, int n_in,
                              void* d_out, int out_size, void* d_ws, size_t ws_size,
                              hipStream_t stream)
{
  const float* u1     = (const float*)d_in[0];
  const float* u2     = (const float*)d_in[1];
  const float* u2c1   = (const float*)d_in[2];
  const float* u1c2   = (const float*)d_in[3];
  const float* W_skip = (const float*)d_in[4];
  const float* W_xs   = (const float*)d_in[5];
  const float* W_bcdt = (const float*)d_in[6];
  const float* cxw    = (const float*)d_in[7];
  const float* cxb    = (const float*)d_in[8];
  const float* cbw    = (const float*)d_in[9];
  const float* cbb    = (const float*)d_in[10];
  const float* Ds     = (const float*)d_in[11];
  const float* normw  = (const float*)d_in[12];
  const float* W_out  = (const float*)d_in[13];
  const float* dt_b   = (const float*)d_in[14];
  const float* A_logs = (const float*)d_in[15];
  float* out = (float*)d_out;
  float* ws  = (float*)d_ws;

  ushort* skipxs  = (ushort*)(ws + OFF_SKIPXS);
  ushort* xbcT    = (ushort*)(ws + OFF_XBCT);
  ushort* XhT     = (ushort*)(ws + OFF_XHT);
  ushort* Bbf     = (ushort*)(ws + OFF_BBF);
  ushort* Cbf     = (ushort*)(ws + OFF_CBF);
  ushort* BTbf    = (ushort*)(ws + OFF_BTBF);
  float*  dAcs    = ws + OFF_DA;
  ushort* CBbf    = (ushort*)(ws + OFF_CB);
  ushort* prevP   = (ushort*)(ws + OFF_PREV);
  ushort* Ybf     = (ushort*)(ws + OFF_Y);
  ushort* o768bf  = (ushort*)(ws + OFF_O768);
  ushort* WsxT    = (ushort*)(ws + OFF_WSXT);
  ushort* WbcdtT  = (ushort*)(ws + OFF_WBCT);
  ushort* WoutT   = (ushort*)(ws + OFF_WOUT);
  ushort* bc_pre  = (ushort*)(ws + OFF_BCP);

  // 1: weight transposes
  k_prep<<<dim3(246), 256, 0, stream>>>(W_skip, W_xs, W_bcdt, W_out, WsxT, WbcdtT, WoutT);
  // 2: both input GEMMs in one launch (bf16 outputs)
  k_gemm_in<<<dim3(12, 16, 2), 256, 0, stream>>>(u1, u2, u2c1, u1c2, WsxT, WbcdtT, skipxs, bc_pre);
  // 3: conv (bf16 in/out)
  k_conv<<<dim3(1024, 2), 256, 0, stream>>>(skipxs, bc_pre, cxw, cxb, cbw, cbb, xbcT);
  // 4: all gathers + cumsum
  k_gather_all<<<dim3(592, 2), 256, 0, stream>>>(xbcT, dt_b, A_logs, XhT, Bbf, Cbf, BTbf, dAcs);
  // 5: CB (lower-tri) + states/scan
  k_scan_core<<<dim3(592), 256, 0, stream>>>(Cbf, Bbf, CBbf, BTbf, XhT, dAcs, prevP);
  // 6: Y (z==0 blocks skip phase A)
  k_y_mfma<<<dim3(2, 32, 8), 256, 0, stream>>>(CBbf, XhT, Cbf, prevP, dAcs, Ybf);
  // 7: combine
  k_combine<<<dim3(1024, 2), 256, 0, stream>>>(Ybf, xbcT, skipxs, Ds, normw, o768bf);
  // 8: out GEMM
  gemm64_bf16<<<dim3(6, 32), 256, 0, stream>>>(o768bf, WoutT, out, 2048, 384, 768);
}

// Round 18
// 111.444 us; speedup vs baseline: 1.3896x; 1.0077x over previous
//
#include <hip/hip_runtime.h>
#include <hip/hip_bf16.h>
#include <cstddef>

// ---------------- problem constants ----------------
#define LSEQ   1024
#define DM     384
#define DSSM   512
#define NSTATE 512
#define HK     32
#define HD     64
#define CHUNKSZ 256
#define NC     4
#define CBCDT  264
#define CTOT   776
#define DMLP   256

typedef __attribute__((ext_vector_type(8))) short short8;
typedef __attribute__((ext_vector_type(4))) float f32x4;

__device__ __forceinline__ float siluf(float x)    { return x / (1.f + expf(-x)); }
__device__ __forceinline__ float softplusf(float x){ return fmaxf(x, 0.f) + log1pf(expf(-fabsf(x))); }

__device__ __forceinline__ ushort f2bf(float f) {
  union { float f; unsigned u; } v; v.f = f;
  unsigned r = v.u + 0x7fffu + ((v.u >> 16) & 1u);
  return (ushort)(r >> 16);
}
__device__ __forceinline__ float bf2f(ushort h) {
  union { unsigned u; float f; } v; v.u = ((unsigned)h) << 16;
  return v.f;
}

__device__ __forceinline__ int dir_src(int k, int l) {
  switch (k) {
    case 0:  return l;
    case 1:  return ((l & 31) << 5) | (l >> 5);
    case 2:  return 1023 - l;
    default: { int lr = 1023 - l; return ((lr & 31) << 5) | (lr >> 5); }
  }
}

// ---------------- weight transpose-casts: grid 246 ----------------
__global__ __launch_bounds__(256) void k_prep(
    const float* __restrict__ W_skip, const float* __restrict__ W_xs,
    const float* __restrict__ W_bcdt, const float* __restrict__ W_out,
    ushort* __restrict__ WsxT, ushort* __restrict__ WbcdtT, ushort* __restrict__ WoutT)
{
  __shared__ __align__(16) ushort T[64 * 72];
  int bid = blockIdx.x;
  const int t = threadIdx.x;
  const float* src; ushort* dst; int N, ldd, nbx;
  if (bid < 96)        {            src = W_skip; dst = WsxT;                     N = 1024; ldd = 384; nbx = 16; }
  else if (bid < 144)  { bid -= 96; src = W_xs;   dst = WsxT + (size_t)1024*384;  N = 512;  ldd = 384; nbx = 8; }
  else if (bid < 174)  { bid -= 144; src = W_bcdt; dst = WbcdtT;                  N = 264;  ldd = 384; nbx = 5; }
  else                 { bid -= 174; src = W_out;  dst = WoutT;                   N = 384;  ldd = 768; nbx = 6; }
  const int n0 = (bid % nbx) * 64, k0 = (bid / nbx) * 64;
  const int rk = t >> 2, q = t & 3;
  const int k = k0 + rk;
  const float* srow = src + (size_t)k * N + n0 + q * 16;
#pragma unroll
  for (int i = 0; i < 16; ++i) {
    int n = n0 + q * 16 + i;
    T[(q * 16 + i) * 72 + rk] = (n < N) ? f2bf(srow[i]) : (ushort)0;
  }
  __syncthreads();
  int n = n0 + rk;
  if (n < N) {
    ushort* d = dst + (size_t)n * ldd + k0 + q * 16;
    *(uint4*)d       = *(const uint4*)&T[rk * 72 + q * 16];
    *(uint4*)(d + 8) = *(const uint4*)&T[rk * 72 + q * 16 + 8];
  }
}

// ---------------- f32-A GEMM body (cast in staging), 128x128 tile, LDS dbuf, bf16 out ----------------
__device__ __forceinline__ void gemm_f32a_body(
    ushort (*As)[128 * 72], ushort (*Bs)[128 * 72],
    const float* __restrict__ A0, const float* __restrict__ A1, int rows0,
    const ushort* __restrict__ BT, ushort* __restrict__ C, int N, int K)
{
  const int n0 = blockIdx.x * 128, m0 = blockIdx.y * 128;
  const int t = threadIdx.x, lane = t & 63, wv = t >> 6;
  const int wm = wv & 1, wn = wv >> 1;
  const int lrow = lane & 15, lk8 = (lane >> 4) * 8;
  const int rowL = t >> 1, cL = (t & 1) * 32;
  const float* Af = (m0 < rows0) ? (A0 + (size_t)m0 * K) : (A1 + (size_t)(m0 - rows0) * K);
  const float* pa_src = Af + (size_t)rowL * K + cL;
  const int nB = n0 + rowL;
  const ushort* pb_src = BT + (size_t)nB * K + cL;
  const bool bval = (nB < N);
  float4 fa[8]; uint4 pb[4];
#define GAISSUE(k0) do { \
    _Pragma("unroll") for (int q2 = 0; q2 < 8; ++q2) fa[q2] = *(const float4*)(pa_src + (k0) + q2 * 4); \
    if (bval) { \
      pb[0] = *(const uint4*)(pb_src + (k0));      pb[1] = *(const uint4*)(pb_src + (k0) + 8); \
      pb[2] = *(const uint4*)(pb_src + (k0) + 16); pb[3] = *(const uint4*)(pb_src + (k0) + 24); \
    } else { uint4 z = {0,0,0,0}; pb[0]=z; pb[1]=z; pb[2]=z; pb[3]=z; } \
  } while(0)
  GAISSUE(0);
  f32x4 acc[4][4] = {};
  for (int k0 = 0; k0 < K; k0 += 64) {
    const int pbuf = (k0 >> 6) & 1;
#pragma unroll
    for (int q2 = 0; q2 < 8; ++q2) {
      ushort o[4] = { f2bf(fa[q2].x), f2bf(fa[q2].y), f2bf(fa[q2].z), f2bf(fa[q2].w) };
      *(uint2*)&As[pbuf][rowL * 72 + cL + q2 * 4] = *(const uint2*)o;
    }
#pragma unroll
    for (int q2 = 0; q2 < 4; ++q2) *(uint4*)&Bs[pbuf][rowL * 72 + cL + q2 * 8] = pb[q2];
    __syncthreads();
    if (k0 + 64 < K) GAISSUE(k0 + 64);
#pragma unroll
    for (int sub = 0; sub < 2; ++sub) {
      const int ko = lk8 + sub * 32;
      short8 a[4], b[4];
#pragma unroll
      for (int f = 0; f < 4; ++f) {
        a[f] = *(const short8*)&As[pbuf][(wm * 64 + 16 * f + lrow) * 72 + ko];
        b[f] = *(const short8*)&Bs[pbuf][(wn * 64 + 16 * f + lrow) * 72 + ko];
      }
#pragma unroll
      for (int fi = 0; fi < 4; ++fi)
#pragma unroll
        for (int fj = 0; fj < 4; ++fj)
          acc[fi][fj] = __builtin_amdgcn_mfma_f32_16x16x32_bf16(a[fi], b[fj], acc[fi][fj], 0, 0, 0);
    }
  }
#pragma unroll
  for (int fi = 0; fi < 4; ++fi) {
    int row0 = m0 + wm * 64 + 16 * fi + (lane >> 4) * 4;
#pragma unroll
    for (int fj = 0; fj < 4; ++fj) {
      int col = n0 + wn * 64 + 16 * fj + lrow;
      if (col < N)
#pragma unroll
        for (int rr = 0; rr < 4; ++rr)
          C[(size_t)(row0 + rr) * N + col] = f2bf(acc[fi][fj][rr]);
    }
  }
}

// ---------------- fused input GEMMs: z=0 skipxs (12x16), z=1 bcdt (3x16) ----------------
__global__ __launch_bounds__(256) void k_gemm_in(
    const float* __restrict__ u1, const float* __restrict__ u2,
    const float* __restrict__ uc1, const float* __restrict__ uc2,
    const ushort* __restrict__ WsxT, const ushort* __restrict__ WbcdtT,
    ushort* __restrict__ skipxs, ushort* __restrict__ bc_pre)
{
  __shared__ __align__(16) ushort As[2][128 * 72];
  __shared__ __align__(16) ushort Bs[2][128 * 72];
  if (blockIdx.z == 0) {
    gemm_f32a_body(As, Bs, u1, u2, 1024, WsxT, skipxs, 1536, 384);
  } else {
    if (blockIdx.x >= 3) return;
    gemm_f32a_body(As, Bs, uc1, uc2, 1024, WbcdtT, bc_pre, 264, 384);
  }
}

// ---------------- depthwise 3x3 conv + bias + SiLU; bf16 in/out; writes xbcT[s][m][c] ----------------
__global__ __launch_bounds__(256) void k_conv(
    const ushort* __restrict__ skipxs, const ushort* __restrict__ bc_pre,
    const float* __restrict__ wxs, const float* __restrict__ bxs,
    const float* __restrict__ wbc, const float* __restrict__ bbc,
    ushort* __restrict__ xbcT)
{
  const int m = blockIdx.x, s = blockIdx.y;
  const int h = m >> 5, w = m & 31;
  const ushort* xp = skipxs + (size_t)s * LSEQ * 1536 + 1024;
  const ushort* bp = bc_pre + (size_t)s * LSEQ * CBCDT;
  for (int c = threadIdx.x; c < CTOT; c += 256) {
    const ushort* src; int stride; const float* wt; float bias;
    if (c < DSSM) { src = xp + c; stride = 1536; wt = wxs + (size_t)c * 9; bias = bxs[c]; }
    else { int cb = c - DSSM; src = bp + cb; stride = CBCDT; wt = wbc + (size_t)cb * 9; bias = bbc[cb]; }
    float acc = bias;
#pragma unroll
    for (int dh = -1; dh <= 1; ++dh) {
      int h2 = h + dh; if (h2 < 0 || h2 > 31) continue;
#pragma unroll
      for (int dw = -1; dw <= 1; ++dw) {
        int w2 = w + dw; if (w2 < 0 || w2 > 31) continue;
        acc += bf2f(src[(size_t)(h2 * 32 + w2) * stride]) * wt[(dh + 1) * 3 + (dw + 1)];
      }
    }
    xbcT[((size_t)s * LSEQ + m) * CTOT + c] = f2bf(siluf(acc));
  }
}

// ---------------- fused gathers (bf16 xbcT): [0,512) Xh, [512,576) B/C/BT, [576,592) dA+cumsum ----------------
__global__ __launch_bounds__(256) void k_gather_all(
    const ushort* __restrict__ xbcT, const float* __restrict__ dt_bias,
    const float* __restrict__ A_logs,
    ushort* __restrict__ XhT, ushort* __restrict__ Bbf, ushort* __restrict__ Cbf,
    ushort* __restrict__ BT, float* __restrict__ dAcs)
{
  __shared__ __align__(16) ushort U[128 * 72];
  const int bid = blockIdx.x, s = blockIdx.y, t = threadIdx.x;
  if (bid < 512) {
    const int lt = bid & 15, kh = bid >> 4;
    const int k = kh >> 3, hh = kh & 7;
    const int r = t >> 2, q = t & 3;
    const int l = lt * 64 + r;
    const int m = dir_src(k, l);
    const ushort* row = xbcT + ((size_t)s * LSEQ + m) * CTOT;
    float dtv = softplusf(bf2f(row[768 + hh]) + dt_bias[kh]);
    const ushort* xp = row + hh * 64 + q * 16;
    ushort xv[16];
    *(uint4*)xv       = *(const uint4*)xp;
    *(uint4*)(xv + 8) = *(const uint4*)(xp + 8);
#pragma unroll
    for (int i = 0; i < 16; ++i)
      U[(q * 16 + i) * 72 + r] = f2bf(bf2f(xv[i]) * dtv);
    __syncthreads();
    ushort* dst = XhT + (((size_t)s * HK + kh) * HD + r) * LSEQ + lt * 64 + q * 16;
    *(uint4*)dst       = *(const uint4*)&U[r * 72 + q * 16];
    *(uint4*)(dst + 8) = *(const uint4*)&U[r * 72 + q * 16 + 8];
    return;
  }
  if (bid < 576) {
    const int idx = bid - 512;
    const int lt = idx & 15, k = idx >> 4;
    const int r = t >> 2, q = t & 3;
    const int l = lt * 64 + r;
    const int m = dir_src(k, l);
    const ushort* row = xbcT + ((size_t)s * LSEQ + m) * CTOT;
    {
      const ushort* bsrc = row + 512 + q * 32;
      ushort ub[32];
#pragma unroll
      for (int i2 = 0; i2 < 4; ++i2) *(uint4*)&ub[i2 * 8] = *(const uint4*)(bsrc + i2 * 8);
      ushort* bd = Bbf + ((size_t)s * LSEQ + l) * NSTATE + k * 128 + q * 32;
#pragma unroll
      for (int i2 = 0; i2 < 4; ++i2) *(uint4*)(bd + i2 * 8) = *(const uint4*)&ub[i2 * 8];
#pragma unroll
      for (int i = 0; i < 32; ++i) U[(q * 32 + i) * 72 + r] = ub[i];
    }
    {
      const ushort* csrc = row + 640 + q * 32;
      ushort uc[32];
#pragma unroll
      for (int i2 = 0; i2 < 4; ++i2) *(uint4*)&uc[i2 * 8] = *(const uint4*)(csrc + i2 * 8);
      ushort* cd = Cbf + ((size_t)s * LSEQ + l) * NSTATE + k * 128 + q * 32;
#pragma unroll
      for (int i2 = 0; i2 < 4; ++i2) *(uint4*)(cd + i2 * 8) = *(const uint4*)&uc[i2 * 8];
    }
    __syncthreads();
    {
      const int n = t >> 1, half = t & 1;
      ushort* dst = BT + ((size_t)s * NSTATE + k * 128 + n) * LSEQ + lt * 64 + half * 32;
      const ushort* src = &U[n * 72 + half * 32];
#pragma unroll
      for (int i2 = 0; i2 < 4; ++i2) *(uint4*)(dst + i2 * 8) = *(const uint4*)(src + i2 * 8);
    }
    return;
  }
  {
    float* Lf = (float*)U;
    const int idx = bid - 576;
    const int z = idx & 3, k = idx >> 2;
    const int m = dir_src(k, z * 256 + t);
    const ushort* rowdt = xbcT + ((size_t)s * LSEQ + m) * CTOT + 768;
    ushort dvu[8];
    *(uint4*)dvu = *(const uint4*)rowdt;
#pragma unroll
    for (int hh = 0; hh < 8; ++hh) {
      int kh = k * 8 + hh;
      float dAv = softplusf(bf2f(dvu[hh]) + dt_bias[kh]) * (-expf(A_logs[kh]));
      Lf[hh * 256 + t] = dAv;
    }
    __syncthreads();
    const int hh = t >> 5, seg = t & 31;
    float p[8]; float run = 0.f;
#pragma unroll
    for (int i = 0; i < 8; ++i) { run += Lf[hh * 256 + seg * 8 + i]; p[i] = run; }
    float sc = run, tot = run;
#pragma unroll
    for (int d = 1; d < 32; d <<= 1) {
      float o = __shfl_up(sc, d, 32);
      if (seg >= d) sc += o;
    }
    float off = sc - tot;
    float* dst = dAcs + ((size_t)s * HK + k * 8 + hh) * LSEQ + z * 256 + seg * 8;
#pragma unroll
    for (int i = 0; i < 8; ++i) dst[i] = p[i] + off;
  }
}

// ---------------- fused scan core: [0,80) CB lower-tri, [80,592) states+scan (LDS dbuf) ----------------
__global__ __launch_bounds__(256) void k_scan_core(
    const ushort* __restrict__ Cbf, const ushort* __restrict__ Bbf, ushort* __restrict__ CBbf,
    const ushort* __restrict__ BT, const ushort* __restrict__ XhT,
    const float* __restrict__ dAcs, ushort* __restrict__ prevP)
{
  __shared__ __align__(16) ushort As[2][64 * 72];
  __shared__ __align__(16) ushort Bs[2][64 * 72];
  __shared__ __align__(16) ushort Tr[64 * 72];
  __shared__ float decay[CHUNKSZ];
  const int bid = blockIdx.x, t = threadIdx.x;
  const int lane = t & 63, wv = t >> 6;
  const int lrow = lane & 15, lk8 = (lane >> 4) * 8;
  const int rA = t >> 2, cA = (t & 3) * 16;

  if (bid < 80) {
    const int sz = bid & 7, pidx = bid >> 3, s = sz >> 2, z = sz & 3;
    int it = 0; { while ((it + 1) * (it + 2) / 2 <= pidx) ++it; }
    const int jt = pidx - it * (it + 1) / 2;
    const ushort* Ap = Cbf + ((size_t)s * LSEQ + z * CHUNKSZ + it * 64 + rA) * NSTATE + cA;
    const ushort* Bp = Bbf + ((size_t)s * LSEQ + z * CHUNKSZ + jt * 64 + rA) * NSTATE + cA;
    uint4 qa[2], qb[2];
#define CBISSUE(k0) do { qa[0]=*(const uint4*)(Ap+(k0)); qa[1]=*(const uint4*)(Ap+(k0)+8); \
                         qb[0]=*(const uint4*)(Bp+(k0)); qb[1]=*(const uint4*)(Bp+(k0)+8); } while(0)
    CBISSUE(0);
    f32x4 acc[4] = {};
    for (int k0 = 0; k0 < NSTATE; k0 += 64) {
      const int pb2 = (k0 >> 6) & 1;
      *(uint4*)&As[pb2][rA * 72 + cA] = qa[0]; *(uint4*)&As[pb2][rA * 72 + cA + 8] = qa[1];
      *(uint4*)&Bs[pb2][rA * 72 + cA] = qb[0]; *(uint4*)&Bs[pb2][rA * 72 + cA + 8] = qb[1];
      __syncthreads();
      if (k0 + 64 < NSTATE) CBISSUE(k0 + 64);
#pragma unroll
      for (int sub = 0; sub < 2; ++sub) {
        const int ko = lk8 + sub * 32;
        short8 a = *(const short8*)&As[pb2][(16 * wv + lrow) * 72 + ko];
#pragma unroll
        for (int fj = 0; fj < 4; ++fj) {
          short8 b = *(const short8*)&Bs[pb2][(16 * fj + lrow) * 72 + ko];
          acc[fj] = __builtin_amdgcn_mfma_f32_16x16x32_bf16(a, b, acc[fj], 0, 0, 0);
        }
      }
    }
    ushort* Cp = CBbf + (size_t)sz * CHUNKSZ * CHUNKSZ;
    const int row0 = it * 64 + 16 * wv + (lane >> 4) * 4;
#pragma unroll
    for (int fj = 0; fj < 4; ++fj) {
      int col = jt * 64 + 16 * fj + lrow;
#pragma unroll
      for (int rr = 0; rr < 4; ++rr)
        Cp[(size_t)(row0 + rr) * CHUNKSZ + col] = f2bf(acc[fj][rr]);
    }
    return;
  }

  // states + inter-chunk scan -> prevP
  {
    const int idx = bid - 80;
    const int nh = idx & 7, kh = (idx >> 3) & 31, s = idx >> 8;
    const float* dA = dAcs + ((size_t)s * HK + kh) * LSEQ;
    float carry[4][4];
#pragma unroll
    for (int fj = 0; fj < 4; ++fj)
#pragma unroll
      for (int rr = 0; rr < 4; ++rr) carry[fj][rr] = 0.f;

    for (int z = 0; z < NC; ++z) {
      __syncthreads();
      const float dlast = dA[z * CHUNKSZ + CHUNKSZ - 1];
      decay[t] = __expf(dlast - dA[z * CHUNKSZ + t]);
      {
        const int n_base = 16 * wv + (lane >> 4) * 4;
#pragma unroll
        for (int fj = 0; fj < 4; ++fj) {
          const int p = 16 * fj + lrow;
#pragma unroll
          for (int rr = 0; rr < 4; ++rr)
            Tr[p * 72 + n_base + rr] = f2bf(carry[fj][rr]);
        }
      }
      __syncthreads();
      {
        const int sz = s * 4 + z;
        ushort* dst = prevP + (((size_t)sz * HK + kh) * HD + rA) * NSTATE + nh * 64 + cA;
        *(uint4*)dst       = *(const uint4*)&Tr[rA * 72 + cA];
        *(uint4*)(dst + 8) = *(const uint4*)&Tr[rA * 72 + cA + 8];
      }
      const ushort* Ap = BT + ((size_t)s * NSTATE + nh * 64 + rA) * LSEQ + z * CHUNKSZ + cA;
      const ushort* Xp = XhT + (((size_t)s * HK + kh) * HD + rA) * LSEQ + z * CHUNKSZ + cA;
      uint4 qa[2], qb[2];
#define SSISSUE(k0) do { qa[0]=*(const uint4*)(Ap+(k0)); qa[1]=*(const uint4*)(Ap+(k0)+8); \
                         qb[0]=*(const uint4*)(Xp+(k0)); qb[1]=*(const uint4*)(Xp+(k0)+8); } while(0)
      SSISSUE(0);
      f32x4 acc[4] = {};
      for (int k0 = 0; k0 < CHUNKSZ; k0 += 64) {
        const int pb2 = (k0 >> 6) & 1;
        *(uint4*)&As[pb2][rA * 72 + cA] = qa[0]; *(uint4*)&As[pb2][rA * 72 + cA + 8] = qa[1];
        {
          ushort tmp[16];
          *(uint4*)&tmp[0] = qb[0]; *(uint4*)&tmp[8] = qb[1];
#pragma unroll
          for (int i2 = 0; i2 < 8; ++i2) {
            int c = k0 + cA + 2 * i2;
            unsigned wpk = (unsigned)f2bf(bf2f(tmp[2 * i2]) * decay[c]) |
                           ((unsigned)f2bf(bf2f(tmp[2 * i2 + 1]) * decay[c + 1]) << 16);
            *(unsigned*)&Bs[pb2][rA * 72 + cA + 2 * i2] = wpk;
          }
        }
        __syncthreads();
        if (k0 + 64 < CHUNKSZ) SSISSUE(k0 + 64);
#pragma unroll
        for (int sub = 0; sub < 2; ++sub) {
          const int ko = lk8 + sub * 32;
          short8 a = *(const short8*)&As[pb2][(16 * wv + lrow) * 72 + ko];
#pragma unroll
          for (int fj = 0; fj < 4; ++fj) {
            short8 b = *(const short8*)&Bs[pb2][(16 * fj + lrow) * 72 + ko];
            acc[fj] = __builtin_amdgcn_mfma_f32_16x16x32_bf16(a, b, acc[fj], 0, 0, 0);
          }
        }
      }
      const float cdec = __expf(dlast);
#pragma unroll
      for (int fj = 0; fj < 4; ++fj)
#pragma unroll
        for (int rr = 0; rr < 4; ++rr)
          carry[fj][rr] = carry[fj][rr] * cdec + acc[fj][rr];
    }
  }
}

// ---------------- Y = Ydiag + Yoff (MFMA, LDS dbuf, bf16 out) ----------------
// Load-balance remap: co-resident blocks (f, f+256) get complementary (it, z)
// so light (z==0, small it) blocks pair with heavy ones on each CU.
__global__ __launch_bounds__(256) void k_y_mfma(
    const ushort* __restrict__ CBbf, const ushort* __restrict__ XhT,
    const ushort* __restrict__ Cbf, const ushort* __restrict__ prevP,
    const float* __restrict__ dAcs, ushort* __restrict__ Ybf)
{
  __shared__ __align__(16) ushort As[2][128 * 72];
  __shared__ __align__(16) ushort Bs[2][64 * 72];
  __shared__ float seg[CHUNKSZ];
  __shared__ float f2s[CHUNKSZ];
  // remap: s from dispatch z-slot; rotate z by 2*s, flip it by s (bijective)
  const int szr = blockIdx.z, kh = blockIdx.y;
  const int s = szr >> 2, zr = szr & 3;
  const int z = (zr + 2 * s) & 3;
  const int it = blockIdx.x ^ s;
  const int sz = s * 4 + z;
  const int t = threadIdx.x, lane = t & 63, wv = t >> 6;
  const int lrow = lane & 15, lk8 = (lane >> 4) * 8;
  const int i0 = it * 128;
  const float* dAp = dAcs + ((size_t)s * HK + kh) * LSEQ + z * CHUNKSZ;
  seg[t] = dAp[t];
  __syncthreads();
  f2s[t] = __expf(seg[(t >> 5) << 5] - seg[t]);
  __syncthreads();

  const int rA = t >> 1, cA = (t & 1) * 32;
  const int rB = t >> 2, cB = (t & 3) * 16;
  f32x4 acc[2][4] = {};
  uint4 qa[4], qb[2];

  // phase A: acc = C @ prev^T  (skip for z==0: prev == 0)
  if (z != 0) {
    const ushort* Cp = Cbf + ((size_t)s * LSEQ + z * CHUNKSZ + i0 + rA) * NSTATE + cA;
    const ushort* Pp = prevP + (((size_t)sz * HK + kh) * HD + rB) * NSTATE + cB;
#define YISSUEA(k0) do { \
    qa[0]=*(const uint4*)(Cp+(k0));    qa[1]=*(const uint4*)(Cp+(k0)+8); \
    qa[2]=*(const uint4*)(Cp+(k0)+16); qa[3]=*(const uint4*)(Cp+(k0)+24); \
    qb[0]=*(const uint4*)(Pp+(k0));    qb[1]=*(const uint4*)(Pp+(k0)+8); } while(0)
    YISSUEA(0);
    for (int k0 = 0; k0 < NSTATE; k0 += 64) {
      const int pb2 = (k0 >> 6) & 1;
#pragma unroll
      for (int q2 = 0; q2 < 4; ++q2) *(uint4*)&As[pb2][rA * 72 + cA + q2 * 8] = qa[q2];
      *(uint4*)&Bs[pb2][rB * 72 + cB] = qb[0]; *(uint4*)&Bs[pb2][rB * 72 + cB + 8] = qb[1];
      __syncthreads();
      if (k0 + 64 < NSTATE) YISSUEA(k0 + 64);
#pragma unroll
      for (int sub = 0; sub < 2; ++sub) {
        const int ko = lk8 + sub * 32;
        short8 a[2], b[4];
#pragma unroll
        for (int f = 0; f < 2; ++f) a[f] = *(const short8*)&As[pb2][(32 * wv + 16 * f + lrow) * 72 + ko];
#pragma unroll
        for (int f = 0; f < 4; ++f) b[f] = *(const short8*)&Bs[pb2][(16 * f + lrow) * 72 + ko];
#pragma unroll
        for (int fi = 0; fi < 2; ++fi)
#pragma unroll
          for (int fj = 0; fj < 4; ++fj)
            acc[fi][fj] = __builtin_amdgcn_mfma_f32_16x16x32_bf16(a[fi], b[fj], acc[fi][fj], 0, 0, 0);
      }
    }
  }

  // prefetch phase-B tile 0 while rescaling
  const ushort* CBp = CBbf + ((size_t)sz * CHUNKSZ + i0 + rA) * CHUNKSZ;
  const ushort* Xp = XhT + (((size_t)s * HK + kh) * HD + rB) * LSEQ + z * CHUNKSZ + cB;
  const int nktB = 2 * it + 2;
#define YISSUEB(kt) do { const ushort* sa = CBp + (kt) * 64 + cA; \
    qa[0]=*(const uint4*)sa;      qa[1]=*(const uint4*)(sa+8); \
    qa[2]=*(const uint4*)(sa+16); qa[3]=*(const uint4*)(sa+24); \
    qb[0]=*(const uint4*)(Xp+(kt)*64); qb[1]=*(const uint4*)(Xp+(kt)*64+8); } while(0)
  YISSUEB(0);

  // scale Yoff rows by e^{seg_i}
  if (z != 0) {
#pragma unroll
    for (int fi = 0; fi < 2; ++fi) {
      int rloc = 32 * wv + 16 * fi + (lane >> 4) * 4;
#pragma unroll
      for (int rr = 0; rr < 4; ++rr) {
        float e = __expf(seg[i0 + rloc + rr]);
#pragma unroll
        for (int fj = 0; fj < 4; ++fj) acc[fi][fj][rr] *= e;
      }
    }
  }

  // phase A ended on buffer pb2=1 (or never ran); phase B starts on buffer 0 -> safe.
  // phase B: Ydiag (slice-factored, CB bf16)
  for (int kt = 0; kt < nktB; ++kt) {
    const int pb2 = kt & 1;
    {
      const int i = i0 + rA;
      const int jbase = kt * 64 + cA;
      if (i >= jbase) {
        float f1 = __expf(seg[i] - seg[jbase]);
        ushort tmp[32];
        *(uint4*)&tmp[0] = qa[0]; *(uint4*)&tmp[8] = qa[1];
        *(uint4*)&tmp[16] = qa[2]; *(uint4*)&tmp[24] = qa[3];
#pragma unroll
        for (int c = 0; c < 32; c += 2) {
          int j = jbase + c;
          float v0 = (j     <= i) ? bf2f(tmp[c])     * f1 : 0.f;
          float v1 = (j + 1 <= i) ? bf2f(tmp[c + 1]) * f1 : 0.f;
          *(unsigned*)&As[pb2][rA * 72 + cA + c] = (unsigned)f2bf(v0) | ((unsigned)f2bf(v1) << 16);
        }
      } else {
        uint4 zz = {0, 0, 0, 0};
#pragma unroll
        for (int q2 = 0; q2 < 4; ++q2) *(uint4*)&As[pb2][rA * 72 + cA + q2 * 8] = zz;
      }
    }
    {
      ushort tmp[16];
      *(uint4*)&tmp[0] = qb[0]; *(uint4*)&tmp[8] = qb[1];
#pragma unroll
      for (int i2 = 0; i2 < 8; ++i2) {
        int j = kt * 64 + cB + 2 * i2;
        unsigned wpk = (unsigned)f2bf(bf2f(tmp[2 * i2]) * f2s[j]) |
                       ((unsigned)f2bf(bf2f(tmp[2 * i2 + 1]) * f2s[j + 1]) << 16);
        *(unsigned*)&Bs[pb2][rB * 72 + cB + 2 * i2] = wpk;
      }
    }
    __syncthreads();
    if (kt + 1 < nktB) YISSUEB(kt + 1);
#pragma unroll
    for (int sub = 0; sub < 2; ++sub) {
      if (2 * kt + sub <= 4 * it + wv) {
        const int ko = lk8 + sub * 32;
        short8 a[2], b[4];
#pragma unroll
        for (int f = 0; f < 2; ++f) a[f] = *(const short8*)&As[pb2][(32 * wv + 16 * f + lrow) * 72 + ko];
#pragma unroll
        for (int f = 0; f < 4; ++f) b[f] = *(const short8*)&Bs[pb2][(16 * f + lrow) * 72 + ko];
#pragma unroll
        for (int fi = 0; fi < 2; ++fi)
#pragma unroll
          for (int fj = 0; fj < 4; ++fj)
            acc[fi][fj] = __builtin_amdgcn_mfma_f32_16x16x32_bf16(a[fi], b[fj], acc[fi][fj], 0, 0, 0);
      }
    }
  }

  ushort* Yp = Ybf + (((size_t)s * LSEQ + z * CHUNKSZ + i0) * HK + kh) * HD;
#pragma unroll
  for (int fi = 0; fi < 2; ++fi) {
    int row0 = 32 * wv + 16 * fi + (lane >> 4) * 4;
#pragma unroll
    for (int fj = 0; fj < 4; ++fj) {
      int col = 16 * fj + lrow;
#pragma unroll
      for (int rr = 0; rr < 4; ++rr)
        Yp[(size_t)(row0 + rr) * (HK * HD) + col] = f2bf(acc[fi][fj][rr]);
    }
  }
}

// ---------------- combine 4 directions + D*x + gated RMSNorm + MLP half (bf16 in/out) ----------------
__global__ __launch_bounds__(256) void k_combine(
    const ushort* __restrict__ Ybf, const ushort* __restrict__ xbcT,
    const ushort* __restrict__ skipxs, const float* __restrict__ Ds,
    const float* __restrict__ normw, ushort* __restrict__ o768bf)
{
  const int m = blockIdx.x, s = blockIdx.y, t = threadIdx.x;
  const int h = m >> 5, w = m & 31;
  const int l0 = m, l1 = (w << 5) | h, l2 = 1023 - m, l3 = 1023 - ((w << 5) | h);
  const ushort* Yb = Ybf + (size_t)s * LSEQ * (HK * HD);
  const ushort* xrow = xbcT + ((size_t)s * LSEQ + m) * CTOT;
  const ushort* srow = skipxs + ((size_t)s * LSEQ + m) * 1536;

  float g[2];
  float ss = 0.f;
#pragma unroll
  for (int q = 0; q < 2; ++q) {
    int d = t + q * 256;
    int hh = d >> 6, p = d & 63;
    float dsum = Ds[hh] + Ds[hh + 8] + Ds[hh + 16] + Ds[hh + 24];
    float val = bf2f(Yb[((size_t)l0 * HK + hh) * HD + p])
              + bf2f(Yb[((size_t)l1 * HK + 8 + hh) * HD + p])
              + bf2f(Yb[((size_t)l2 * HK + 16 + hh) * HD + p])
              + bf2f(Yb[((size_t)l3 * HK + 24 + hh) * HD + p])
              + bf2f(xrow[d]) * dsum;
    float zv = bf2f(srow[512 + d]);
    g[q] = val * siluf(zv);
    ss += g[q] * g[q];
  }
  for (int off = 32; off > 0; off >>= 1) ss += __shfl_down(ss, off, 64);
  __shared__ float red[4];
  if ((t & 63) == 0) red[t >> 6] = ss;
  __syncthreads();
  float total = red[0] + red[1] + red[2] + red[3];
  float scale = rsqrtf(total * (1.f / 512.f) + 1e-5f);

  ushort* orow = o768bf + ((size_t)s * LSEQ + m) * 768;
#pragma unroll
  for (int q = 0; q < 2; ++q) {
    int d = t + q * 256;
    orow[256 + d] = f2bf(g[q] * scale * normw[d]);
  }
  float z0 = bf2f(srow[t]), x0 = bf2f(srow[256 + t]);
  orow[t] = f2bf(siluf(z0) * x0);
}

// ---------------- 64x64-tile bf16 GEMM (out GEMM), LDS dbuf ----------------
__global__ __launch_bounds__(256) void gemm64_bf16(
    const ushort* __restrict__ A, const ushort* __restrict__ BT,
    float* __restrict__ C, int M, int N, int K)
{
  __shared__ __align__(16) ushort As[2][64 * 72];
  __shared__ __align__(16) ushort Bs[2][64 * 72];
  const int n0 = blockIdx.x * 64, m0 = blockIdx.y * 64;
  const int t = threadIdx.x, lane = t & 63, wv = t >> 6;
  const int wm = wv & 1, wn = wv >> 1;
  const int lrow = lane & 15, lk8 = (lane >> 4) * 8;
  const int rowL = t >> 2, cL = (t & 3) * 16;
  const ushort* pa_src = A + (size_t)(m0 + rowL) * K + cL;
  const int nB = n0 + rowL;
  const ushort* pb_src = BT + (size_t)nB * K + cL;
  const bool bval = (nB < N);
  uint4 pa[2], pb[2];
#define G64ISSUE(k0) do { \
    pa[0]=*(const uint4*)(pa_src+(k0)); pa[1]=*(const uint4*)(pa_src+(k0)+8); \
    if (bval) { pb[0]=*(const uint4*)(pb_src+(k0)); pb[1]=*(const uint4*)(pb_src+(k0)+8); } \
    else { uint4 z={0,0,0,0}; pb[0]=z; pb[1]=z; } } while(0)
  G64ISSUE(0);
  f32x4 acc[2][2] = {};
  for (int k0 = 0; k0 < K; k0 += 64) {
    const int pbuf = (k0 >> 6) & 1;
    *(uint4*)&As[pbuf][rowL * 72 + cL] = pa[0]; *(uint4*)&As[pbuf][rowL * 72 + cL + 8] = pa[1];
    *(uint4*)&Bs[pbuf][rowL * 72 + cL] = pb[0]; *(uint4*)&Bs[pbuf][rowL * 72 + cL + 8] = pb[1];
    __syncthreads();
    if (k0 + 64 < K) G64ISSUE(k0 + 64);
#pragma unroll
    for (int sub = 0; sub < 2; ++sub) {
      const int ko = lk8 + sub * 32;
      short8 a[2], b[2];
#pragma unroll
      for (int f = 0; f < 2; ++f) {
        a[f] = *(const short8*)&As[pbuf][(wm * 32 + 16 * f + lrow) * 72 + ko];
        b[f] = *(const short8*)&Bs[pbuf][(wn * 32 + 16 * f + lrow) * 72 + ko];
      }
#pragma unroll
      for (int fi = 0; fi < 2; ++fi)
#pragma unroll
        for (int fj = 0; fj < 2; ++fj)
          acc[fi][fj] = __builtin_amdgcn_mfma_f32_16x16x32_bf16(a[fi], b[fj], acc[fi][fj], 0, 0, 0);
    }
  }
#pragma unroll
  for (int fi = 0; fi < 2; ++fi) {
    int row0 = m0 + wm * 32 + 16 * fi + (lane >> 4) * 4;
#pragma unroll
    for (int fj = 0; fj < 2; ++fj) {
      int col = n0 + wn * 32 + 16 * fj + lrow;
      if (col < N)
#pragma unroll
        for (int rr = 0; rr < 4; ++rr)
          C[(size_t)(row0 + rr) * N + col] = acc[fi][fj][rr];
    }
  }
}

// ---------------- workspace layout (float units; bf16 buffers use half) ----------------
constexpr size_t OFF_SKIPXS = 0;                         // bf16 2048*1536 -> 1572864 f
constexpr size_t OFF_XBCT   = 3145728;                   // bf16 2048*776 -> 794624 f (slot kept)
constexpr size_t OFF_XHT    = OFF_XBCT + 1589248;        // bf16 -> 2097152 f
constexpr size_t OFF_BBF    = OFF_XHT + 2097152;         // 524288
constexpr size_t OFF_CBF    = OFF_BBF + 524288;          // 524288
constexpr size_t OFF_BTBF   = OFF_CBF + 524288;          // 524288
constexpr size_t OFF_DA     = OFF_BTBF + 524288;         // 65536
constexpr size_t OFF_CB     = OFF_DA + 65536;            // bf16 -> 262144 f
constexpr size_t OFF_PREV   = OFF_CB + 262144;           // bf16 -> 4194304 f
constexpr size_t OFF_Y      = OFF_PREV + 4194304;        // bf16 -> 2097152 f
constexpr size_t OFF_O768   = OFF_Y + 2097152;           // bf16 -> 786432 f
constexpr size_t OFF_WSXT   = OFF_O768 + 786432;         // 294912
constexpr size_t OFF_WBCT   = OFF_WSXT + 294912;         // 50688
constexpr size_t OFF_WOUT   = OFF_WBCT + 50688;          // 147456
constexpr size_t OFF_BCP    = OFF_PREV;                  // overlay: bc_pre bf16 (dead before prevP)

extern "C" void kernel_launch(void* const* d_in, const int* in_sizes, int n_in,
                              void* d_out, int out_size, void* d_ws, size_t ws_size,
                              hipStream_t stream)
{
  const float* u1     = (const float*)d_in[0];
  const float* u2     = (const float*)d_in[1];
  const float* u2c1   = (const float*)d_in[2];
  const float* u1c2   = (const float*)d_in[3];
  const float* W_skip = (const float*)d_in[4];
  const float* W_xs   = (const float*)d_in[5];
  const float* W_bcdt = (const float*)d_in[6];
  const float* cxw    = (const float*)d_in[7];
  const float* cxb    = (const float*)d_in[8];
  const float* cbw    = (const float*)d_in[9];
  const float* cbb    = (const float*)d_in[10];
  const float* Ds     = (const float*)d_in[11];
  const float* normw  = (const float*)d_in[12];
  const float* W_out  = (const float*)d_in[13];
  const float* dt_b   = (const float*)d_in[14];
  const float* A_logs = (const float*)d_in[15];
  float* out = (float*)d_out;
  float* ws  = (float*)d_ws;

  ushort* skipxs  = (ushort*)(ws + OFF_SKIPXS);
  ushort* xbcT    = (ushort*)(ws + OFF_XBCT);
  ushort* XhT     = (ushort*)(ws + OFF_XHT);
  ushort* Bbf     = (ushort*)(ws + OFF_BBF);
  ushort* Cbf     = (ushort*)(ws + OFF_CBF);
  ushort* BTbf    = (ushort*)(ws + OFF_BTBF);
  float*  dAcs    = ws + OFF_DA;
  ushort* CBbf    = (ushort*)(ws + OFF_CB);
  ushort* prevP   = (ushort*)(ws + OFF_PREV);
  ushort* Ybf     = (ushort*)(ws + OFF_Y);
  ushort* o768bf  = (ushort*)(ws + OFF_O768);
  ushort* WsxT    = (ushort*)(ws + OFF_WSXT);
  ushort* WbcdtT  = (ushort*)(ws + OFF_WBCT);
  ushort* WoutT   = (ushort*)(ws + OFF_WOUT);
  ushort* bc_pre  = (ushort*)(ws + OFF_BCP);

  // 1: weight transposes
  k_prep<<<dim3(246), 256, 0, stream>>>(W_skip, W_xs, W_bcdt, W_out, WsxT, WbcdtT, WoutT);
  // 2: both input GEMMs in one launch (bf16 outputs)
  k_gemm_in<<<dim3(12, 16, 2), 256, 0, stream>>>(u1, u2, u2c1, u1c2, WsxT, WbcdtT, skipxs, bc_pre);
  // 3: conv (bf16 in/out)
  k_conv<<<dim3(1024, 2), 256, 0, stream>>>(skipxs, bc_pre, cxw, cxb, cbw, cbb, xbcT);
  // 4: all gathers + cumsum
  k_gather_all<<<dim3(592, 2), 256, 0, stream>>>(xbcT, dt_b, A_logs, XhT, Bbf, Cbf, BTbf, dAcs);
  // 5: CB (lower-tri) + states/scan
  k_scan_core<<<dim3(592), 256, 0, stream>>>(Cbf, Bbf, CBbf, BTbf, XhT, dAcs, prevP);
  // 6: Y (load-balanced remap; z==0 blocks skip phase A)
  k_y_mfma<<<dim3(2, 32, 8), 256, 0, stream>>>(CBbf, XhT, Cbf, prevP, dAcs, Ybf);
  // 7: combine
  k_combine<<<dim3(1024, 2), 256, 0, stream>>>(Ybf, xbcT, skipxs, Ds, normw, o768bf);
  // 8: out GEMM
  gemm64_bf16<<<dim3(6, 32), 256, 0, stream>>>(o768bf, WoutT, out, 2048, 384, 768);
}

// Round 19
// 106.817 us; speedup vs baseline: 1.4498x; 1.0433x over previous
//
#include <hip/hip_runtime.h>
#include <hip/hip_bf16.h>
#include <cstddef>

// ---------------- problem constants ----------------
#define LSEQ   1024
#define DM     384
#define DSSM   512
#define NSTATE 512
#define HK     32
#define HD     64
#define CHUNKSZ 256
#define NC     4
#define CBCDT  264
#define CTOT   776
#define DMLP   256

typedef __attribute__((ext_vector_type(8))) short short8;
typedef __attribute__((ext_vector_type(4))) float f32x4;

__device__ __forceinline__ float siluf(float x)    { return x / (1.f + expf(-x)); }
__device__ __forceinline__ float softplusf(float x){ return fmaxf(x, 0.f) + log1pf(expf(-fabsf(x))); }

__device__ __forceinline__ ushort f2bf(float f) {
  union { float f; unsigned u; } v; v.f = f;
  unsigned r = v.u + 0x7fffu + ((v.u >> 16) & 1u);
  return (ushort)(r >> 16);
}
__device__ __forceinline__ float bf2f(ushort h) {
  union { unsigned u; float f; } v; v.u = ((unsigned)h) << 16;
  return v.f;
}

__device__ __forceinline__ int dir_src(int k, int l) {
  switch (k) {
    case 0:  return l;
    case 1:  return ((l & 31) << 5) | (l >> 5);
    case 2:  return 1023 - l;
    default: { int lr = 1023 - l; return ((lr & 31) << 5) | (lr >> 5); }
  }
}

// ---------------- weight transpose-casts: grid 246 ----------------
__global__ __launch_bounds__(256) void k_prep(
    const float* __restrict__ W_skip, const float* __restrict__ W_xs,
    const float* __restrict__ W_bcdt, const float* __restrict__ W_out,
    ushort* __restrict__ WsxT, ushort* __restrict__ WbcdtT, ushort* __restrict__ WoutT)
{
  __shared__ __align__(16) ushort T[64 * 72];
  int bid = blockIdx.x;
  const int t = threadIdx.x;
  const float* src; ushort* dst; int N, ldd, nbx;
  if (bid < 96)        {            src = W_skip; dst = WsxT;                     N = 1024; ldd = 384; nbx = 16; }
  else if (bid < 144)  { bid -= 96; src = W_xs;   dst = WsxT + (size_t)1024*384;  N = 512;  ldd = 384; nbx = 8; }
  else if (bid < 174)  { bid -= 144; src = W_bcdt; dst = WbcdtT;                  N = 264;  ldd = 384; nbx = 5; }
  else                 { bid -= 174; src = W_out;  dst = WoutT;                   N = 384;  ldd = 768; nbx = 6; }
  const int n0 = (bid % nbx) * 64, k0 = (bid / nbx) * 64;
  const int rk = t >> 2, q = t & 3;
  const int k = k0 + rk;
  const float* srow = src + (size_t)k * N + n0 + q * 16;
#pragma unroll
  for (int i = 0; i < 16; ++i) {
    int n = n0 + q * 16 + i;
    T[(q * 16 + i) * 72 + rk] = (n < N) ? f2bf(srow[i]) : (ushort)0;
  }
  __syncthreads();
  int n = n0 + rk;
  if (n < N) {
    ushort* d = dst + (size_t)n * ldd + k0 + q * 16;
    *(uint4*)d       = *(const uint4*)&T[rk * 72 + q * 16];
    *(uint4*)(d + 8) = *(const uint4*)&T[rk * 72 + q * 16 + 8];
  }
}

// ---------------- f32-A GEMM body (cast in staging), 64x128 tile, LDS dbuf, bf16 out ----------------
__device__ __forceinline__ void gemm_f32a_body(
    ushort (*As)[64 * 72], ushort (*Bs)[128 * 72],
    const float* __restrict__ A0, const float* __restrict__ A1, int rows0,
    const ushort* __restrict__ BT, ushort* __restrict__ C, int N, int K)
{
  const int n0 = blockIdx.x * 128, m0 = blockIdx.y * 64;
  const int t = threadIdx.x, lane = t & 63, wv = t >> 6;
  const int wm = wv & 1, wn = wv >> 1;
  const int lrow = lane & 15, lk8 = (lane >> 4) * 8;
  const int rA4 = t >> 2, cA16 = (t & 3) * 16;     // A staging: 64 rows x 64 f32 cols
  const int rowL = t >> 1, cL = (t & 1) * 32;      // B staging: 128 rows x 64 bf16 cols
  const float* Af = (m0 < rows0) ? (A0 + (size_t)m0 * K) : (A1 + (size_t)(m0 - rows0) * K);
  const float* pa_src = Af + (size_t)rA4 * K + cA16;
  const int nB = n0 + rowL;
  const ushort* pb_src = BT + (size_t)nB * K + cL;
  const bool bval = (nB < N);
  float4 fa[4]; uint4 pb[4];
#define GAISSUE(k0) do { \
    _Pragma("unroll") for (int q2 = 0; q2 < 4; ++q2) fa[q2] = *(const float4*)(pa_src + (k0) + q2 * 4); \
    if (bval) { \
      pb[0] = *(const uint4*)(pb_src + (k0));      pb[1] = *(const uint4*)(pb_src + (k0) + 8); \
      pb[2] = *(const uint4*)(pb_src + (k0) + 16); pb[3] = *(const uint4*)(pb_src + (k0) + 24); \
    } else { uint4 z = {0,0,0,0}; pb[0]=z; pb[1]=z; pb[2]=z; pb[3]=z; } \
  } while(0)
  GAISSUE(0);
  f32x4 acc[2][4] = {};
  for (int k0 = 0; k0 < K; k0 += 64) {
    const int pbuf = (k0 >> 6) & 1;
#pragma unroll
    for (int q2 = 0; q2 < 4; ++q2) {
      ushort o[4] = { f2bf(fa[q2].x), f2bf(fa[q2].y), f2bf(fa[q2].z), f2bf(fa[q2].w) };
      *(uint2*)&As[pbuf][rA4 * 72 + cA16 + q2 * 4] = *(const uint2*)o;
    }
#pragma unroll
    for (int q2 = 0; q2 < 4; ++q2) *(uint4*)&Bs[pbuf][rowL * 72 + cL + q2 * 8] = pb[q2];
    __syncthreads();
    if (k0 + 64 < K) GAISSUE(k0 + 64);
#pragma unroll
    for (int sub = 0; sub < 2; ++sub) {
      const int ko = lk8 + sub * 32;
      short8 a[2], b[4];
#pragma unroll
      for (int f = 0; f < 2; ++f)
        a[f] = *(const short8*)&As[pbuf][(wm * 32 + 16 * f + lrow) * 72 + ko];
#pragma unroll
      for (int f = 0; f < 4; ++f)
        b[f] = *(const short8*)&Bs[pbuf][(wn * 64 + 16 * f + lrow) * 72 + ko];
#pragma unroll
      for (int fi = 0; fi < 2; ++fi)
#pragma unroll
        for (int fj = 0; fj < 4; ++fj)
          acc[fi][fj] = __builtin_amdgcn_mfma_f32_16x16x32_bf16(a[fi], b[fj], acc[fi][fj], 0, 0, 0);
    }
  }
#pragma unroll
  for (int fi = 0; fi < 2; ++fi) {
    int row0 = m0 + wm * 32 + 16 * fi + (lane >> 4) * 4;
#pragma unroll
    for (int fj = 0; fj < 4; ++fj) {
      int col = n0 + wn * 64 + 16 * fj + lrow;
      if (col < N)
#pragma unroll
        for (int rr = 0; rr < 4; ++rr)
          C[(size_t)(row0 + rr) * N + col] = f2bf(acc[fi][fj][rr]);
    }
  }
}

// ---------------- fused input GEMMs: z=0 skipxs (12x32), z=1 bcdt (3x32) ----------------
__global__ __launch_bounds__(256) void k_gemm_in(
    const float* __restrict__ u1, const float* __restrict__ u2,
    const float* __restrict__ uc1, const float* __restrict__ uc2,
    const ushort* __restrict__ WsxT, const ushort* __restrict__ WbcdtT,
    ushort* __restrict__ skipxs, ushort* __restrict__ bc_pre)
{
  __shared__ __align__(16) ushort As[2][64 * 72];
  __shared__ __align__(16) ushort Bs[2][128 * 72];
  if (blockIdx.z == 0) {
    gemm_f32a_body(As, Bs, u1, u2, 1024, WsxT, skipxs, 1536, 384);
  } else {
    if (blockIdx.x >= 3) return;
    gemm_f32a_body(As, Bs, uc1, uc2, 1024, WbcdtT, bc_pre, 264, 384);
  }
}

// ---------------- depthwise 3x3 conv + bias + SiLU; bf16 in/out; writes xbcT[s][m][c] ----------------
__global__ __launch_bounds__(256) void k_conv(
    const ushort* __restrict__ skipxs, const ushort* __restrict__ bc_pre,
    const float* __restrict__ wxs, const float* __restrict__ bxs,
    const float* __restrict__ wbc, const float* __restrict__ bbc,
    ushort* __restrict__ xbcT)
{
  const int m = blockIdx.x, s = blockIdx.y;
  const int h = m >> 5, w = m & 31;
  const ushort* xp = skipxs + (size_t)s * LSEQ * 1536 + 1024;
  const ushort* bp = bc_pre + (size_t)s * LSEQ * CBCDT;
  for (int c = threadIdx.x; c < CTOT; c += 256) {
    const ushort* src; int stride; const float* wt; float bias;
    if (c < DSSM) { src = xp + c; stride = 1536; wt = wxs + (size_t)c * 9; bias = bxs[c]; }
    else { int cb = c - DSSM; src = bp + cb; stride = CBCDT; wt = wbc + (size_t)cb * 9; bias = bbc[cb]; }
    float acc = bias;
#pragma unroll
    for (int dh = -1; dh <= 1; ++dh) {
      int h2 = h + dh; if (h2 < 0 || h2 > 31) continue;
#pragma unroll
      for (int dw = -1; dw <= 1; ++dw) {
        int w2 = w + dw; if (w2 < 0 || w2 > 31) continue;
        acc += bf2f(src[(size_t)(h2 * 32 + w2) * stride]) * wt[(dh + 1) * 3 + (dw + 1)];
      }
    }
    xbcT[((size_t)s * LSEQ + m) * CTOT + c] = f2bf(siluf(acc));
  }
}

// ---------------- fused gathers (bf16 xbcT): [0,512) Xh, [512,576) B/C/BT, [576,592) dA+cumsum ----------------
__global__ __launch_bounds__(256) void k_gather_all(
    const ushort* __restrict__ xbcT, const float* __restrict__ dt_bias,
    const float* __restrict__ A_logs,
    ushort* __restrict__ XhT, ushort* __restrict__ Bbf, ushort* __restrict__ Cbf,
    ushort* __restrict__ BT, float* __restrict__ dAcs)
{
  __shared__ __align__(16) ushort U[128 * 72];
  const int bid = blockIdx.x, s = blockIdx.y, t = threadIdx.x;
  if (bid < 512) {
    const int lt = bid & 15, kh = bid >> 4;
    const int k = kh >> 3, hh = kh & 7;
    const int r = t >> 2, q = t & 3;
    const int l = lt * 64 + r;
    const int m = dir_src(k, l);
    const ushort* row = xbcT + ((size_t)s * LSEQ + m) * CTOT;
    float dtv = softplusf(bf2f(row[768 + hh]) + dt_bias[kh]);
    const ushort* xp = row + hh * 64 + q * 16;
    ushort xv[16];
    *(uint4*)xv       = *(const uint4*)xp;
    *(uint4*)(xv + 8) = *(const uint4*)(xp + 8);
#pragma unroll
    for (int i = 0; i < 16; ++i)
      U[(q * 16 + i) * 72 + r] = f2bf(bf2f(xv[i]) * dtv);
    __syncthreads();
    ushort* dst = XhT + (((size_t)s * HK + kh) * HD + r) * LSEQ + lt * 64 + q * 16;
    *(uint4*)dst       = *(const uint4*)&U[r * 72 + q * 16];
    *(uint4*)(dst + 8) = *(const uint4*)&U[r * 72 + q * 16 + 8];
    return;
  }
  if (bid < 576) {
    const int idx = bid - 512;
    const int lt = idx & 15, k = idx >> 4;
    const int r = t >> 2, q = t & 3;
    const int l = lt * 64 + r;
    const int m = dir_src(k, l);
    const ushort* row = xbcT + ((size_t)s * LSEQ + m) * CTOT;
    {
      const ushort* bsrc = row + 512 + q * 32;
      ushort ub[32];
#pragma unroll
      for (int i2 = 0; i2 < 4; ++i2) *(uint4*)&ub[i2 * 8] = *(const uint4*)(bsrc + i2 * 8);
      ushort* bd = Bbf + ((size_t)s * LSEQ + l) * NSTATE + k * 128 + q * 32;
#pragma unroll
      for (int i2 = 0; i2 < 4; ++i2) *(uint4*)(bd + i2 * 8) = *(const uint4*)&ub[i2 * 8];
#pragma unroll
      for (int i = 0; i < 32; ++i) U[(q * 32 + i) * 72 + r] = ub[i];
    }
    {
      const ushort* csrc = row + 640 + q * 32;
      ushort uc[32];
#pragma unroll
      for (int i2 = 0; i2 < 4; ++i2) *(uint4*)&uc[i2 * 8] = *(const uint4*)(csrc + i2 * 8);
      ushort* cd = Cbf + ((size_t)s * LSEQ + l) * NSTATE + k * 128 + q * 32;
#pragma unroll
      for (int i2 = 0; i2 < 4; ++i2) *(uint4*)(cd + i2 * 8) = *(const uint4*)&uc[i2 * 8];
    }
    __syncthreads();
    {
      const int n = t >> 1, half = t & 1;
      ushort* dst = BT + ((size_t)s * NSTATE + k * 128 + n) * LSEQ + lt * 64 + half * 32;
      const ushort* src = &U[n * 72 + half * 32];
#pragma unroll
      for (int i2 = 0; i2 < 4; ++i2) *(uint4*)(dst + i2 * 8) = *(const uint4*)(src + i2 * 8);
    }
    return;
  }
  {
    float* Lf = (float*)U;
    const int idx = bid - 576;
    const int z = idx & 3, k = idx >> 2;
    const int m = dir_src(k, z * 256 + t);
    const ushort* rowdt = xbcT + ((size_t)s * LSEQ + m) * CTOT + 768;
    ushort dvu[8];
    *(uint4*)dvu = *(const uint4*)rowdt;
#pragma unroll
    for (int hh = 0; hh < 8; ++hh) {
      int kh = k * 8 + hh;
      float dAv = softplusf(bf2f(dvu[hh]) + dt_bias[kh]) * (-expf(A_logs[kh]));
      Lf[hh * 256 + t] = dAv;
    }
    __syncthreads();
    const int hh = t >> 5, seg = t & 31;
    float p[8]; float run = 0.f;
#pragma unroll
    for (int i = 0; i < 8; ++i) { run += Lf[hh * 256 + seg * 8 + i]; p[i] = run; }
    float sc = run, tot = run;
#pragma unroll
    for (int d = 1; d < 32; d <<= 1) {
      float o = __shfl_up(sc, d, 32);
      if (seg >= d) sc += o;
    }
    float off = sc - tot;
    float* dst = dAcs + ((size_t)s * HK + k * 8 + hh) * LSEQ + z * 256 + seg * 8;
#pragma unroll
    for (int i = 0; i < 8; ++i) dst[i] = p[i] + off;
  }
}

// ---------------- fused scan core: [0,80) CB lower-tri, [80,592) states+scan (LDS dbuf) ----------------
__global__ __launch_bounds__(256) void k_scan_core(
    const ushort* __restrict__ Cbf, const ushort* __restrict__ Bbf, ushort* __restrict__ CBbf,
    const ushort* __restrict__ BT, const ushort* __restrict__ XhT,
    const float* __restrict__ dAcs, ushort* __restrict__ prevP)
{
  __shared__ __align__(16) ushort As[2][64 * 72];
  __shared__ __align__(16) ushort Bs[2][64 * 72];
  __shared__ __align__(16) ushort Tr[64 * 72];
  __shared__ float decay[CHUNKSZ];
  const int bid = blockIdx.x, t = threadIdx.x;
  const int lane = t & 63, wv = t >> 6;
  const int lrow = lane & 15, lk8 = (lane >> 4) * 8;
  const int rA = t >> 2, cA = (t & 3) * 16;

  if (bid < 80) {
    const int sz = bid & 7, pidx = bid >> 3, s = sz >> 2, z = sz & 3;
    int it = 0; { while ((it + 1) * (it + 2) / 2 <= pidx) ++it; }
    const int jt = pidx - it * (it + 1) / 2;
    const ushort* Ap = Cbf + ((size_t)s * LSEQ + z * CHUNKSZ + it * 64 + rA) * NSTATE + cA;
    const ushort* Bp = Bbf + ((size_t)s * LSEQ + z * CHUNKSZ + jt * 64 + rA) * NSTATE + cA;
    uint4 qa[2], qb[2];
#define CBISSUE(k0) do { qa[0]=*(const uint4*)(Ap+(k0)); qa[1]=*(const uint4*)(Ap+(k0)+8); \
                         qb[0]=*(const uint4*)(Bp+(k0)); qb[1]=*(const uint4*)(Bp+(k0)+8); } while(0)
    CBISSUE(0);
    f32x4 acc[4] = {};
    for (int k0 = 0; k0 < NSTATE; k0 += 64) {
      const int pb2 = (k0 >> 6) & 1;
      *(uint4*)&As[pb2][rA * 72 + cA] = qa[0]; *(uint4*)&As[pb2][rA * 72 + cA + 8] = qa[1];
      *(uint4*)&Bs[pb2][rA * 72 + cA] = qb[0]; *(uint4*)&Bs[pb2][rA * 72 + cA + 8] = qb[1];
      __syncthreads();
      if (k0 + 64 < NSTATE) CBISSUE(k0 + 64);
#pragma unroll
      for (int sub = 0; sub < 2; ++sub) {
        const int ko = lk8 + sub * 32;
        short8 a = *(const short8*)&As[pb2][(16 * wv + lrow) * 72 + ko];
#pragma unroll
        for (int fj = 0; fj < 4; ++fj) {
          short8 b = *(const short8*)&Bs[pb2][(16 * fj + lrow) * 72 + ko];
          acc[fj] = __builtin_amdgcn_mfma_f32_16x16x32_bf16(a, b, acc[fj], 0, 0, 0);
        }
      }
    }
    ushort* Cp = CBbf + (size_t)sz * CHUNKSZ * CHUNKSZ;
    const int row0 = it * 64 + 16 * wv + (lane >> 4) * 4;
#pragma unroll
    for (int fj = 0; fj < 4; ++fj) {
      int col = jt * 64 + 16 * fj + lrow;
#pragma unroll
      for (int rr = 0; rr < 4; ++rr)
        Cp[(size_t)(row0 + rr) * CHUNKSZ + col] = f2bf(acc[fj][rr]);
    }
    return;
  }

  // states + inter-chunk scan -> prevP
  {
    const int idx = bid - 80;
    const int nh = idx & 7, kh = (idx >> 3) & 31, s = idx >> 8;
    const float* dA = dAcs + ((size_t)s * HK + kh) * LSEQ;
    float carry[4][4];
#pragma unroll
    for (int fj = 0; fj < 4; ++fj)
#pragma unroll
      for (int rr = 0; rr < 4; ++rr) carry[fj][rr] = 0.f;

    for (int z = 0; z < NC; ++z) {
      __syncthreads();
      const float dlast = dA[z * CHUNKSZ + CHUNKSZ - 1];
      decay[t] = __expf(dlast - dA[z * CHUNKSZ + t]);
      {
        const int n_base = 16 * wv + (lane >> 4) * 4;
#pragma unroll
        for (int fj = 0; fj < 4; ++fj) {
          const int p = 16 * fj + lrow;
#pragma unroll
          for (int rr = 0; rr < 4; ++rr)
            Tr[p * 72 + n_base + rr] = f2bf(carry[fj][rr]);
        }
      }
      __syncthreads();
      {
        const int sz = s * 4 + z;
        ushort* dst = prevP + (((size_t)sz * HK + kh) * HD + rA) * NSTATE + nh * 64 + cA;
        *(uint4*)dst       = *(const uint4*)&Tr[rA * 72 + cA];
        *(uint4*)(dst + 8) = *(const uint4*)&Tr[rA * 72 + cA + 8];
      }
      const ushort* Ap = BT + ((size_t)s * NSTATE + nh * 64 + rA) * LSEQ + z * CHUNKSZ + cA;
      const ushort* Xp = XhT + (((size_t)s * HK + kh) * HD + rA) * LSEQ + z * CHUNKSZ + cA;
      uint4 qa[2], qb[2];
#define SSISSUE(k0) do { qa[0]=*(const uint4*)(Ap+(k0)); qa[1]=*(const uint4*)(Ap+(k0)+8); \
                         qb[0]=*(const uint4*)(Xp+(k0)); qb[1]=*(const uint4*)(Xp+(k0)+8); } while(0)
      SSISSUE(0);
      f32x4 acc[4] = {};
      for (int k0 = 0; k0 < CHUNKSZ; k0 += 64) {
        const int pb2 = (k0 >> 6) & 1;
        *(uint4*)&As[pb2][rA * 72 + cA] = qa[0]; *(uint4*)&As[pb2][rA * 72 + cA + 8] = qa[1];
        {
          ushort tmp[16];
          *(uint4*)&tmp[0] = qb[0]; *(uint4*)&tmp[8] = qb[1];
#pragma unroll
          for (int i2 = 0; i2 < 8; ++i2) {
            int c = k0 + cA + 2 * i2;
            unsigned wpk = (unsigned)f2bf(bf2f(tmp[2 * i2]) * decay[c]) |
                           ((unsigned)f2bf(bf2f(tmp[2 * i2 + 1]) * decay[c + 1]) << 16);
            *(unsigned*)&Bs[pb2][rA * 72 + cA + 2 * i2] = wpk;
          }
        }
        __syncthreads();
        if (k0 + 64 < CHUNKSZ) SSISSUE(k0 + 64);
#pragma unroll
        for (int sub = 0; sub < 2; ++sub) {
          const int ko = lk8 + sub * 32;
          short8 a = *(const short8*)&As[pb2][(16 * wv + lrow) * 72 + ko];
#pragma unroll
          for (int fj = 0; fj < 4; ++fj) {
            short8 b = *(const short8*)&Bs[pb2][(16 * fj + lrow) * 72 + ko];
            acc[fj] = __builtin_amdgcn_mfma_f32_16x16x32_bf16(a, b, acc[fj], 0, 0, 0);
          }
        }
      }
      const float cdec = __expf(dlast);
#pragma unroll
      for (int fj = 0; fj < 4; ++fj)
#pragma unroll
        for (int rr = 0; rr < 4; ++rr)
          carry[fj][rr] = carry[fj][rr] * cdec + acc[fj][rr];
    }
  }
}

// ---------------- Y = Ydiag + Yoff (MFMA, LDS dbuf, bf16 out) ----------------
// Load-balance remap: co-resident blocks (f, f+256) get complementary (it, z)
__global__ __launch_bounds__(256) void k_y_mfma(
    const ushort* __restrict__ CBbf, const ushort* __restrict__ XhT,
    const ushort* __restrict__ Cbf, const ushort* __restrict__ prevP,
    const float* __restrict__ dAcs, ushort* __restrict__ Ybf)
{
  __shared__ __align__(16) ushort As[2][128 * 72];
  __shared__ __align__(16) ushort Bs[2][64 * 72];
  __shared__ float seg[CHUNKSZ];
  __shared__ float f2s[CHUNKSZ];
  const int szr = blockIdx.z, kh = blockIdx.y;
  const int s = szr >> 2, zr = szr & 3;
  const int z = (zr + 2 * s) & 3;
  const int it = blockIdx.x ^ s;
  const int sz = s * 4 + z;
  const int t = threadIdx.x, lane = t & 63, wv = t >> 6;
  const int lrow = lane & 15, lk8 = (lane >> 4) * 8;
  const int i0 = it * 128;
  const float* dAp = dAcs + ((size_t)s * HK + kh) * LSEQ + z * CHUNKSZ;
  seg[t] = dAp[t];
  __syncthreads();
  f2s[t] = __expf(seg[(t >> 5) << 5] - seg[t]);
  __syncthreads();

  const int rA = t >> 1, cA = (t & 1) * 32;
  const int rB = t >> 2, cB = (t & 3) * 16;
  f32x4 acc[2][4] = {};
  uint4 qa[4], qb[2];

  // phase A: acc = C @ prev^T  (skip for z==0: prev == 0)
  if (z != 0) {
    const ushort* Cp = Cbf + ((size_t)s * LSEQ + z * CHUNKSZ + i0 + rA) * NSTATE + cA;
    const ushort* Pp = prevP + (((size_t)sz * HK + kh) * HD + rB) * NSTATE + cB;
#define YISSUEA(k0) do { \
    qa[0]=*(const uint4*)(Cp+(k0));    qa[1]=*(const uint4*)(Cp+(k0)+8); \
    qa[2]=*(const uint4*)(Cp+(k0)+16); qa[3]=*(const uint4*)(Cp+(k0)+24); \
    qb[0]=*(const uint4*)(Pp+(k0));    qb[1]=*(const uint4*)(Pp+(k0)+8); } while(0)
    YISSUEA(0);
    for (int k0 = 0; k0 < NSTATE; k0 += 64) {
      const int pb2 = (k0 >> 6) & 1;
#pragma unroll
      for (int q2 = 0; q2 < 4; ++q2) *(uint4*)&As[pb2][rA * 72 + cA + q2 * 8] = qa[q2];
      *(uint4*)&Bs[pb2][rB * 72 + cB] = qb[0]; *(uint4*)&Bs[pb2][rB * 72 + cB + 8] = qb[1];
      __syncthreads();
      if (k0 + 64 < NSTATE) YISSUEA(k0 + 64);
#pragma unroll
      for (int sub = 0; sub < 2; ++sub) {
        const int ko = lk8 + sub * 32;
        short8 a[2], b[4];
#pragma unroll
        for (int f = 0; f < 2; ++f) a[f] = *(const short8*)&As[pb2][(32 * wv + 16 * f + lrow) * 72 + ko];
#pragma unroll
        for (int f = 0; f < 4; ++f) b[f] = *(const short8*)&Bs[pb2][(16 * f + lrow) * 72 + ko];
#pragma unroll
        for (int fi = 0; fi < 2; ++fi)
#pragma unroll
          for (int fj = 0; fj < 4; ++fj)
            acc[fi][fj] = __builtin_amdgcn_mfma_f32_16x16x32_bf16(a[fi], b[fj], acc[fi][fj], 0, 0, 0);
      }
    }
  }

  // prefetch phase-B tile 0 while rescaling
  const ushort* CBp = CBbf + ((size_t)sz * CHUNKSZ + i0 + rA) * CHUNKSZ;
  const ushort* Xp = XhT + (((size_t)s * HK + kh) * HD + rB) * LSEQ + z * CHUNKSZ + cB;
  const int nktB = 2 * it + 2;
#define YISSUEB(kt) do { const ushort* sa = CBp + (kt) * 64 + cA; \
    qa[0]=*(const uint4*)sa;      qa[1]=*(const uint4*)(sa+8); \
    qa[2]=*(const uint4*)(sa+16); qa[3]=*(const uint4*)(sa+24); \
    qb[0]=*(const uint4*)(Xp+(kt)*64); qb[1]=*(const uint4*)(Xp+(kt)*64+8); } while(0)
  YISSUEB(0);

  // scale Yoff rows by e^{seg_i}
  if (z != 0) {
#pragma unroll
    for (int fi = 0; fi < 2; ++fi) {
      int rloc = 32 * wv + 16 * fi + (lane >> 4) * 4;
#pragma unroll
      for (int rr = 0; rr < 4; ++rr) {
        float e = __expf(seg[i0 + rloc + rr]);
#pragma unroll
        for (int fj = 0; fj < 4; ++fj) acc[fi][fj][rr] *= e;
      }
    }
  }

  // phase B: Ydiag (slice-factored, CB bf16)
  for (int kt = 0; kt < nktB; ++kt) {
    const int pb2 = kt & 1;
    {
      const int i = i0 + rA;
      const int jbase = kt * 64 + cA;
      if (i >= jbase) {
        float f1 = __expf(seg[i] - seg[jbase]);
        ushort tmp[32];
        *(uint4*)&tmp[0] = qa[0]; *(uint4*)&tmp[8] = qa[1];
        *(uint4*)&tmp[16] = qa[2]; *(uint4*)&tmp[24] = qa[3];
#pragma unroll
        for (int c = 0; c < 32; c += 2) {
          int j = jbase + c;
          float v0 = (j     <= i) ? bf2f(tmp[c])     * f1 : 0.f;
          float v1 = (j + 1 <= i) ? bf2f(tmp[c + 1]) * f1 : 0.f;
          *(unsigned*)&As[pb2][rA * 72 + cA + c] = (unsigned)f2bf(v0) | ((unsigned)f2bf(v1) << 16);
        }
      } else {
        uint4 zz = {0, 0, 0, 0};
#pragma unroll
        for (int q2 = 0; q2 < 4; ++q2) *(uint4*)&As[pb2][rA * 72 + cA + q2 * 8] = zz;
      }
    }
    {
      ushort tmp[16];
      *(uint4*)&tmp[0] = qb[0]; *(uint4*)&tmp[8] = qb[1];
#pragma unroll
      for (int i2 = 0; i2 < 8; ++i2) {
        int j = kt * 64 + cB + 2 * i2;
        unsigned wpk = (unsigned)f2bf(bf2f(tmp[2 * i2]) * f2s[j]) |
                       ((unsigned)f2bf(bf2f(tmp[2 * i2 + 1]) * f2s[j + 1]) << 16);
        *(unsigned*)&Bs[pb2][rB * 72 + cB + 2 * i2] = wpk;
      }
    }
    __syncthreads();
    if (kt + 1 < nktB) YISSUEB(kt + 1);
#pragma unroll
    for (int sub = 0; sub < 2; ++sub) {
      if (2 * kt + sub <= 4 * it + wv) {
        const int ko = lk8 + sub * 32;
        short8 a[2], b[4];
#pragma unroll
        for (int f = 0; f < 2; ++f) a[f] = *(const short8*)&As[pb2][(32 * wv + 16 * f + lrow) * 72 + ko];
#pragma unroll
        for (int f = 0; f < 4; ++f) b[f] = *(const short8*)&Bs[pb2][(16 * f + lrow) * 72 + ko];
#pragma unroll
        for (int fi = 0; fi < 2; ++fi)
#pragma unroll
          for (int fj = 0; fj < 4; ++fj)
            acc[fi][fj] = __builtin_amdgcn_mfma_f32_16x16x32_bf16(a[fi], b[fj], acc[fi][fj], 0, 0, 0);
      }
    }
  }

  ushort* Yp = Ybf + (((size_t)s * LSEQ + z * CHUNKSZ + i0) * HK + kh) * HD;
#pragma unroll
  for (int fi = 0; fi < 2; ++fi) {
    int row0 = 32 * wv + 16 * fi + (lane >> 4) * 4;
#pragma unroll
    for (int fj = 0; fj < 4; ++fj) {
      int col = 16 * fj + lrow;
#pragma unroll
      for (int rr = 0; rr < 4; ++rr)
        Yp[(size_t)(row0 + rr) * (HK * HD) + col] = f2bf(acc[fi][fj][rr]);
    }
  }
}

// ---------------- combine 4 directions + D*x + gated RMSNorm + MLP half (bf16 in/out) ----------------
__global__ __launch_bounds__(256) void k_combine(
    const ushort* __restrict__ Ybf, const ushort* __restrict__ xbcT,
    const ushort* __restrict__ skipxs, const float* __restrict__ Ds,
    const float* __restrict__ normw, ushort* __restrict__ o768bf)
{
  const int m = blockIdx.x, s = blockIdx.y, t = threadIdx.x;
  const int h = m >> 5, w = m & 31;
  const int l0 = m, l1 = (w << 5) | h, l2 = 1023 - m, l3 = 1023 - ((w << 5) | h);
  const ushort* Yb = Ybf + (size_t)s * LSEQ * (HK * HD);
  const ushort* xrow = xbcT + ((size_t)s * LSEQ + m) * CTOT;
  const ushort* srow = skipxs + ((size_t)s * LSEQ + m) * 1536;

  float g[2];
  float ss = 0.f;
#pragma unroll
  for (int q = 0; q < 2; ++q) {
    int d = t + q * 256;
    int hh = d >> 6, p = d & 63;
    float dsum = Ds[hh] + Ds[hh + 8] + Ds[hh + 16] + Ds[hh + 24];
    float val = bf2f(Yb[((size_t)l0 * HK + hh) * HD + p])
              + bf2f(Yb[((size_t)l1 * HK + 8 + hh) * HD + p])
              + bf2f(Yb[((size_t)l2 * HK + 16 + hh) * HD + p])
              + bf2f(Yb[((size_t)l3 * HK + 24 + hh) * HD + p])
              + bf2f(xrow[d]) * dsum;
    float zv = bf2f(srow[512 + d]);
    g[q] = val * siluf(zv);
    ss += g[q] * g[q];
  }
  for (int off = 32; off > 0; off >>= 1) ss += __shfl_down(ss, off, 64);
  __shared__ float red[4];
  if ((t & 63) == 0) red[t >> 6] = ss;
  __syncthreads();
  float total = red[0] + red[1] + red[2] + red[3];
  float scale = rsqrtf(total * (1.f / 512.f) + 1e-5f);

  ushort* orow = o768bf + ((size_t)s * LSEQ + m) * 768;
#pragma unroll
  for (int q = 0; q < 2; ++q) {
    int d = t + q * 256;
    orow[256 + d] = f2bf(g[q] * scale * normw[d]);
  }
  float z0 = bf2f(srow[t]), x0 = bf2f(srow[256 + t]);
  orow[t] = f2bf(siluf(z0) * x0);
}

// ---------------- 64x64-tile bf16 GEMM (out GEMM), LDS dbuf ----------------
__global__ __launch_bounds__(256) void gemm64_bf16(
    const ushort* __restrict__ A, const ushort* __restrict__ BT,
    float* __restrict__ C, int M, int N, int K)
{
  __shared__ __align__(16) ushort As[2][64 * 72];
  __shared__ __align__(16) ushort Bs[2][64 * 72];
  const int n0 = blockIdx.x * 64, m0 = blockIdx.y * 64;
  const int t = threadIdx.x, lane = t & 63, wv = t >> 6;
  const int wm = wv & 1, wn = wv >> 1;
  const int lrow = lane & 15, lk8 = (lane >> 4) * 8;
  const int rowL = t >> 2, cL = (t & 3) * 16;
  const ushort* pa_src = A + (size_t)(m0 + rowL) * K + cL;
  const int nB = n0 + rowL;
  const ushort* pb_src = BT + (size_t)nB * K + cL;
  const bool bval = (nB < N);
  uint4 pa[2], pb[2];
#define G64ISSUE(k0) do { \
    pa[0]=*(const uint4*)(pa_src+(k0)); pa[1]=*(const uint4*)(pa_src+(k0)+8); \
    if (bval) { pb[0]=*(const uint4*)(pb_src+(k0)); pb[1]=*(const uint4*)(pb_src+(k0)+8); } \
    else { uint4 z={0,0,0,0}; pb[0]=z; pb[1]=z; } } while(0)
  G64ISSUE(0);
  f32x4 acc[2][2] = {};
  for (int k0 = 0; k0 < K; k0 += 64) {
    const int pbuf = (k0 >> 6) & 1;
    *(uint4*)&As[pbuf][rowL * 72 + cL] = pa[0]; *(uint4*)&As[pbuf][rowL * 72 + cL + 8] = pa[1];
    *(uint4*)&Bs[pbuf][rowL * 72 + cL] = pb[0]; *(uint4*)&Bs[pbuf][rowL * 72 + cL + 8] = pb[1];
    __syncthreads();
    if (k0 + 64 < K) G64ISSUE(k0 + 64);
#pragma unroll
    for (int sub = 0; sub < 2; ++sub) {
      const int ko = lk8 + sub * 32;
      short8 a[2], b[2];
#pragma unroll
      for (int f = 0; f < 2; ++f) {
        a[f] = *(const short8*)&As[pbuf][(wm * 32 + 16 * f + lrow) * 72 + ko];
        b[f] = *(const short8*)&Bs[pbuf][(wn * 32 + 16 * f + lrow) * 72 + ko];
      }
#pragma unroll
      for (int fi = 0; fi < 2; ++fi)
#pragma unroll
        for (int fj = 0; fj < 2; ++fj)
          acc[fi][fj] = __builtin_amdgcn_mfma_f32_16x16x32_bf16(a[fi], b[fj], acc[fi][fj], 0, 0, 0);
    }
  }
#pragma unroll
  for (int fi = 0; fi < 2; ++fi) {
    int row0 = m0 + wm * 32 + 16 * fi + (lane >> 4) * 4;
#pragma unroll
    for (int fj = 0; fj < 2; ++fj) {
      int col = n0 + wn * 32 + 16 * fj + lrow;
      if (col < N)
#pragma unroll
        for (int rr = 0; rr < 4; ++rr)
          C[(size_t)(row0 + rr) * N + col] = acc[fi][fj][rr];
    }
  }
}

// ---------------- workspace layout (float units; bf16 buffers use half) ----------------
constexpr size_t OFF_SKIPXS = 0;                         // bf16 2048*1536 -> 1572864 f
constexpr size_t OFF_XBCT   = 3145728;                   // bf16 2048*776 -> 794624 f (slot kept)
constexpr size_t OFF_XHT    = OFF_XBCT + 1589248;        // bf16 -> 2097152 f
constexpr size_t OFF_BBF    = OFF_XHT + 2097152;         // 524288
constexpr size_t OFF_CBF    = OFF_BBF + 524288;          // 524288
constexpr size_t OFF_BTBF   = OFF_CBF + 524288;          // 524288
constexpr size_t OFF_DA     = OFF_BTBF + 524288;         // 65536
constexpr size_t OFF_CB     = OFF_DA + 65536;            // bf16 -> 262144 f
constexpr size_t OFF_PREV   = OFF_CB + 262144;           // bf16 -> 4194304 f
constexpr size_t OFF_Y      = OFF_PREV + 4194304;        // bf16 -> 2097152 f
constexpr size_t OFF_O768   = OFF_Y + 2097152;           // bf16 -> 786432 f
constexpr size_t OFF_WSXT   = OFF_O768 + 786432;         // 294912
constexpr size_t OFF_WBCT   = OFF_WSXT + 294912;         // 50688
constexpr size_t OFF_WOUT   = OFF_WBCT + 50688;          // 147456
constexpr size_t OFF_BCP    = OFF_PREV;                  // overlay: bc_pre bf16 (dead before prevP)

extern "C" void kernel_launch(void* const* d_in, const int* in_sizes, int n_in,
                              void* d_out, int out_size, void* d_ws, size_t ws_size,
                              hipStream_t stream)
{
  const float* u1     = (const float*)d_in[0];
  const float* u2     = (const float*)d_in[1];
  const float* u2c1   = (const float*)d_in[2];
  const float* u1c2   = (const float*)d_in[3];
  const float* W_skip = (const float*)d_in[4];
  const float* W_xs   = (const float*)d_in[5];
  const float* W_bcdt = (const float*)d_in[6];
  const float* cxw    = (const float*)d_in[7];
  const float* cxb    = (const float*)d_in[8];
  const float* cbw    = (const float*)d_in[9];
  const float* cbb    = (const float*)d_in[10];
  const float* Ds     = (const float*)d_in[11];
  const float* normw  = (const float*)d_in[12];
  const float* W_out  = (const float*)d_in[13];
  const float* dt_b   = (const float*)d_in[14];
  const float* A_logs = (const float*)d_in[15];
  float* out = (float*)d_out;
  float* ws  = (float*)d_ws;

  ushort* skipxs  = (ushort*)(ws + OFF_SKIPXS);
  ushort* xbcT    = (ushort*)(ws + OFF_XBCT);
  ushort* XhT     = (ushort*)(ws + OFF_XHT);
  ushort* Bbf     = (ushort*)(ws + OFF_BBF);
  ushort* Cbf     = (ushort*)(ws + OFF_CBF);
  ushort* BTbf    = (ushort*)(ws + OFF_BTBF);
  float*  dAcs    = ws + OFF_DA;
  ushort* CBbf    = (ushort*)(ws + OFF_CB);
  ushort* prevP   = (ushort*)(ws + OFF_PREV);
  ushort* Ybf     = (ushort*)(ws + OFF_Y);
  ushort* o768bf  = (ushort*)(ws + OFF_O768);
  ushort* WsxT    = (ushort*)(ws + OFF_WSXT);
  ushort* WbcdtT  = (ushort*)(ws + OFF_WBCT);
  ushort* WoutT   = (ushort*)(ws + OFF_WOUT);
  ushort* bc_pre  = (ushort*)(ws + OFF_BCP);

  // 1: weight transposes
  k_prep<<<dim3(246), 256, 0, stream>>>(W_skip, W_xs, W_bcdt, W_out, WsxT, WbcdtT, WoutT);
  // 2: both input GEMMs in one launch (64-row tiles -> 480 blocks, ~2/CU)
  k_gemm_in<<<dim3(12, 32, 2), 256, 0, stream>>>(u1, u2, u2c1, u1c2, WsxT, WbcdtT, skipxs, bc_pre);
  // 3: conv (bf16 in/out)
  k_conv<<<dim3(1024, 2), 256, 0, stream>>>(skipxs, bc_pre, cxw, cxb, cbw, cbb, xbcT);
  // 4: all gathers + cumsum
  k_gather_all<<<dim3(592, 2), 256, 0, stream>>>(xbcT, dt_b, A_logs, XhT, Bbf, Cbf, BTbf, dAcs);
  // 5: CB (lower-tri) + states/scan
  k_scan_core<<<dim3(592), 256, 0, stream>>>(Cbf, Bbf, CBbf, BTbf, XhT, dAcs, prevP);
  // 6: Y (load-balanced remap; z==0 blocks skip phase A)
  k_y_mfma<<<dim3(2, 32, 8), 256, 0, stream>>>(CBbf, XhT, Cbf, prevP, dAcs, Ybf);
  // 7: combine
  k_combine<<<dim3(1024, 2), 256, 0, stream>>>(Ybf, xbcT, skipxs, Ds, normw, o768bf);
  // 8: out GEMM
  gemm64_bf16<<<dim3(6, 32), 256, 0, stream>>>(o768bf, WoutT, out, 2048, 384, 768);
}

// Round 20
// 100.115 us; speedup vs baseline: 1.5468x; 1.0669x over previous
//
#include <hip/hip_runtime.h>
#include <hip/hip_bf16.h>
#include <cstddef>

// ---------------- problem constants ----------------
#define LSEQ   1024
#define DM     384
#define DSSM   512
#define NSTATE 512
#define HK     32
#define HD     64
#define CHUNKSZ 256
#define NC     4
#define CBCDT  264
#define CTOT   776
#define DMLP   256

typedef __attribute__((ext_vector_type(8))) short short8;
typedef __attribute__((ext_vector_type(4))) float f32x4;

__device__ __forceinline__ float siluf(float x)    { return x / (1.f + expf(-x)); }
__device__ __forceinline__ float softplusf(float x){ return fmaxf(x, 0.f) + log1pf(expf(-fabsf(x))); }

__device__ __forceinline__ ushort f2bf(float f) {
  union { float f; unsigned u; } v; v.f = f;
  unsigned r = v.u + 0x7fffu + ((v.u >> 16) & 1u);
  return (ushort)(r >> 16);
}
__device__ __forceinline__ float bf2f(ushort h) {
  union { unsigned u; float f; } v; v.u = ((unsigned)h) << 16;
  return v.f;
}

__device__ __forceinline__ int dir_src(int k, int l) {
  switch (k) {
    case 0:  return l;
    case 1:  return ((l & 31) << 5) | (l >> 5);
    case 2:  return 1023 - l;
    default: { int lr = 1023 - l; return ((lr & 31) << 5) | (lr >> 5); }
  }
}

// ---------------- weight transpose-casts: grid 246 ----------------
__global__ __launch_bounds__(256) void k_prep(
    const float* __restrict__ W_skip, const float* __restrict__ W_xs,
    const float* __restrict__ W_bcdt, const float* __restrict__ W_out,
    ushort* __restrict__ WsxT, ushort* __restrict__ WbcdtT, ushort* __restrict__ WoutT)
{
  __shared__ __align__(16) ushort T[64 * 72];
  int bid = blockIdx.x;
  const int t = threadIdx.x;
  const float* src; ushort* dst; int N, ldd, nbx;
  if (bid < 96)        {            src = W_skip; dst = WsxT;                     N = 1024; ldd = 384; nbx = 16; }
  else if (bid < 144)  { bid -= 96; src = W_xs;   dst = WsxT + (size_t)1024*384;  N = 512;  ldd = 384; nbx = 8; }
  else if (bid < 174)  { bid -= 144; src = W_bcdt; dst = WbcdtT;                  N = 264;  ldd = 384; nbx = 5; }
  else                 { bid -= 174; src = W_out;  dst = WoutT;                   N = 384;  ldd = 768; nbx = 6; }
  const int n0 = (bid % nbx) * 64, k0 = (bid / nbx) * 64;
  const int rk = t >> 2, q = t & 3;
  const int k = k0 + rk;
  const float* srow = src + (size_t)k * N + n0 + q * 16;
#pragma unroll
  for (int i = 0; i < 16; ++i) {
    int n = n0 + q * 16 + i;
    T[(q * 16 + i) * 72 + rk] = (n < N) ? f2bf(srow[i]) : (ushort)0;
  }
  __syncthreads();
  int n = n0 + rk;
  if (n < N) {
    ushort* d = dst + (size_t)n * ldd + k0 + q * 16;
    *(uint4*)d       = *(const uint4*)&T[rk * 72 + q * 16];
    *(uint4*)(d + 8) = *(const uint4*)&T[rk * 72 + q * 16 + 8];
  }
}

// ---------------- f32-A GEMM body (cast in staging), 64x128 tile, LDS dbuf, bf16 out ----------------
__device__ __forceinline__ void gemm_f32a_body(
    ushort (*As)[64 * 72], ushort (*Bs)[128 * 72],
    const float* __restrict__ A0, const float* __restrict__ A1, int rows0,
    const ushort* __restrict__ BT, ushort* __restrict__ C, int N, int K)
{
  const int n0 = blockIdx.x * 128, m0 = blockIdx.y * 64;
  const int t = threadIdx.x, lane = t & 63, wv = t >> 6;
  const int wm = wv & 1, wn = wv >> 1;
  const int lrow = lane & 15, lk8 = (lane >> 4) * 8;
  const int rA4 = t >> 2, cA16 = (t & 3) * 16;     // A staging: 64 rows x 64 f32 cols
  const int rowL = t >> 1, cL = (t & 1) * 32;      // B staging: 128 rows x 64 bf16 cols
  const float* Af = (m0 < rows0) ? (A0 + (size_t)m0 * K) : (A1 + (size_t)(m0 - rows0) * K);
  const float* pa_src = Af + (size_t)rA4 * K + cA16;
  const int nB = n0 + rowL;
  const ushort* pb_src = BT + (size_t)nB * K + cL;
  const bool bval = (nB < N);
  float4 fa[4]; uint4 pb[4];
#define GAISSUE(k0) do { \
    _Pragma("unroll") for (int q2 = 0; q2 < 4; ++q2) fa[q2] = *(const float4*)(pa_src + (k0) + q2 * 4); \
    if (bval) { \
      pb[0] = *(const uint4*)(pb_src + (k0));      pb[1] = *(const uint4*)(pb_src + (k0) + 8); \
      pb[2] = *(const uint4*)(pb_src + (k0) + 16); pb[3] = *(const uint4*)(pb_src + (k0) + 24); \
    } else { uint4 z = {0,0,0,0}; pb[0]=z; pb[1]=z; pb[2]=z; pb[3]=z; } \
  } while(0)
  GAISSUE(0);
  f32x4 acc[2][4] = {};
  for (int k0 = 0; k0 < K; k0 += 64) {
    const int pbuf = (k0 >> 6) & 1;
#pragma unroll
    for (int q2 = 0; q2 < 4; ++q2) {
      ushort o[4] = { f2bf(fa[q2].x), f2bf(fa[q2].y), f2bf(fa[q2].z), f2bf(fa[q2].w) };
      *(uint2*)&As[pbuf][rA4 * 72 + cA16 + q2 * 4] = *(const uint2*)o;
    }
#pragma unroll
    for (int q2 = 0; q2 < 4; ++q2) *(uint4*)&Bs[pbuf][rowL * 72 + cL + q2 * 8] = pb[q2];
    __syncthreads();
    if (k0 + 64 < K) GAISSUE(k0 + 64);
#pragma unroll
    for (int sub = 0; sub < 2; ++sub) {
      const int ko = lk8 + sub * 32;
      short8 a[2], b[4];
#pragma unroll
      for (int f = 0; f < 2; ++f)
        a[f] = *(const short8*)&As[pbuf][(wm * 32 + 16 * f + lrow) * 72 + ko];
#pragma unroll
      for (int f = 0; f < 4; ++f)
        b[f] = *(const short8*)&Bs[pbuf][(wn * 64 + 16 * f + lrow) * 72 + ko];
#pragma unroll
      for (int fi = 0; fi < 2; ++fi)
#pragma unroll
        for (int fj = 0; fj < 4; ++fj)
          acc[fi][fj] = __builtin_amdgcn_mfma_f32_16x16x32_bf16(a[fi], b[fj], acc[fi][fj], 0, 0, 0);
    }
  }
#pragma unroll
  for (int fi = 0; fi < 2; ++fi) {
    int row0 = m0 + wm * 32 + 16 * fi + (lane >> 4) * 4;
#pragma unroll
    for (int fj = 0; fj < 4; ++fj) {
      int col = n0 + wn * 64 + 16 * fj + lrow;
      if (col < N)
#pragma unroll
        for (int rr = 0; rr < 4; ++rr)
          C[(size_t)(row0 + rr) * N + col] = f2bf(acc[fi][fj][rr]);
    }
  }
}

// ---------------- fused input GEMMs: z=0 skipxs (12x32), z=1 bcdt (3x32) ----------------
__global__ __launch_bounds__(256) void k_gemm_in(
    const float* __restrict__ u1, const float* __restrict__ u2,
    const float* __restrict__ uc1, const float* __restrict__ uc2,
    const ushort* __restrict__ WsxT, const ushort* __restrict__ WbcdtT,
    ushort* __restrict__ skipxs, ushort* __restrict__ bc_pre)
{
  __shared__ __align__(16) ushort As[2][64 * 72];
  __shared__ __align__(16) ushort Bs[2][128 * 72];
  if (blockIdx.z == 0) {
    gemm_f32a_body(As, Bs, u1, u2, 1024, WsxT, skipxs, 1536, 384);
  } else {
    if (blockIdx.x >= 3) return;
    gemm_f32a_body(As, Bs, uc1, uc2, 1024, WbcdtT, bc_pre, 264, 384);
  }
}

// ---------------- depthwise 3x3 conv + bias + SiLU; bf16 in/out; writes xbcT[s][m][c] ----------------
__global__ __launch_bounds__(256) void k_conv(
    const ushort* __restrict__ skipxs, const ushort* __restrict__ bc_pre,
    const float* __restrict__ wxs, const float* __restrict__ bxs,
    const float* __restrict__ wbc, const float* __restrict__ bbc,
    ushort* __restrict__ xbcT)
{
  const int m = blockIdx.x, s = blockIdx.y;
  const int h = m >> 5, w = m & 31;
  const ushort* xp = skipxs + (size_t)s * LSEQ * 1536 + 1024;
  const ushort* bp = bc_pre + (size_t)s * LSEQ * CBCDT;
  for (int c = threadIdx.x; c < CTOT; c += 256) {
    const ushort* src; int stride; const float* wt; float bias;
    if (c < DSSM) { src = xp + c; stride = 1536; wt = wxs + (size_t)c * 9; bias = bxs[c]; }
    else { int cb = c - DSSM; src = bp + cb; stride = CBCDT; wt = wbc + (size_t)cb * 9; bias = bbc[cb]; }
    float acc = bias;
#pragma unroll
    for (int dh = -1; dh <= 1; ++dh) {
      int h2 = h + dh; if (h2 < 0 || h2 > 31) continue;
#pragma unroll
      for (int dw = -1; dw <= 1; ++dw) {
        int w2 = w + dw; if (w2 < 0 || w2 > 31) continue;
        acc += bf2f(src[(size_t)(h2 * 32 + w2) * stride]) * wt[(dh + 1) * 3 + (dw + 1)];
      }
    }
    xbcT[((size_t)s * LSEQ + m) * CTOT + c] = f2bf(siluf(acc));
  }
}

// ---------------- fused gathers (bf16 xbcT): [0,512) Xh, [512,576) B/C/BT, [576,592) dA+cumsum ----------------
__global__ __launch_bounds__(256) void k_gather_all(
    const ushort* __restrict__ xbcT, const float* __restrict__ dt_bias,
    const float* __restrict__ A_logs,
    ushort* __restrict__ XhT, ushort* __restrict__ Bbf, ushort* __restrict__ Cbf,
    ushort* __restrict__ BT, float* __restrict__ dAcs)
{
  __shared__ __align__(16) ushort U[128 * 72];
  const int bid = blockIdx.x, s = blockIdx.y, t = threadIdx.x;
  if (bid < 512) {
    const int lt = bid & 15, kh = bid >> 4;
    const int k = kh >> 3, hh = kh & 7;
    const int r = t >> 2, q = t & 3;
    const int l = lt * 64 + r;
    const int m = dir_src(k, l);
    const ushort* row = xbcT + ((size_t)s * LSEQ + m) * CTOT;
    float dtv = softplusf(bf2f(row[768 + hh]) + dt_bias[kh]);
    const ushort* xp = row + hh * 64 + q * 16;
    ushort xv[16];
    *(uint4*)xv       = *(const uint4*)xp;
    *(uint4*)(xv + 8) = *(const uint4*)(xp + 8);
#pragma unroll
    for (int i = 0; i < 16; ++i)
      U[(q * 16 + i) * 72 + r] = f2bf(bf2f(xv[i]) * dtv);
    __syncthreads();
    ushort* dst = XhT + (((size_t)s * HK + kh) * HD + r) * LSEQ + lt * 64 + q * 16;
    *(uint4*)dst       = *(const uint4*)&U[r * 72 + q * 16];
    *(uint4*)(dst + 8) = *(const uint4*)&U[r * 72 + q * 16 + 8];
    return;
  }
  if (bid < 576) {
    const int idx = bid - 512;
    const int lt = idx & 15, k = idx >> 4;
    const int r = t >> 2, q = t & 3;
    const int l = lt * 64 + r;
    const int m = dir_src(k, l);
    const ushort* row = xbcT + ((size_t)s * LSEQ + m) * CTOT;
    {
      const ushort* bsrc = row + 512 + q * 32;
      ushort ub[32];
#pragma unroll
      for (int i2 = 0; i2 < 4; ++i2) *(uint4*)&ub[i2 * 8] = *(const uint4*)(bsrc + i2 * 8);
      ushort* bd = Bbf + ((size_t)s * LSEQ + l) * NSTATE + k * 128 + q * 32;
#pragma unroll
      for (int i2 = 0; i2 < 4; ++i2) *(uint4*)(bd + i2 * 8) = *(const uint4*)&ub[i2 * 8];
#pragma unroll
      for (int i = 0; i < 32; ++i) U[(q * 32 + i) * 72 + r] = ub[i];
    }
    {
      const ushort* csrc = row + 640 + q * 32;
      ushort uc[32];
#pragma unroll
      for (int i2 = 0; i2 < 4; ++i2) *(uint4*)&uc[i2 * 8] = *(const uint4*)(csrc + i2 * 8);
      ushort* cd = Cbf + ((size_t)s * LSEQ + l) * NSTATE + k * 128 + q * 32;
#pragma unroll
      for (int i2 = 0; i2 < 4; ++i2) *(uint4*)(cd + i2 * 8) = *(const uint4*)&uc[i2 * 8];
    }
    __syncthreads();
    {
      const int n = t >> 1, half = t & 1;
      ushort* dst = BT + ((size_t)s * NSTATE + k * 128 + n) * LSEQ + lt * 64 + half * 32;
      const ushort* src = &U[n * 72 + half * 32];
#pragma unroll
      for (int i2 = 0; i2 < 4; ++i2) *(uint4*)(dst + i2 * 8) = *(const uint4*)(src + i2 * 8);
    }
    return;
  }
  {
    float* Lf = (float*)U;
    const int idx = bid - 576;
    const int z = idx & 3, k = idx >> 2;
    const int m = dir_src(k, z * 256 + t);
    const ushort* rowdt = xbcT + ((size_t)s * LSEQ + m) * CTOT + 768;
    ushort dvu[8];
    *(uint4*)dvu = *(const uint4*)rowdt;
#pragma unroll
    for (int hh = 0; hh < 8; ++hh) {
      int kh = k * 8 + hh;
      float dAv = softplusf(bf2f(dvu[hh]) + dt_bias[kh]) * (-expf(A_logs[kh]));
      Lf[hh * 256 + t] = dAv;
    }
    __syncthreads();
    const int hh = t >> 5, seg = t & 31;
    float p[8]; float run = 0.f;
#pragma unroll
    for (int i = 0; i < 8; ++i) { run += Lf[hh * 256 + seg * 8 + i]; p[i] = run; }
    float sc = run, tot = run;
#pragma unroll
    for (int d = 1; d < 32; d <<= 1) {
      float o = __shfl_up(sc, d, 32);
      if (seg >= d) sc += o;
    }
    float off = sc - tot;
    float* dst = dAcs + ((size_t)s * HK + k * 8 + hh) * LSEQ + z * 256 + seg * 8;
#pragma unroll
    for (int i = 0; i < 8; ++i) dst[i] = p[i] + off;
  }
}

// ---------------- fused scan core: [0,80) CB lower-tri, [80,592) states+scan (LDS dbuf) ----------------
__global__ __launch_bounds__(256) void k_scan_core(
    const ushort* __restrict__ Cbf, const ushort* __restrict__ Bbf, ushort* __restrict__ CBbf,
    const ushort* __restrict__ BT, const ushort* __restrict__ XhT,
    const float* __restrict__ dAcs, ushort* __restrict__ prevP)
{
  __shared__ __align__(16) ushort As[2][64 * 72];
  __shared__ __align__(16) ushort Bs[2][64 * 72];
  __shared__ __align__(16) ushort Tr[64 * 72];
  __shared__ float decay[CHUNKSZ];
  const int bid = blockIdx.x, t = threadIdx.x;
  const int lane = t & 63, wv = t >> 6;
  const int lrow = lane & 15, lk8 = (lane >> 4) * 8;
  const int rA = t >> 2, cA = (t & 3) * 16;

  if (bid < 80) {
    const int sz = bid & 7, pidx = bid >> 3, s = sz >> 2, z = sz & 3;
    int it = 0; { while ((it + 1) * (it + 2) / 2 <= pidx) ++it; }
    const int jt = pidx - it * (it + 1) / 2;
    const ushort* Ap = Cbf + ((size_t)s * LSEQ + z * CHUNKSZ + it * 64 + rA) * NSTATE + cA;
    const ushort* Bp = Bbf + ((size_t)s * LSEQ + z * CHUNKSZ + jt * 64 + rA) * NSTATE + cA;
    uint4 qa[2], qb[2];
#define CBISSUE(k0) do { qa[0]=*(const uint4*)(Ap+(k0)); qa[1]=*(const uint4*)(Ap+(k0)+8); \
                         qb[0]=*(const uint4*)(Bp+(k0)); qb[1]=*(const uint4*)(Bp+(k0)+8); } while(0)
    CBISSUE(0);
    f32x4 acc[4] = {};
    for (int k0 = 0; k0 < NSTATE; k0 += 64) {
      const int pb2 = (k0 >> 6) & 1;
      *(uint4*)&As[pb2][rA * 72 + cA] = qa[0]; *(uint4*)&As[pb2][rA * 72 + cA + 8] = qa[1];
      *(uint4*)&Bs[pb2][rA * 72 + cA] = qb[0]; *(uint4*)&Bs[pb2][rA * 72 + cA + 8] = qb[1];
      __syncthreads();
      if (k0 + 64 < NSTATE) CBISSUE(k0 + 64);
#pragma unroll
      for (int sub = 0; sub < 2; ++sub) {
        const int ko = lk8 + sub * 32;
        short8 a = *(const short8*)&As[pb2][(16 * wv + lrow) * 72 + ko];
#pragma unroll
        for (int fj = 0; fj < 4; ++fj) {
          short8 b = *(const short8*)&Bs[pb2][(16 * fj + lrow) * 72 + ko];
          acc[fj] = __builtin_amdgcn_mfma_f32_16x16x32_bf16(a, b, acc[fj], 0, 0, 0);
        }
      }
    }
    ushort* Cp = CBbf + (size_t)sz * CHUNKSZ * CHUNKSZ;
    const int row0 = it * 64 + 16 * wv + (lane >> 4) * 4;
#pragma unroll
    for (int fj = 0; fj < 4; ++fj) {
      int col = jt * 64 + 16 * fj + lrow;
#pragma unroll
      for (int rr = 0; rr < 4; ++rr)
        Cp[(size_t)(row0 + rr) * CHUNKSZ + col] = f2bf(acc[fj][rr]);
    }
    return;
  }

  // states + inter-chunk scan -> prevP
  {
    const int idx = bid - 80;
    const int nh = idx & 7, kh = (idx >> 3) & 31, s = idx >> 8;
    const float* dA = dAcs + ((size_t)s * HK + kh) * LSEQ;
    float carry[4][4];
#pragma unroll
    for (int fj = 0; fj < 4; ++fj)
#pragma unroll
      for (int rr = 0; rr < 4; ++rr) carry[fj][rr] = 0.f;

    for (int z = 0; z < NC; ++z) {
      __syncthreads();
      const float dlast = dA[z * CHUNKSZ + CHUNKSZ - 1];
      decay[t] = __expf(dlast - dA[z * CHUNKSZ + t]);
      {
        const int n_base = 16 * wv + (lane >> 4) * 4;
#pragma unroll
        for (int fj = 0; fj < 4; ++fj) {
          const int p = 16 * fj + lrow;
#pragma unroll
          for (int rr = 0; rr < 4; ++rr)
            Tr[p * 72 + n_base + rr] = f2bf(carry[fj][rr]);
        }
      }
      __syncthreads();
      {
        const int sz = s * 4 + z;
        ushort* dst = prevP + (((size_t)sz * HK + kh) * HD + rA) * NSTATE + nh * 64 + cA;
        *(uint4*)dst       = *(const uint4*)&Tr[rA * 72 + cA];
        *(uint4*)(dst + 8) = *(const uint4*)&Tr[rA * 72 + cA + 8];
      }
      const ushort* Ap = BT + ((size_t)s * NSTATE + nh * 64 + rA) * LSEQ + z * CHUNKSZ + cA;
      const ushort* Xp = XhT + (((size_t)s * HK + kh) * HD + rA) * LSEQ + z * CHUNKSZ + cA;
      uint4 qa[2], qb[2];
#define SSISSUE(k0) do { qa[0]=*(const uint4*)(Ap+(k0)); qa[1]=*(const uint4*)(Ap+(k0)+8); \
                         qb[0]=*(const uint4*)(Xp+(k0)); qb[1]=*(const uint4*)(Xp+(k0)+8); } while(0)
      SSISSUE(0);
      f32x4 acc[4] = {};
      for (int k0 = 0; k0 < CHUNKSZ; k0 += 64) {
        const int pb2 = (k0 >> 6) & 1;
        *(uint4*)&As[pb2][rA * 72 + cA] = qa[0]; *(uint4*)&As[pb2][rA * 72 + cA + 8] = qa[1];
        {
          ushort tmp[16];
          *(uint4*)&tmp[0] = qb[0]; *(uint4*)&tmp[8] = qb[1];
#pragma unroll
          for (int i2 = 0; i2 < 8; ++i2) {
            int c = k0 + cA + 2 * i2;
            unsigned wpk = (unsigned)f2bf(bf2f(tmp[2 * i2]) * decay[c]) |
                           ((unsigned)f2bf(bf2f(tmp[2 * i2 + 1]) * decay[c + 1]) << 16);
            *(unsigned*)&Bs[pb2][rA * 72 + cA + 2 * i2] = wpk;
          }
        }
        __syncthreads();
        if (k0 + 64 < CHUNKSZ) SSISSUE(k0 + 64);
#pragma unroll
        for (int sub = 0; sub < 2; ++sub) {
          const int ko = lk8 + sub * 32;
          short8 a = *(const short8*)&As[pb2][(16 * wv + lrow) * 72 + ko];
#pragma unroll
          for (int fj = 0; fj < 4; ++fj) {
            short8 b = *(const short8*)&Bs[pb2][(16 * fj + lrow) * 72 + ko];
            acc[fj] = __builtin_amdgcn_mfma_f32_16x16x32_bf16(a, b, acc[fj], 0, 0, 0);
          }
        }
      }
      const float cdec = __expf(dlast);
#pragma unroll
      for (int fj = 0; fj < 4; ++fj)
#pragma unroll
        for (int rr = 0; rr < 4; ++rr)
          carry[fj][rr] = carry[fj][rr] * cdec + acc[fj][rr];
    }
  }
}

// ---------------- Y = Ydiag + Yoff (MFMA, LDS dbuf, bf16 out) ----------------
// Load-balance remap: co-resident blocks (f, f+256) get complementary (it, z)
__global__ __launch_bounds__(256) void k_y_mfma(
    const ushort* __restrict__ CBbf, const ushort* __restrict__ XhT,
    const ushort* __restrict__ Cbf, const ushort* __restrict__ prevP,
    const float* __restrict__ dAcs, ushort* __restrict__ Ybf)
{
  __shared__ __align__(16) ushort As[2][128 * 72];
  __shared__ __align__(16) ushort Bs[2][64 * 72];
  __shared__ float seg[CHUNKSZ];
  __shared__ float f2s[CHUNKSZ];
  const int szr = blockIdx.z, kh = blockIdx.y;
  const int s = szr >> 2, zr = szr & 3;
  const int z = (zr + 2 * s) & 3;
  const int it = blockIdx.x ^ s;
  const int sz = s * 4 + z;
  const int t = threadIdx.x, lane = t & 63, wv = t >> 6;
  const int lrow = lane & 15, lk8 = (lane >> 4) * 8;
  const int i0 = it * 128;
  const float* dAp = dAcs + ((size_t)s * HK + kh) * LSEQ + z * CHUNKSZ;
  seg[t] = dAp[t];
  __syncthreads();
  f2s[t] = __expf(seg[(t >> 5) << 5] - seg[t]);
  __syncthreads();

  const int rA = t >> 1, cA = (t & 1) * 32;
  const int rB = t >> 2, cB = (t & 3) * 16;
  f32x4 acc[2][4] = {};
  uint4 qa[4], qb[2];

  // phase A: acc = C @ prev^T  (skip for z==0: prev == 0)
  if (z != 0) {
    const ushort* Cp = Cbf + ((size_t)s * LSEQ + z * CHUNKSZ + i0 + rA) * NSTATE + cA;
    const ushort* Pp = prevP + (((size_t)sz * HK + kh) * HD + rB) * NSTATE + cB;
#define YISSUEA(k0) do { \
    qa[0]=*(const uint4*)(Cp+(k0));    qa[1]=*(const uint4*)(Cp+(k0)+8); \
    qa[2]=*(const uint4*)(Cp+(k0)+16); qa[3]=*(const uint4*)(Cp+(k0)+24); \
    qb[0]=*(const uint4*)(Pp+(k0));    qb[1]=*(const uint4*)(Pp+(k0)+8); } while(0)
    YISSUEA(0);
    for (int k0 = 0; k0 < NSTATE; k0 += 64) {
      const int pb2 = (k0 >> 6) & 1;
#pragma unroll
      for (int q2 = 0; q2 < 4; ++q2) *(uint4*)&As[pb2][rA * 72 + cA + q2 * 8] = qa[q2];
      *(uint4*)&Bs[pb2][rB * 72 + cB] = qb[0]; *(uint4*)&Bs[pb2][rB * 72 + cB + 8] = qb[1];
      __syncthreads();
      if (k0 + 64 < NSTATE) YISSUEA(k0 + 64);
#pragma unroll
      for (int sub = 0; sub < 2; ++sub) {
        const int ko = lk8 + sub * 32;
        short8 a[2], b[4];
#pragma unroll
        for (int f = 0; f < 2; ++f) a[f] = *(const short8*)&As[pb2][(32 * wv + 16 * f + lrow) * 72 + ko];
#pragma unroll
        for (int f = 0; f < 4; ++f) b[f] = *(const short8*)&Bs[pb2][(16 * f + lrow) * 72 + ko];
#pragma unroll
        for (int fi = 0; fi < 2; ++fi)
#pragma unroll
          for (int fj = 0; fj < 4; ++fj)
            acc[fi][fj] = __builtin_amdgcn_mfma_f32_16x16x32_bf16(a[fi], b[fj], acc[fi][fj], 0, 0, 0);
      }
    }
  }

  // prefetch phase-B tile 0 while rescaling
  const ushort* CBp = CBbf + ((size_t)sz * CHUNKSZ + i0 + rA) * CHUNKSZ;
  const ushort* Xp = XhT + (((size_t)s * HK + kh) * HD + rB) * LSEQ + z * CHUNKSZ + cB;
  const int nktB = 2 * it + 2;
#define YISSUEB(kt) do { const ushort* sa = CBp + (kt) * 64 + cA; \
    qa[0]=*(const uint4*)sa;      qa[1]=*(const uint4*)(sa+8); \
    qa[2]=*(const uint4*)(sa+16); qa[3]=*(const uint4*)(sa+24); \
    qb[0]=*(const uint4*)(Xp+(kt)*64); qb[1]=*(const uint4*)(Xp+(kt)*64+8); } while(0)
  YISSUEB(0);

  // scale Yoff rows by e^{seg_i}
  if (z != 0) {
#pragma unroll
    for (int fi = 0; fi < 2; ++fi) {
      int rloc = 32 * wv + 16 * fi + (lane >> 4) * 4;
#pragma unroll
      for (int rr = 0; rr < 4; ++rr) {
        float e = __expf(seg[i0 + rloc + rr]);
#pragma unroll
        for (int fj = 0; fj < 4; ++fj) acc[fi][fj][rr] *= e;
      }
    }
  }

  // phase B: Ydiag (slice-factored, CB bf16)
  for (int kt = 0; kt < nktB; ++kt) {
    const int pb2 = kt & 1;
    {
      const int i = i0 + rA;
      const int jbase = kt * 64 + cA;
      if (i >= jbase) {
        float f1 = __expf(seg[i] - seg[jbase]);
        ushort tmp[32];
        *(uint4*)&tmp[0] = qa[0]; *(uint4*)&tmp[8] = qa[1];
        *(uint4*)&tmp[16] = qa[2]; *(uint4*)&tmp[24] = qa[3];
#pragma unroll
        for (int c = 0; c < 32; c += 2) {
          int j = jbase + c;
          float v0 = (j     <= i) ? bf2f(tmp[c])     * f1 : 0.f;
          float v1 = (j + 1 <= i) ? bf2f(tmp[c + 1]) * f1 : 0.f;
          *(unsigned*)&As[pb2][rA * 72 + cA + c] = (unsigned)f2bf(v0) | ((unsigned)f2bf(v1) << 16);
        }
      } else {
        uint4 zz = {0, 0, 0, 0};
#pragma unroll
        for (int q2 = 0; q2 < 4; ++q2) *(uint4*)&As[pb2][rA * 72 + cA + q2 * 8] = zz;
      }
    }
    {
      ushort tmp[16];
      *(uint4*)&tmp[0] = qb[0]; *(uint4*)&tmp[8] = qb[1];
#pragma unroll
      for (int i2 = 0; i2 < 8; ++i2) {
        int j = kt * 64 + cB + 2 * i2;
        unsigned wpk = (unsigned)f2bf(bf2f(tmp[2 * i2]) * f2s[j]) |
                       ((unsigned)f2bf(bf2f(tmp[2 * i2 + 1]) * f2s[j + 1]) << 16);
        *(unsigned*)&Bs[pb2][rB * 72 + cB + 2 * i2] = wpk;
      }
    }
    __syncthreads();
    if (kt + 1 < nktB) YISSUEB(kt + 1);
#pragma unroll
    for (int sub = 0; sub < 2; ++sub) {
      if (2 * kt + sub <= 4 * it + wv) {
        const int ko = lk8 + sub * 32;
        short8 a[2], b[4];
#pragma unroll
        for (int f = 0; f < 2; ++f) a[f] = *(const short8*)&As[pb2][(32 * wv + 16 * f + lrow) * 72 + ko];
#pragma unroll
        for (int f = 0; f < 4; ++f) b[f] = *(const short8*)&Bs[pb2][(16 * f + lrow) * 72 + ko];
#pragma unroll
        for (int fi = 0; fi < 2; ++fi)
#pragma unroll
          for (int fj = 0; fj < 4; ++fj)
            acc[fi][fj] = __builtin_amdgcn_mfma_f32_16x16x32_bf16(a[fi], b[fj], acc[fi][fj], 0, 0, 0);
      }
    }
  }

  ushort* Yp = Ybf + (((size_t)s * LSEQ + z * CHUNKSZ + i0) * HK + kh) * HD;
#pragma unroll
  for (int fi = 0; fi < 2; ++fi) {
    int row0 = 32 * wv + 16 * fi + (lane >> 4) * 4;
#pragma unroll
    for (int fj = 0; fj < 4; ++fj) {
      int col = 16 * fj + lrow;
#pragma unroll
      for (int rr = 0; rr < 4; ++rr)
        Yp[(size_t)(row0 + rr) * (HK * HD) + col] = f2bf(acc[fi][fj][rr]);
    }
  }
}

// ---------------- combine 4 directions + D*x + gated RMSNorm + MLP half (bf16 in/out) ----------------
__global__ __launch_bounds__(256) void k_combine(
    const ushort* __restrict__ Ybf, const ushort* __restrict__ xbcT,
    const ushort* __restrict__ skipxs, const float* __restrict__ Ds,
    const float* __restrict__ normw, ushort* __restrict__ o768bf)
{
  const int m = blockIdx.x, s = blockIdx.y, t = threadIdx.x;
  const int h = m >> 5, w = m & 31;
  const int l0 = m, l1 = (w << 5) | h, l2 = 1023 - m, l3 = 1023 - ((w << 5) | h);
  const ushort* Yb = Ybf + (size_t)s * LSEQ * (HK * HD);
  const ushort* xrow = xbcT + ((size_t)s * LSEQ + m) * CTOT;
  const ushort* srow = skipxs + ((size_t)s * LSEQ + m) * 1536;

  float g[2];
  float ss = 0.f;
#pragma unroll
  for (int q = 0; q < 2; ++q) {
    int d = t + q * 256;
    int hh = d >> 6, p = d & 63;
    float dsum = Ds[hh] + Ds[hh + 8] + Ds[hh + 16] + Ds[hh + 24];
    float val = bf2f(Yb[((size_t)l0 * HK + hh) * HD + p])
              + bf2f(Yb[((size_t)l1 * HK + 8 + hh) * HD + p])
              + bf2f(Yb[((size_t)l2 * HK + 16 + hh) * HD + p])
              + bf2f(Yb[((size_t)l3 * HK + 24 + hh) * HD + p])
              + bf2f(xrow[d]) * dsum;
    float zv = bf2f(srow[512 + d]);
    g[q] = val * siluf(zv);
    ss += g[q] * g[q];
  }
  for (int off = 32; off > 0; off >>= 1) ss += __shfl_down(ss, off, 64);
  __shared__ float red[4];
  if ((t & 63) == 0) red[t >> 6] = ss;
  __syncthreads();
  float total = red[0] + red[1] + red[2] + red[3];
  float scale = rsqrtf(total * (1.f / 512.f) + 1e-5f);

  ushort* orow = o768bf + ((size_t)s * LSEQ + m) * 768;
#pragma unroll
  for (int q = 0; q < 2; ++q) {
    int d = t + q * 256;
    orow[256 + d] = f2bf(g[q] * scale * normw[d]);
  }
  float z0 = bf2f(srow[t]), x0 = bf2f(srow[256 + t]);
  orow[t] = f2bf(siluf(z0) * x0);
}

// ---------------- 32x64-tile bf16 GEMM (out GEMM), LDS dbuf, grid (6,64) ----------------
__global__ __launch_bounds__(256) void gemm64_bf16(
    const ushort* __restrict__ A, const ushort* __restrict__ BT,
    float* __restrict__ C, int M, int N, int K)
{
  __shared__ __align__(16) ushort As[2][32 * 72];
  __shared__ __align__(16) ushort Bs[2][64 * 72];
  const int n0 = blockIdx.x * 64, m0 = blockIdx.y * 32;
  const int t = threadIdx.x, lane = t & 63, wv = t >> 6;
  const int wm = wv & 1, wn = wv >> 1;
  const int lrow = lane & 15, lk8 = (lane >> 4) * 8;
  const int rA8 = t >> 3, cA8 = (t & 7) * 8;     // A staging: 32 rows x 64 cols
  const int rB4 = t >> 2, cB16 = (t & 3) * 16;   // B staging: 64 rows x 64 cols
  const ushort* pa_src = A + (size_t)(m0 + rA8) * K + cA8;
  const int nB = n0 + rB4;
  const ushort* pb_src = BT + (size_t)nB * K + cB16;
  const bool bval = (nB < N);
  uint4 pa[1], pb[2];
#define G64ISSUE(k0) do { \
    pa[0]=*(const uint4*)(pa_src+(k0)); \
    if (bval) { pb[0]=*(const uint4*)(pb_src+(k0)); pb[1]=*(const uint4*)(pb_src+(k0)+8); } \
    else { uint4 z={0,0,0,0}; pb[0]=z; pb[1]=z; } } while(0)
  G64ISSUE(0);
  f32x4 acc[2] = {};
  for (int k0 = 0; k0 < K; k0 += 64) {
    const int pbuf = (k0 >> 6) & 1;
    *(uint4*)&As[pbuf][rA8 * 72 + cA8] = pa[0];
    *(uint4*)&Bs[pbuf][rB4 * 72 + cB16] = pb[0]; *(uint4*)&Bs[pbuf][rB4 * 72 + cB16 + 8] = pb[1];
    __syncthreads();
    if (k0 + 64 < K) G64ISSUE(k0 + 64);
#pragma unroll
    for (int sub = 0; sub < 2; ++sub) {
      const int ko = lk8 + sub * 32;
      short8 a = *(const short8*)&As[pbuf][(wm * 16 + lrow) * 72 + ko];
#pragma unroll
      for (int fj = 0; fj < 2; ++fj) {
        short8 b = *(const short8*)&Bs[pbuf][(wn * 32 + 16 * fj + lrow) * 72 + ko];
        acc[fj] = __builtin_amdgcn_mfma_f32_16x16x32_bf16(a, b, acc[fj], 0, 0, 0);
      }
    }
  }
#pragma unroll
  for (int fj = 0; fj < 2; ++fj) {
    int row0 = m0 + wm * 16 + (lane >> 4) * 4;
    int col = n0 + wn * 32 + 16 * fj + lrow;
    if (col < N)
#pragma unroll
      for (int rr = 0; rr < 4; ++rr)
        C[(size_t)(row0 + rr) * N + col] = acc[fj][rr];
  }
}

// ---------------- workspace layout (float units; bf16 buffers use half) ----------------
constexpr size_t OFF_SKIPXS = 0;                         // bf16 2048*1536 -> 1572864 f
constexpr size_t OFF_XBCT   = 3145728;                   // bf16 2048*776 -> 794624 f (slot kept)
constexpr size_t OFF_XHT    = OFF_XBCT + 1589248;        // bf16 -> 2097152 f
constexpr size_t OFF_BBF    = OFF_XHT + 2097152;         // 524288
constexpr size_t OFF_CBF    = OFF_BBF + 524288;          // 524288
constexpr size_t OFF_BTBF   = OFF_CBF + 524288;          // 524288
constexpr size_t OFF_DA     = OFF_BTBF + 524288;         // 65536
constexpr size_t OFF_CB     = OFF_DA + 65536;            // bf16 -> 262144 f
constexpr size_t OFF_PREV   = OFF_CB + 262144;           // bf16 -> 4194304 f
constexpr size_t OFF_Y      = OFF_PREV + 4194304;        // bf16 -> 2097152 f
constexpr size_t OFF_O768   = OFF_Y + 2097152;           // bf16 -> 786432 f
constexpr size_t OFF_WSXT   = OFF_O768 + 786432;         // 294912
constexpr size_t OFF_WBCT   = OFF_WSXT + 294912;         // 50688
constexpr size_t OFF_WOUT   = OFF_WBCT + 50688;          // 147456
constexpr size_t OFF_BCP    = OFF_PREV;                  // overlay: bc_pre bf16 (dead before prevP)

extern "C" void kernel_launch(void* const* d_in, const int* in_sizes, int n_in,
                              void* d_out, int out_size, void* d_ws, size_t ws_size,
                              hipStream_t stream)
{
  const float* u1     = (const float*)d_in[0];
  const float* u2     = (const float*)d_in[1];
  const float* u2c1   = (const float*)d_in[2];
  const float* u1c2   = (const float*)d_in[3];
  const float* W_skip = (const float*)d_in[4];
  const float* W_xs   = (const float*)d_in[5];
  const float* W_bcdt = (const float*)d_in[6];
  const float* cxw    = (const float*)d_in[7];
  const float* cxb    = (const float*)d_in[8];
  const float* cbw    = (const float*)d_in[9];
  const float* cbb    = (const float*)d_in[10];
  const float* Ds     = (const float*)d_in[11];
  const float* normw  = (const float*)d_in[12];
  const float* W_out  = (const float*)d_in[13];
  const float* dt_b   = (const float*)d_in[14];
  const float* A_logs = (const float*)d_in[15];
  float* out = (float*)d_out;
  float* ws  = (float*)d_ws;

  ushort* skipxs  = (ushort*)(ws + OFF_SKIPXS);
  ushort* xbcT    = (ushort*)(ws + OFF_XBCT);
  ushort* XhT     = (ushort*)(ws + OFF_XHT);
  ushort* Bbf     = (ushort*)(ws + OFF_BBF);
  ushort* Cbf     = (ushort*)(ws + OFF_CBF);
  ushort* BTbf    = (ushort*)(ws + OFF_BTBF);
  float*  dAcs    = ws + OFF_DA;
  ushort* CBbf    = (ushort*)(ws + OFF_CB);
  ushort* prevP   = (ushort*)(ws + OFF_PREV);
  ushort* Ybf     = (ushort*)(ws + OFF_Y);
  ushort* o768bf  = (ushort*)(ws + OFF_O768);
  ushort* WsxT    = (ushort*)(ws + OFF_WSXT);
  ushort* WbcdtT  = (ushort*)(ws + OFF_WBCT);
  ushort* WoutT   = (ushort*)(ws + OFF_WOUT);
  ushort* bc_pre  = (ushort*)(ws + OFF_BCP);

  // 1: weight transposes
  k_prep<<<dim3(246), 256, 0, stream>>>(W_skip, W_xs, W_bcdt, W_out, WsxT, WbcdtT, WoutT);
  // 2: both input GEMMs in one launch (64-row tiles -> 480 blocks, ~2/CU)
  k_gemm_in<<<dim3(12, 32, 2), 256, 0, stream>>>(u1, u2, u2c1, u1c2, WsxT, WbcdtT, skipxs, bc_pre);
  // 3: conv (bf16 in/out)
  k_conv<<<dim3(1024, 2), 256, 0, stream>>>(skipxs, bc_pre, cxw, cxb, cbw, cbb, xbcT);
  // 4: all gathers + cumsum
  k_gather_all<<<dim3(592, 2), 256, 0, stream>>>(xbcT, dt_b, A_logs, XhT, Bbf, Cbf, BTbf, dAcs);
  // 5: CB (lower-tri) + states/scan
  k_scan_core<<<dim3(592), 256, 0, stream>>>(Cbf, Bbf, CBbf, BTbf, XhT, dAcs, prevP);
  // 6: Y (load-balanced remap; z==0 blocks skip phase A)
  k_y_mfma<<<dim3(2, 32, 8), 256, 0, stream>>>(CBbf, XhT, Cbf, prevP, dAcs, Ybf);
  // 7: combine
  k_combine<<<dim3(1024, 2), 256, 0, stream>>>(Ybf, xbcT, skipxs, Ds, normw, o768bf);
  // 8: out GEMM (32-row tiles -> 384 blocks, ~1.5/CU)
  gemm64_bf16<<<dim3(6, 64), 256, 0, stream>>>(o768bf, WoutT, out, 2048, 384, 768);
}

// Round 21
// 98.881 us; speedup vs baseline: 1.5661x; 1.0125x over previous
//
#include <hip/hip_runtime.h>
#include <hip/hip_bf16.h>
#include <cstddef>

// ---------------- problem constants ----------------
#define LSEQ   1024
#define DM     384
#define DSSM   512
#define NSTATE 512
#define HK     32
#define HD     64
#define CHUNKSZ 256
#define NC     4
#define CBCDT  264
#define CTOT   776
#define DMLP   256

typedef __attribute__((ext_vector_type(8))) short short8;
typedef __attribute__((ext_vector_type(4))) float f32x4;

__device__ __forceinline__ float siluf(float x)    { return x / (1.f + expf(-x)); }
__device__ __forceinline__ float softplusf(float x){ return fmaxf(x, 0.f) + log1pf(expf(-fabsf(x))); }

__device__ __forceinline__ ushort f2bf(float f) {
  union { float f; unsigned u; } v; v.f = f;
  unsigned r = v.u + 0x7fffu + ((v.u >> 16) & 1u);
  return (ushort)(r >> 16);
}
__device__ __forceinline__ float bf2f(ushort h) {
  union { unsigned u; float f; } v; v.u = ((unsigned)h) << 16;
  return v.f;
}

__device__ __forceinline__ int dir_src(int k, int l) {
  switch (k) {
    case 0:  return l;
    case 1:  return ((l & 31) << 5) | (l >> 5);
    case 2:  return 1023 - l;
    default: { int lr = 1023 - l; return ((lr & 31) << 5) | (lr >> 5); }
  }
}

// ---------------- weight transpose-casts: grid 246 ----------------
__global__ __launch_bounds__(256) void k_prep(
    const float* __restrict__ W_skip, const float* __restrict__ W_xs,
    const float* __restrict__ W_bcdt, const float* __restrict__ W_out,
    ushort* __restrict__ WsxT, ushort* __restrict__ WbcdtT, ushort* __restrict__ WoutT)
{
  __shared__ __align__(16) ushort T[64 * 72];
  int bid = blockIdx.x;
  const int t = threadIdx.x;
  const float* src; ushort* dst; int N, ldd, nbx;
  if (bid < 96)        {            src = W_skip; dst = WsxT;                     N = 1024; ldd = 384; nbx = 16; }
  else if (bid < 144)  { bid -= 96; src = W_xs;   dst = WsxT + (size_t)1024*384;  N = 512;  ldd = 384; nbx = 8; }
  else if (bid < 174)  { bid -= 144; src = W_bcdt; dst = WbcdtT;                  N = 264;  ldd = 384; nbx = 5; }
  else                 { bid -= 174; src = W_out;  dst = WoutT;                   N = 384;  ldd = 768; nbx = 6; }
  const int n0 = (bid % nbx) * 64, k0 = (bid / nbx) * 64;
  const int rk = t >> 2, q = t & 3;
  const int k = k0 + rk;
  const float* srow = src + (size_t)k * N + n0 + q * 16;
#pragma unroll
  for (int i = 0; i < 16; ++i) {
    int n = n0 + q * 16 + i;
    T[(q * 16 + i) * 72 + rk] = (n < N) ? f2bf(srow[i]) : (ushort)0;
  }
  __syncthreads();
  int n = n0 + rk;
  if (n < N) {
    ushort* d = dst + (size_t)n * ldd + k0 + q * 16;
    *(uint4*)d       = *(const uint4*)&T[rk * 72 + q * 16];
    *(uint4*)(d + 8) = *(const uint4*)&T[rk * 72 + q * 16 + 8];
  }
}

// ---------------- f32-A GEMM body (cast in staging), 64x64 tile, LDS dbuf, bf16 out ----------------
__device__ __forceinline__ void gemm_f32a_body(
    ushort (*As)[64 * 72], ushort (*Bs)[64 * 72],
    const float* __restrict__ A0, const float* __restrict__ A1, int rows0,
    const ushort* __restrict__ BT, ushort* __restrict__ C, int N, int K)
{
  const int n0 = blockIdx.x * 64, m0 = blockIdx.y * 64;
  const int t = threadIdx.x, lane = t & 63, wv = t >> 6;
  const int wm = wv & 1, wn = wv >> 1;
  const int lrow = lane & 15, lk8 = (lane >> 4) * 8;
  const int rA4 = t >> 2, cA16 = (t & 3) * 16;     // A staging: 64 rows x 64 f32 cols
  const int rB4 = t >> 2, cB16 = (t & 3) * 16;     // B staging: 64 rows x 64 bf16 cols
  const float* Af = (m0 < rows0) ? (A0 + (size_t)m0 * K) : (A1 + (size_t)(m0 - rows0) * K);
  const float* pa_src = Af + (size_t)rA4 * K + cA16;
  const int nB = n0 + rB4;
  const ushort* pb_src = BT + (size_t)nB * K + cB16;
  const bool bval = (nB < N);
  float4 fa[4]; uint4 pb[2];
#define GAISSUE(k0) do { \
    _Pragma("unroll") for (int q2 = 0; q2 < 4; ++q2) fa[q2] = *(const float4*)(pa_src + (k0) + q2 * 4); \
    if (bval) { pb[0] = *(const uint4*)(pb_src + (k0)); pb[1] = *(const uint4*)(pb_src + (k0) + 8); } \
    else { uint4 z = {0,0,0,0}; pb[0]=z; pb[1]=z; } \
  } while(0)
  GAISSUE(0);
  f32x4 acc[2][2] = {};
  for (int k0 = 0; k0 < K; k0 += 64) {
    const int pbuf = (k0 >> 6) & 1;
#pragma unroll
    for (int q2 = 0; q2 < 4; ++q2) {
      ushort o[4] = { f2bf(fa[q2].x), f2bf(fa[q2].y), f2bf(fa[q2].z), f2bf(fa[q2].w) };
      *(uint2*)&As[pbuf][rA4 * 72 + cA16 + q2 * 4] = *(const uint2*)o;
    }
    *(uint4*)&Bs[pbuf][rB4 * 72 + cB16] = pb[0];
    *(uint4*)&Bs[pbuf][rB4 * 72 + cB16 + 8] = pb[1];
    __syncthreads();
    if (k0 + 64 < K) GAISSUE(k0 + 64);
#pragma unroll
    for (int sub = 0; sub < 2; ++sub) {
      const int ko = lk8 + sub * 32;
      short8 a[2], b[2];
#pragma unroll
      for (int f = 0; f < 2; ++f) {
        a[f] = *(const short8*)&As[pbuf][(wm * 32 + 16 * f + lrow) * 72 + ko];
        b[f] = *(const short8*)&Bs[pbuf][(wn * 32 + 16 * f + lrow) * 72 + ko];
      }
#pragma unroll
      for (int fi = 0; fi < 2; ++fi)
#pragma unroll
        for (int fj = 0; fj < 2; ++fj)
          acc[fi][fj] = __builtin_amdgcn_mfma_f32_16x16x32_bf16(a[fi], b[fj], acc[fi][fj], 0, 0, 0);
    }
  }
#pragma unroll
  for (int fi = 0; fi < 2; ++fi) {
    int row0 = m0 + wm * 32 + 16 * fi + (lane >> 4) * 4;
#pragma unroll
    for (int fj = 0; fj < 2; ++fj) {
      int col = n0 + wn * 32 + 16 * fj + lrow;
      if (col < N)
#pragma unroll
        for (int rr = 0; rr < 4; ++rr)
          C[(size_t)(row0 + rr) * N + col] = f2bf(acc[fi][fj][rr]);
    }
  }
}

// ---------------- fused input GEMMs: z=0 skipxs (24x32), z=1 bcdt (5x32) ----------------
__global__ __launch_bounds__(256) void k_gemm_in(
    const float* __restrict__ u1, const float* __restrict__ u2,
    const float* __restrict__ uc1, const float* __restrict__ uc2,
    const ushort* __restrict__ WsxT, const ushort* __restrict__ WbcdtT,
    ushort* __restrict__ skipxs, ushort* __restrict__ bc_pre)
{
  __shared__ __align__(16) ushort As[2][64 * 72];
  __shared__ __align__(16) ushort Bs[2][64 * 72];
  if (blockIdx.z == 0) {
    gemm_f32a_body(As, Bs, u1, u2, 1024, WsxT, skipxs, 1536, 384);
  } else {
    if (blockIdx.x >= 5) return;
    gemm_f32a_body(As, Bs, uc1, uc2, 1024, WbcdtT, bc_pre, 264, 384);
  }
}

// ---------------- depthwise 3x3 conv + bias + SiLU; bf16 in/out; writes xbcT[s][m][c] ----------------
__global__ __launch_bounds__(256) void k_conv(
    const ushort* __restrict__ skipxs, const ushort* __restrict__ bc_pre,
    const float* __restrict__ wxs, const float* __restrict__ bxs,
    const float* __restrict__ wbc, const float* __restrict__ bbc,
    ushort* __restrict__ xbcT)
{
  const int m = blockIdx.x, s = blockIdx.y;
  const int h = m >> 5, w = m & 31;
  const ushort* xp = skipxs + (size_t)s * LSEQ * 1536 + 1024;
  const ushort* bp = bc_pre + (size_t)s * LSEQ * CBCDT;
  for (int c = threadIdx.x; c < CTOT; c += 256) {
    const ushort* src; int stride; const float* wt; float bias;
    if (c < DSSM) { src = xp + c; stride = 1536; wt = wxs + (size_t)c * 9; bias = bxs[c]; }
    else { int cb = c - DSSM; src = bp + cb; stride = CBCDT; wt = wbc + (size_t)cb * 9; bias = bbc[cb]; }
    float acc = bias;
#pragma unroll
    for (int dh = -1; dh <= 1; ++dh) {
      int h2 = h + dh; if (h2 < 0 || h2 > 31) continue;
#pragma unroll
      for (int dw = -1; dw <= 1; ++dw) {
        int w2 = w + dw; if (w2 < 0 || w2 > 31) continue;
        acc += bf2f(src[(size_t)(h2 * 32 + w2) * stride]) * wt[(dh + 1) * 3 + (dw + 1)];
      }
    }
    xbcT[((size_t)s * LSEQ + m) * CTOT + c] = f2bf(siluf(acc));
  }
}

// ---------------- fused gathers (bf16 xbcT): [0,512) Xh, [512,576) B/C/BT, [576,592) dA+cumsum ----------------
__global__ __launch_bounds__(256) void k_gather_all(
    const ushort* __restrict__ xbcT, const float* __restrict__ dt_bias,
    const float* __restrict__ A_logs,
    ushort* __restrict__ XhT, ushort* __restrict__ Bbf, ushort* __restrict__ Cbf,
    ushort* __restrict__ BT, float* __restrict__ dAcs)
{
  __shared__ __align__(16) ushort U[128 * 72];
  const int bid = blockIdx.x, s = blockIdx.y, t = threadIdx.x;
  if (bid < 512) {
    const int lt = bid & 15, kh = bid >> 4;
    const int k = kh >> 3, hh = kh & 7;
    const int r = t >> 2, q = t & 3;
    const int l = lt * 64 + r;
    const int m = dir_src(k, l);
    const ushort* row = xbcT + ((size_t)s * LSEQ + m) * CTOT;
    float dtv = softplusf(bf2f(row[768 + hh]) + dt_bias[kh]);
    const ushort* xp = row + hh * 64 + q * 16;
    ushort xv[16];
    *(uint4*)xv       = *(const uint4*)xp;
    *(uint4*)(xv + 8) = *(const uint4*)(xp + 8);
#pragma unroll
    for (int i = 0; i < 16; ++i)
      U[(q * 16 + i) * 72 + r] = f2bf(bf2f(xv[i]) * dtv);
    __syncthreads();
    ushort* dst = XhT + (((size_t)s * HK + kh) * HD + r) * LSEQ + lt * 64 + q * 16;
    *(uint4*)dst       = *(const uint4*)&U[r * 72 + q * 16];
    *(uint4*)(dst + 8) = *(const uint4*)&U[r * 72 + q * 16 + 8];
    return;
  }
  if (bid < 576) {
    const int idx = bid - 512;
    const int lt = idx & 15, k = idx >> 4;
    const int r = t >> 2, q = t & 3;
    const int l = lt * 64 + r;
    const int m = dir_src(k, l);
    const ushort* row = xbcT + ((size_t)s * LSEQ + m) * CTOT;
    {
      const ushort* bsrc = row + 512 + q * 32;
      ushort ub[32];
#pragma unroll
      for (int i2 = 0; i2 < 4; ++i2) *(uint4*)&ub[i2 * 8] = *(const uint4*)(bsrc + i2 * 8);
      ushort* bd = Bbf + ((size_t)s * LSEQ + l) * NSTATE + k * 128 + q * 32;
#pragma unroll
      for (int i2 = 0; i2 < 4; ++i2) *(uint4*)(bd + i2 * 8) = *(const uint4*)&ub[i2 * 8];
#pragma unroll
      for (int i = 0; i < 32; ++i) U[(q * 32 + i) * 72 + r] = ub[i];
    }
    {
      const ushort* csrc = row + 640 + q * 32;
      ushort uc[32];
#pragma unroll
      for (int i2 = 0; i2 < 4; ++i2) *(uint4*)&uc[i2 * 8] = *(const uint4*)(csrc + i2 * 8);
      ushort* cd = Cbf + ((size_t)s * LSEQ + l) * NSTATE + k * 128 + q * 32;
#pragma unroll
      for (int i2 = 0; i2 < 4; ++i2) *(uint4*)(cd + i2 * 8) = *(const uint4*)&uc[i2 * 8];
    }
    __syncthreads();
    {
      const int n = t >> 1, half = t & 1;
      ushort* dst = BT + ((size_t)s * NSTATE + k * 128 + n) * LSEQ + lt * 64 + half * 32;
      const ushort* src = &U[n * 72 + half * 32];
#pragma unroll
      for (int i2 = 0; i2 < 4; ++i2) *(uint4*)(dst + i2 * 8) = *(const uint4*)(src + i2 * 8);
    }
    return;
  }
  {
    float* Lf = (float*)U;
    const int idx = bid - 576;
    const int z = idx & 3, k = idx >> 2;
    const int m = dir_src(k, z * 256 + t);
    const ushort* rowdt = xbcT + ((size_t)s * LSEQ + m) * CTOT + 768;
    ushort dvu[8];
    *(uint4*)dvu = *(const uint4*)rowdt;
#pragma unroll
    for (int hh = 0; hh < 8; ++hh) {
      int kh = k * 8 + hh;
      float dAv = softplusf(bf2f(dvu[hh]) + dt_bias[kh]) * (-expf(A_logs[kh]));
      Lf[hh * 256 + t] = dAv;
    }
    __syncthreads();
    const int hh = t >> 5, seg = t & 31;
    float p[8]; float run = 0.f;
#pragma unroll
    for (int i = 0; i < 8; ++i) { run += Lf[hh * 256 + seg * 8 + i]; p[i] = run; }
    float sc = run, tot = run;
#pragma unroll
    for (int d = 1; d < 32; d <<= 1) {
      float o = __shfl_up(sc, d, 32);
      if (seg >= d) sc += o;
    }
    float off = sc - tot;
    float* dst = dAcs + ((size_t)s * HK + k * 8 + hh) * LSEQ + z * 256 + seg * 8;
#pragma unroll
    for (int i = 0; i < 8; ++i) dst[i] = p[i] + off;
  }
}

// ---------------- fused scan core: [0,80) CB lower-tri, [80,592) states+scan (LDS dbuf) ----------------
__global__ __launch_bounds__(256) void k_scan_core(
    const ushort* __restrict__ Cbf, const ushort* __restrict__ Bbf, ushort* __restrict__ CBbf,
    const ushort* __restrict__ BT, const ushort* __restrict__ XhT,
    const float* __restrict__ dAcs, ushort* __restrict__ prevP)
{
  __shared__ __align__(16) ushort As[2][64 * 72];
  __shared__ __align__(16) ushort Bs[2][64 * 72];
  __shared__ __align__(16) ushort Tr[64 * 72];
  __shared__ float decay[CHUNKSZ];
  const int bid = blockIdx.x, t = threadIdx.x;
  const int lane = t & 63, wv = t >> 6;
  const int lrow = lane & 15, lk8 = (lane >> 4) * 8;
  const int rA = t >> 2, cA = (t & 3) * 16;

  if (bid < 80) {
    const int sz = bid & 7, pidx = bid >> 3, s = sz >> 2, z = sz & 3;
    int it = 0; { while ((it + 1) * (it + 2) / 2 <= pidx) ++it; }
    const int jt = pidx - it * (it + 1) / 2;
    const ushort* Ap = Cbf + ((size_t)s * LSEQ + z * CHUNKSZ + it * 64 + rA) * NSTATE + cA;
    const ushort* Bp = Bbf + ((size_t)s * LSEQ + z * CHUNKSZ + jt * 64 + rA) * NSTATE + cA;
    uint4 qa[2], qb[2];
#define CBISSUE(k0) do { qa[0]=*(const uint4*)(Ap+(k0)); qa[1]=*(const uint4*)(Ap+(k0)+8); \
                         qb[0]=*(const uint4*)(Bp+(k0)); qb[1]=*(const uint4*)(Bp+(k0)+8); } while(0)
    CBISSUE(0);
    f32x4 acc[4] = {};
    for (int k0 = 0; k0 < NSTATE; k0 += 64) {
      const int pb2 = (k0 >> 6) & 1;
      *(uint4*)&As[pb2][rA * 72 + cA] = qa[0]; *(uint4*)&As[pb2][rA * 72 + cA + 8] = qa[1];
      *(uint4*)&Bs[pb2][rA * 72 + cA] = qb[0]; *(uint4*)&Bs[pb2][rA * 72 + cA + 8] = qb[1];
      __syncthreads();
      if (k0 + 64 < NSTATE) CBISSUE(k0 + 64);
#pragma unroll
      for (int sub = 0; sub < 2; ++sub) {
        const int ko = lk8 + sub * 32;
        short8 a = *(const short8*)&As[pb2][(16 * wv + lrow) * 72 + ko];
#pragma unroll
        for (int fj = 0; fj < 4; ++fj) {
          short8 b = *(const short8*)&Bs[pb2][(16 * fj + lrow) * 72 + ko];
          acc[fj] = __builtin_amdgcn_mfma_f32_16x16x32_bf16(a, b, acc[fj], 0, 0, 0);
        }
      }
    }
    ushort* Cp = CBbf + (size_t)sz * CHUNKSZ * CHUNKSZ;
    const int row0 = it * 64 + 16 * wv + (lane >> 4) * 4;
#pragma unroll
    for (int fj = 0; fj < 4; ++fj) {
      int col = jt * 64 + 16 * fj + lrow;
#pragma unroll
      for (int rr = 0; rr < 4; ++rr)
        Cp[(size_t)(row0 + rr) * CHUNKSZ + col] = f2bf(acc[fj][rr]);
    }
    return;
  }

  // states + inter-chunk scan -> prevP
  {
    const int idx = bid - 80;
    const int nh = idx & 7, kh = (idx >> 3) & 31, s = idx >> 8;
    const float* dA = dAcs + ((size_t)s * HK + kh) * LSEQ;
    float carry[4][4];
#pragma unroll
    for (int fj = 0; fj < 4; ++fj)
#pragma unroll
      for (int rr = 0; rr < 4; ++rr) carry[fj][rr] = 0.f;

    for (int z = 0; z < NC; ++z) {
      __syncthreads();
      const float dlast = dA[z * CHUNKSZ + CHUNKSZ - 1];
      decay[t] = __expf(dlast - dA[z * CHUNKSZ + t]);
      {
        const int n_base = 16 * wv + (lane >> 4) * 4;
#pragma unroll
        for (int fj = 0; fj < 4; ++fj) {
          const int p = 16 * fj + lrow;
#pragma unroll
          for (int rr = 0; rr < 4; ++rr)
            Tr[p * 72 + n_base + rr] = f2bf(carry[fj][rr]);
        }
      }
      __syncthreads();
      {
        const int sz = s * 4 + z;
        ushort* dst = prevP + (((size_t)sz * HK + kh) * HD + rA) * NSTATE + nh * 64 + cA;
        *(uint4*)dst       = *(const uint4*)&Tr[rA * 72 + cA];
        *(uint4*)(dst + 8) = *(const uint4*)&Tr[rA * 72 + cA + 8];
      }
      const ushort* Ap = BT + ((size_t)s * NSTATE + nh * 64 + rA) * LSEQ + z * CHUNKSZ + cA;
      const ushort* Xp = XhT + (((size_t)s * HK + kh) * HD + rA) * LSEQ + z * CHUNKSZ + cA;
      uint4 qa[2], qb[2];
#define SSISSUE(k0) do { qa[0]=*(const uint4*)(Ap+(k0)); qa[1]=*(const uint4*)(Ap+(k0)+8); \
                         qb[0]=*(const uint4*)(Xp+(k0)); qb[1]=*(const uint4*)(Xp+(k0)+8); } while(0)
      SSISSUE(0);
      f32x4 acc[4] = {};
      for (int k0 = 0; k0 < CHUNKSZ; k0 += 64) {
        const int pb2 = (k0 >> 6) & 1;
        *(uint4*)&As[pb2][rA * 72 + cA] = qa[0]; *(uint4*)&As[pb2][rA * 72 + cA + 8] = qa[1];
        {
          ushort tmp[16];
          *(uint4*)&tmp[0] = qb[0]; *(uint4*)&tmp[8] = qb[1];
#pragma unroll
          for (int i2 = 0; i2 < 8; ++i2) {
            int c = k0 + cA + 2 * i2;
            unsigned wpk = (unsigned)f2bf(bf2f(tmp[2 * i2]) * decay[c]) |
                           ((unsigned)f2bf(bf2f(tmp[2 * i2 + 1]) * decay[c + 1]) << 16);
            *(unsigned*)&Bs[pb2][rA * 72 + cA + 2 * i2] = wpk;
          }
        }
        __syncthreads();
        if (k0 + 64 < CHUNKSZ) SSISSUE(k0 + 64);
#pragma unroll
        for (int sub = 0; sub < 2; ++sub) {
          const int ko = lk8 + sub * 32;
          short8 a = *(const short8*)&As[pb2][(16 * wv + lrow) * 72 + ko];
#pragma unroll
          for (int fj = 0; fj < 4; ++fj) {
            short8 b = *(const short8*)&Bs[pb2][(16 * fj + lrow) * 72 + ko];
            acc[fj] = __builtin_amdgcn_mfma_f32_16x16x32_bf16(a, b, acc[fj], 0, 0, 0);
          }
        }
      }
      const float cdec = __expf(dlast);
#pragma unroll
      for (int fj = 0; fj < 4; ++fj)
#pragma unroll
        for (int rr = 0; rr < 4; ++rr)
          carry[fj][rr] = carry[fj][rr] * cdec + acc[fj][rr];
    }
  }
}

// ---------------- Y = Ydiag + Yoff (MFMA, LDS dbuf, bf16 out) ----------------
// Load-balance remap: co-resident blocks (f, f+256) get complementary (it, z)
__global__ __launch_bounds__(256) void k_y_mfma(
    const ushort* __restrict__ CBbf, const ushort* __restrict__ XhT,
    const ushort* __restrict__ Cbf, const ushort* __restrict__ prevP,
    const float* __restrict__ dAcs, ushort* __restrict__ Ybf)
{
  __shared__ __align__(16) ushort As[2][128 * 72];
  __shared__ __align__(16) ushort Bs[2][64 * 72];
  __shared__ float seg[CHUNKSZ];
  __shared__ float f2s[CHUNKSZ];
  const int szr = blockIdx.z, kh = blockIdx.y;
  const int s = szr >> 2, zr = szr & 3;
  const int z = (zr + 2 * s) & 3;
  const int it = blockIdx.x ^ s;
  const int sz = s * 4 + z;
  const int t = threadIdx.x, lane = t & 63, wv = t >> 6;
  const int lrow = lane & 15, lk8 = (lane >> 4) * 8;
  const int i0 = it * 128;
  const float* dAp = dAcs + ((size_t)s * HK + kh) * LSEQ + z * CHUNKSZ;
  seg[t] = dAp[t];
  __syncthreads();
  f2s[t] = __expf(seg[(t >> 5) << 5] - seg[t]);
  __syncthreads();

  const int rA = t >> 1, cA = (t & 1) * 32;
  const int rB = t >> 2, cB = (t & 3) * 16;
  f32x4 acc[2][4] = {};
  uint4 qa[4], qb[2];

  // phase A: acc = C @ prev^T  (skip for z==0: prev == 0)
  if (z != 0) {
    const ushort* Cp = Cbf + ((size_t)s * LSEQ + z * CHUNKSZ + i0 + rA) * NSTATE + cA;
    const ushort* Pp = prevP + (((size_t)sz * HK + kh) * HD + rB) * NSTATE + cB;
#define YISSUEA(k0) do { \
    qa[0]=*(const uint4*)(Cp+(k0));    qa[1]=*(const uint4*)(Cp+(k0)+8); \
    qa[2]=*(const uint4*)(Cp+(k0)+16); qa[3]=*(const uint4*)(Cp+(k0)+24); \
    qb[0]=*(const uint4*)(Pp+(k0));    qb[1]=*(const uint4*)(Pp+(k0)+8); } while(0)
    YISSUEA(0);
    for (int k0 = 0; k0 < NSTATE; k0 += 64) {
      const int pb2 = (k0 >> 6) & 1;
#pragma unroll
      for (int q2 = 0; q2 < 4; ++q2) *(uint4*)&As[pb2][rA * 72 + cA + q2 * 8] = qa[q2];
      *(uint4*)&Bs[pb2][rB * 72 + cB] = qb[0]; *(uint4*)&Bs[pb2][rB * 72 + cB + 8] = qb[1];
      __syncthreads();
      if (k0 + 64 < NSTATE) YISSUEA(k0 + 64);
#pragma unroll
      for (int sub = 0; sub < 2; ++sub) {
        const int ko = lk8 + sub * 32;
        short8 a[2], b[4];
#pragma unroll
        for (int f = 0; f < 2; ++f) a[f] = *(const short8*)&As[pb2][(32 * wv + 16 * f + lrow) * 72 + ko];
#pragma unroll
        for (int f = 0; f < 4; ++f) b[f] = *(const short8*)&Bs[pb2][(16 * f + lrow) * 72 + ko];
#pragma unroll
        for (int fi = 0; fi < 2; ++fi)
#pragma unroll
          for (int fj = 0; fj < 4; ++fj)
            acc[fi][fj] = __builtin_amdgcn_mfma_f32_16x16x32_bf16(a[fi], b[fj], acc[fi][fj], 0, 0, 0);
      }
    }
  }

  // prefetch phase-B tile 0 while rescaling
  const ushort* CBp = CBbf + ((size_t)sz * CHUNKSZ + i0 + rA) * CHUNKSZ;
  const ushort* Xp = XhT + (((size_t)s * HK + kh) * HD + rB) * LSEQ + z * CHUNKSZ + cB;
  const int nktB = 2 * it + 2;
#define YISSUEB(kt) do { const ushort* sa = CBp + (kt) * 64 + cA; \
    qa[0]=*(const uint4*)sa;      qa[1]=*(const uint4*)(sa+8); \
    qa[2]=*(const uint4*)(sa+16); qa[3]=*(const uint4*)(sa+24); \
    qb[0]=*(const uint4*)(Xp+(kt)*64); qb[1]=*(const uint4*)(Xp+(kt)*64+8); } while(0)
  YISSUEB(0);

  // scale Yoff rows by e^{seg_i}
  if (z != 0) {
#pragma unroll
    for (int fi = 0; fi < 2; ++fi) {
      int rloc = 32 * wv + 16 * fi + (lane >> 4) * 4;
#pragma unroll
      for (int rr = 0; rr < 4; ++rr) {
        float e = __expf(seg[i0 + rloc + rr]);
#pragma unroll
        for (int fj = 0; fj < 4; ++fj) acc[fi][fj][rr] *= e;
      }
    }
  }

  // phase B: Ydiag (slice-factored, CB bf16)
  for (int kt = 0; kt < nktB; ++kt) {
    const int pb2 = kt & 1;
    {
      const int i = i0 + rA;
      const int jbase = kt * 64 + cA;
      if (i >= jbase) {
        float f1 = __expf(seg[i] - seg[jbase]);
        ushort tmp[32];
        *(uint4*)&tmp[0] = qa[0]; *(uint4*)&tmp[8] = qa[1];
        *(uint4*)&tmp[16] = qa[2]; *(uint4*)&tmp[24] = qa[3];
#pragma unroll
        for (int c = 0; c < 32; c += 2) {
          int j = jbase + c;
          float v0 = (j     <= i) ? bf2f(tmp[c])     * f1 : 0.f;
          float v1 = (j + 1 <= i) ? bf2f(tmp[c + 1]) * f1 : 0.f;
          *(unsigned*)&As[pb2][rA * 72 + cA + c] = (unsigned)f2bf(v0) | ((unsigned)f2bf(v1) << 16);
        }
      } else {
        uint4 zz = {0, 0, 0, 0};
#pragma unroll
        for (int q2 = 0; q2 < 4; ++q2) *(uint4*)&As[pb2][rA * 72 + cA + q2 * 8] = zz;
      }
    }
    {
      ushort tmp[16];
      *(uint4*)&tmp[0] = qb[0]; *(uint4*)&tmp[8] = qb[1];
#pragma unroll
      for (int i2 = 0; i2 < 8; ++i2) {
        int j = kt * 64 + cB + 2 * i2;
        unsigned wpk = (unsigned)f2bf(bf2f(tmp[2 * i2]) * f2s[j]) |
                       ((unsigned)f2bf(bf2f(tmp[2 * i2 + 1]) * f2s[j + 1]) << 16);
        *(unsigned*)&Bs[pb2][rB * 72 + cB + 2 * i2] = wpk;
      }
    }
    __syncthreads();
    if (kt + 1 < nktB) YISSUEB(kt + 1);
#pragma unroll
    for (int sub = 0; sub < 2; ++sub) {
      if (2 * kt + sub <= 4 * it + wv) {
        const int ko = lk8 + sub * 32;
        short8 a[2], b[4];
#pragma unroll
        for (int f = 0; f < 2; ++f) a[f] = *(const short8*)&As[pb2][(32 * wv + 16 * f + lrow) * 72 + ko];
#pragma unroll
        for (int f = 0; f < 4; ++f) b[f] = *(const short8*)&Bs[pb2][(16 * f + lrow) * 72 + ko];
#pragma unroll
        for (int fi = 0; fi < 2; ++fi)
#pragma unroll
          for (int fj = 0; fj < 4; ++fj)
            acc[fi][fj] = __builtin_amdgcn_mfma_f32_16x16x32_bf16(a[fi], b[fj], acc[fi][fj], 0, 0, 0);
      }
    }
  }

  ushort* Yp = Ybf + (((size_t)s * LSEQ + z * CHUNKSZ + i0) * HK + kh) * HD;
#pragma unroll
  for (int fi = 0; fi < 2; ++fi) {
    int row0 = 32 * wv + 16 * fi + (lane >> 4) * 4;
#pragma unroll
    for (int fj = 0; fj < 4; ++fj) {
      int col = 16 * fj + lrow;
#pragma unroll
      for (int rr = 0; rr < 4; ++rr)
        Yp[(size_t)(row0 + rr) * (HK * HD) + col] = f2bf(acc[fi][fj][rr]);
    }
  }
}

// ---------------- combine 4 directions + D*x + gated RMSNorm + MLP half (bf16 in/out) ----------------
__global__ __launch_bounds__(256) void k_combine(
    const ushort* __restrict__ Ybf, const ushort* __restrict__ xbcT,
    const ushort* __restrict__ skipxs, const float* __restrict__ Ds,
    const float* __restrict__ normw, ushort* __restrict__ o768bf)
{
  const int m = blockIdx.x, s = blockIdx.y, t = threadIdx.x;
  const int h = m >> 5, w = m & 31;
  const int l0 = m, l1 = (w << 5) | h, l2 = 1023 - m, l3 = 1023 - ((w << 5) | h);
  const ushort* Yb = Ybf + (size_t)s * LSEQ * (HK * HD);
  const ushort* xrow = xbcT + ((size_t)s * LSEQ + m) * CTOT;
  const ushort* srow = skipxs + ((size_t)s * LSEQ + m) * 1536;

  float g[2];
  float ss = 0.f;
#pragma unroll
  for (int q = 0; q < 2; ++q) {
    int d = t + q * 256;
    int hh = d >> 6, p = d & 63;
    float dsum = Ds[hh] + Ds[hh + 8] + Ds[hh + 16] + Ds[hh + 24];
    float val = bf2f(Yb[((size_t)l0 * HK + hh) * HD + p])
              + bf2f(Yb[((size_t)l1 * HK + 8 + hh) * HD + p])
              + bf2f(Yb[((size_t)l2 * HK + 16 + hh) * HD + p])
              + bf2f(Yb[((size_t)l3 * HK + 24 + hh) * HD + p])
              + bf2f(xrow[d]) * dsum;
    float zv = bf2f(srow[512 + d]);
    g[q] = val * siluf(zv);
    ss += g[q] * g[q];
  }
  for (int off = 32; off > 0; off >>= 1) ss += __shfl_down(ss, off, 64);
  __shared__ float red[4];
  if ((t & 63) == 0) red[t >> 6] = ss;
  __syncthreads();
  float total = red[0] + red[1] + red[2] + red[3];
  float scale = rsqrtf(total * (1.f / 512.f) + 1e-5f);

  ushort* orow = o768bf + ((size_t)s * LSEQ + m) * 768;
#pragma unroll
  for (int q = 0; q < 2; ++q) {
    int d = t + q * 256;
    orow[256 + d] = f2bf(g[q] * scale * normw[d]);
  }
  float z0 = bf2f(srow[t]), x0 = bf2f(srow[256 + t]);
  orow[t] = f2bf(siluf(z0) * x0);
}

// ---------------- 16x64-tile bf16 GEMM (out GEMM), LDS dbuf, grid (6,128) ----------------
__global__ __launch_bounds__(256) void gemm64_bf16(
    const ushort* __restrict__ A, const ushort* __restrict__ BT,
    float* __restrict__ C, int M, int N, int K)
{
  __shared__ __align__(16) ushort As[2][16 * 72];
  __shared__ __align__(16) ushort Bs[2][64 * 72];
  const int n0 = blockIdx.x * 64, m0 = blockIdx.y * 16;
  const int t = threadIdx.x, lane = t & 63, wv = t >> 6;
  const int lrow = lane & 15, lk8 = (lane >> 4) * 8;
  const int rA16 = t >> 4, cA4 = (t & 15) * 4;   // A staging: 16 rows x 64 cols, 4/thread
  const int rB4 = t >> 2, cB16 = (t & 3) * 16;   // B staging: 64 rows x 64 cols
  const ushort* pa_src = A + (size_t)(m0 + rA16) * K + cA4;
  const int nB = n0 + rB4;
  const ushort* pb_src = BT + (size_t)nB * K + cB16;
  const bool bval = (nB < N);
  uint2 pa; uint4 pb[2];
#define G64ISSUE(k0) do { \
    pa = *(const uint2*)(pa_src+(k0)); \
    if (bval) { pb[0]=*(const uint4*)(pb_src+(k0)); pb[1]=*(const uint4*)(pb_src+(k0)+8); } \
    else { uint4 z={0,0,0,0}; pb[0]=z; pb[1]=z; } } while(0)
  G64ISSUE(0);
  f32x4 acc = {};
  for (int k0 = 0; k0 < K; k0 += 64) {
    const int pbuf = (k0 >> 6) & 1;
    *(uint2*)&As[pbuf][rA16 * 72 + cA4] = pa;
    *(uint4*)&Bs[pbuf][rB4 * 72 + cB16] = pb[0]; *(uint4*)&Bs[pbuf][rB4 * 72 + cB16 + 8] = pb[1];
    __syncthreads();
    if (k0 + 64 < K) G64ISSUE(k0 + 64);
#pragma unroll
    for (int sub = 0; sub < 2; ++sub) {
      const int ko = lk8 + sub * 32;
      short8 a = *(const short8*)&As[pbuf][lrow * 72 + ko];
      short8 b = *(const short8*)&Bs[pbuf][(wv * 16 + lrow) * 72 + ko];
      acc = __builtin_amdgcn_mfma_f32_16x16x32_bf16(a, b, acc, 0, 0, 0);
    }
  }
  {
    int row0 = m0 + (lane >> 4) * 4;
    int col = n0 + wv * 16 + lrow;
    if (col < N)
#pragma unroll
      for (int rr = 0; rr < 4; ++rr)
        C[(size_t)(row0 + rr) * N + col] = acc[rr];
  }
}

// ---------------- workspace layout (float units; bf16 buffers use half) ----------------
constexpr size_t OFF_SKIPXS = 0;                         // bf16 2048*1536 -> 1572864 f
constexpr size_t OFF_XBCT   = 3145728;                   // bf16 2048*776 -> 794624 f (slot kept)
constexpr size_t OFF_XHT    = OFF_XBCT + 1589248;        // bf16 -> 2097152 f
constexpr size_t OFF_BBF    = OFF_XHT + 2097152;         // 524288
constexpr size_t OFF_CBF    = OFF_BBF + 524288;          // 524288
constexpr size_t OFF_BTBF   = OFF_CBF + 524288;          // 524288
constexpr size_t OFF_DA     = OFF_BTBF + 524288;         // 65536
constexpr size_t OFF_CB     = OFF_DA + 65536;            // bf16 -> 262144 f
constexpr size_t OFF_PREV   = OFF_CB + 262144;           // bf16 -> 4194304 f
constexpr size_t OFF_Y      = OFF_PREV + 4194304;        // bf16 -> 2097152 f
constexpr size_t OFF_O768   = OFF_Y + 2097152;           // bf16 -> 786432 f
constexpr size_t OFF_WSXT   = OFF_O768 + 786432;         // 294912
constexpr size_t OFF_WBCT   = OFF_WSXT + 294912;         // 50688
constexpr size_t OFF_WOUT   = OFF_WBCT + 50688;          // 147456
constexpr size_t OFF_BCP    = OFF_PREV;                  // overlay: bc_pre bf16 (dead before prevP)

extern "C" void kernel_launch(void* const* d_in, const int* in_sizes, int n_in,
                              void* d_out, int out_size, void* d_ws, size_t ws_size,
                              hipStream_t stream)
{
  const float* u1     = (const float*)d_in[0];
  const float* u2     = (const float*)d_in[1];
  const float* u2c1   = (const float*)d_in[2];
  const float* u1c2   = (const float*)d_in[3];
  const float* W_skip = (const float*)d_in[4];
  const float* W_xs   = (const float*)d_in[5];
  const float* W_bcdt = (const float*)d_in[6];
  const float* cxw    = (const float*)d_in[7];
  const float* cxb    = (const float*)d_in[8];
  const float* cbw    = (const float*)d_in[9];
  const float* cbb    = (const float*)d_in[10];
  const float* Ds     = (const float*)d_in[11];
  const float* normw  = (const float*)d_in[12];
  const float* W_out  = (const float*)d_in[13];
  const float* dt_b   = (const float*)d_in[14];
  const float* A_logs = (const float*)d_in[15];
  float* out = (float*)d_out;
  float* ws  = (float*)d_ws;

  ushort* skipxs  = (ushort*)(ws + OFF_SKIPXS);
  ushort* xbcT    = (ushort*)(ws + OFF_XBCT);
  ushort* XhT     = (ushort*)(ws + OFF_XHT);
  ushort* Bbf     = (ushort*)(ws + OFF_BBF);
  ushort* Cbf     = (ushort*)(ws + OFF_CBF);
  ushort* BTbf    = (ushort*)(ws + OFF_BTBF);
  float*  dAcs    = ws + OFF_DA;
  ushort* CBbf    = (ushort*)(ws + OFF_CB);
  ushort* prevP   = (ushort*)(ws + OFF_PREV);
  ushort* Ybf     = (ushort*)(ws + OFF_Y);
  ushort* o768bf  = (ushort*)(ws + OFF_O768);
  ushort* WsxT    = (ushort*)(ws + OFF_WSXT);
  ushort* WbcdtT  = (ushort*)(ws + OFF_WBCT);
  ushort* WoutT   = (ushort*)(ws + OFF_WOUT);
  ushort* bc_pre  = (ushort*)(ws + OFF_BCP);

  // 1: weight transposes
  k_prep<<<dim3(246), 256, 0, stream>>>(W_skip, W_xs, W_bcdt, W_out, WsxT, WbcdtT, WoutT);
  // 2: both input GEMMs in one launch (64x64 tiles -> 928 blocks, ~3.6/CU)
  k_gemm_in<<<dim3(24, 32, 2), 256, 0, stream>>>(u1, u2, u2c1, u1c2, WsxT, WbcdtT, skipxs, bc_pre);
  // 3: conv (bf16 in/out)
  k_conv<<<dim3(1024, 2), 256, 0, stream>>>(skipxs, bc_pre, cxw, cxb, cbw, cbb, xbcT);
  // 4: all gathers + cumsum
  k_gather_all<<<dim3(592, 2), 256, 0, stream>>>(xbcT, dt_b, A_logs, XhT, Bbf, Cbf, BTbf, dAcs);
  // 5: CB (lower-tri) + states/scan
  k_scan_core<<<dim3(592), 256, 0, stream>>>(Cbf, Bbf, CBbf, BTbf, XhT, dAcs, prevP);
  // 6: Y (load-balanced remap; z==0 blocks skip phase A)
  k_y_mfma<<<dim3(2, 32, 8), 256, 0, stream>>>(CBbf, XhT, Cbf, prevP, dAcs, Ybf);
  // 7: combine
  k_combine<<<dim3(1024, 2), 256, 0, stream>>>(Ybf, xbcT, skipxs, Ds, normw, o768bf);
  // 8: out GEMM (16-row tiles -> 768 blocks, ~3/CU)
  gemm64_bf16<<<dim3(6, 128), 256, 0, stream>>>(o768bf, WoutT, out, 2048, 384, 768);
}